// Round 3
// baseline (16720.544 us; speedup 1.0000x reference)
//
#include <hip/hip_runtime.h>
#include <hip/hip_bf16.h>

typedef __attribute__((ext_vector_type(8))) short bf16x8;
typedef __attribute__((ext_vector_type(4))) float f32x4;
typedef __hip_bfloat16 bf16;

#define ALPHA_F 0.42728713f
#define LN_EPS 1e-3f

__device__ __forceinline__ float silu_f(float x) { return x / (1.0f + __expf(-x)); }
__device__ __forceinline__ float mish_f(float x) {
  float sp = (x > 20.0f) ? x : log1pf(__expf(x));
  return x * tanhf(sp);
}

// acc in AGPRs ("+a") — keeps the 128-float accumulator out of the VGPR file;
// "+v" here forced per-MFMA accvgpr/scratch shuttling (R2: VGPR=92 < 128 acc floats,
// MfmaUtil 3%).
__device__ __forceinline__ void mfma16(f32x4& acc, bf16x8 a, bf16x8 b) {
  asm("v_mfma_f32_16x16x32_bf16 %0, %1, %2, %0" : "+a"(acc) : "v"(a), "v"(b));
}

#define GLOAD_LDS16(gp, lp)                                                              \
  __builtin_amdgcn_global_load_lds((__attribute__((address_space(1))) void*)(void*)(gp), \
                                   (__attribute__((address_space(3))) void*)(void*)(lp), \
                                   16, 0, 0)

#define BAR() asm volatile("s_barrier" ::: "memory")
#define LGKM0() asm volatile("s_waitcnt lgkmcnt(0)" ::: "memory")

// ---------------- batched per-layer weight transpose: W[K,N] f32 -> Wt[N,K] bf16 -------
__global__ __launch_bounds__(256) void transpose_layer(
    const float* __restrict__ wq, const float* __restrict__ wk, const float* __restrict__ wv,
    const float* __restrict__ wo, const float* __restrict__ f1, const float* __restrict__ f2,
    const float* __restrict__ sgf, const float* __restrict__ swg,
    bf16* __restrict__ Wqkv, bf16* __restrict__ Wo, bf16* __restrict__ Wf1,
    bf16* __restrict__ Wf2, bf16* __restrict__ Wsgf, bf16* __restrict__ Wswg) {
  __shared__ float tile[32][33];
  int b = blockIdx.x;
  const float* W;
  bf16* Wt;
  int K, N, tb;
  if (b < 3072) {
    int m = b >> 10;
    W = (m == 0) ? wq : ((m == 1) ? wk : wv);
    Wt = Wqkv + (size_t)m * 1024 * 1024;
    K = 1024; N = 1024; tb = b & 1023;
  } else if (b < 4096) { W = wo;  Wt = Wo;   K = 1024; N = 1024; tb = b - 3072; }
  else if (b < 5632)   { W = f1;  Wt = Wf1;  K = 1024; N = 1536; tb = b - 4096; }
  else if (b < 7168)   { W = f2;  Wt = Wf2;  K = 1536; N = 1024; tb = b - 5632; }
  else if (b < 9216)   { W = sgf; Wt = Wsgf; K = 256;  N = 8192; tb = b - 7168; }
  else                 { W = swg; Wt = Wswg; K = 256;  N = 4096; tb = b - 9216; }
  int ntx = N >> 5;
  int ty_ = tb / ntx, tx_ = tb - ty_ * ntx;
  int nb = tx_ * 32, kb = ty_ * 32;
  int tx = threadIdx.x & 31, ty = threadIdx.x >> 5;
#pragma unroll
  for (int i = 0; i < 4; ++i)
    tile[ty + i * 8][tx] = W[(size_t)(kb + ty + i * 8) * N + nb + tx];
  __syncthreads();
#pragma unroll
  for (int i = 0; i < 4; ++i)
    Wt[(size_t)(nb + ty + i * 8) * K + kb + tx] = __float2bfloat16(tile[tx][ty + i * 8]);
}

__global__ __launch_bounds__(256) void cvt_f32_bf16_k(const float* __restrict__ in,
                                                      bf16* __restrict__ out, long long n) {
  long long i = ((long long)blockIdx.x * 256 + threadIdx.x) * 4;
  if (i + 3 < n) {
    float4 v = *(const float4*)(in + i);
    out[i + 0] = __float2bfloat16(v.x);
    out[i + 1] = __float2bfloat16(v.y);
    out[i + 2] = __float2bfloat16(v.z);
    out[i + 3] = __float2bfloat16(v.w);
  }
}

__global__ __launch_bounds__(256) void pack3_k(const float* __restrict__ a,
                                               const float* __restrict__ b,
                                               const float* __restrict__ c,
                                               float* __restrict__ o) {
  int i = blockIdx.x * 256 + threadIdx.x;
  if (i < 1024) o[i] = a[i];
  else if (i < 2048) o[i] = b[i - 1024];
  else if (i < 3072) o[i] = c[i - 2048];
}

__global__ __launch_bounds__(1) void sentinel_k(float* __restrict__ o) { o[0] = 1.2345e7f; }

// =======================================================================================
// 256x256-tile phase-pipelined bf16 GEMM: C[M,N] = A[M,K] @ Bt[N,K]^T (+bias, act)
// BK=32, 4-deep LDS ring per operand (128 KiB total), 2 phases/K-tile, counted vmcnt,
// raw s_barrier, setprio around MFMA, XOR-swizzled LDS (inverse-swizzled global source).
// Requires: M%256==0, N%256==0, K%32==0, K/32 >= 4.
// =======================================================================================
template <int ACT, bool OUTBF16, bool BIAS>
__global__ __launch_bounds__(512, 1) void gemm256(const bf16* __restrict__ A,
                                                  const bf16* __restrict__ Bt,
                                                  const float* __restrict__ bias,
                                                  float* __restrict__ Cf,
                                                  bf16* __restrict__ Cb,
                                                  int M, int N, int K) {
  __shared__ __align__(128) short lds[65536];  // A ring: [0,32768) shorts, B ring: [32768,65536)
  const int t = threadIdx.x;
  const int lane = t & 63, wave = t >> 6;
  const int wr = wave >> 2, wc = wave & 3;

  // grid: 1D, XCD-swizzled
  const int nbx = N >> 8, nby = M >> 8;
  int nwg = nbx * nby;
  int bid = blockIdx.x;
  if ((nwg & 7) == 0) bid = (bid & 7) * (nwg >> 3) + (bid >> 3);
  const int by = bid / nbx, bx = bid - by * nbx;
  const int bm0 = by << 8, bn0 = bx << 8;

  const int NT = K >> 5;

  // ---- staging addressing (per thread): phys lds slot p = t&3 holds logical k-slot
  // slog = p ^ ((R>>1)&3); global source pre-inverse-swizzled so swizzled read is linear.
  const int slog8 = (((t & 3) ^ ((t >> 3) & 3)) << 3);  // logical k element offset
  const bf16* Abase = A + (size_t)bm0 * K;
  const bf16* Bbase = Bt + (size_t)bn0 * K;

  auto stageA = [&](int T) {
    int col = (T << 5) + slog8;
#pragma unroll
    for (int j = 0; j < 2; ++j) {
      const bf16* src = Abase + (size_t)(j * 128 + (t >> 2)) * K + col;
      short* dst = lds + ((T & 3) * 8192) + j * 4096 + t * 8;
      GLOAD_LDS16(src, dst);
    }
  };
  auto stageB = [&](int T) {
    int col = (T << 5) + slog8;
#pragma unroll
    for (int j = 0; j < 2; ++j) {
      const bf16* src = Bbase + (size_t)(j * 128 + (t >> 2)) * K + col;
      short* dst = lds + 32768 + ((T & 3) * 8192) + j * 4096 + t * 8;
      GLOAD_LDS16(src, dst);
    }
  };

  // ---- fragment read bases (per lane; swizzle bits constant across frag index)
  const int fr = lane & 15, s = lane >> 4;
  const int scol_sh = ((s ^ ((fr >> 1) & 3)) << 3);  // shorts
  const short* ArdBase = lds + (wr * 128 + fr) * 32 + scol_sh;
  const short* BrdBase = lds + 32768 + (wc * 64 + fr) * 32 + scol_sh;

  f32x4 acc[8][4] = {};

  // ---- prologue: stage units 0..4 = A0,B0,A1,B1,A2; wait for tile 0 (vmcnt 6)
  stageA(0); stageB(0); stageA(1); stageB(1); stageA(2);
  asm volatile("s_waitcnt vmcnt(6)" ::: "memory");
  BAR();

  for (int kt = 0; kt < NT; ++kt) {
    const int slot = (kt & 3) * 8192;
    bf16x8 bfr[4], afr[4];
    // ---- phase 0: read all B + A frags 0..3; stage B(kt+2)
#pragma unroll
    for (int n = 0; n < 4; ++n) bfr[n] = *(const bf16x8*)(BrdBase + slot + n * 512);
#pragma unroll
    for (int q = 0; q < 4; ++q) afr[q] = *(const bf16x8*)(ArdBase + slot + q * 512);
    if (kt + 2 < NT) stageB(kt + 2);
    BAR();
    LGKM0();
    __builtin_amdgcn_sched_barrier(0);
    __builtin_amdgcn_s_setprio(1);
#pragma unroll
    for (int m = 0; m < 4; ++m)
#pragma unroll
      for (int n = 0; n < 4; ++n) mfma16(acc[m][n], afr[m], bfr[n]);
    __builtin_amdgcn_s_setprio(0);
    BAR();
    // ---- phase 1: read A frags 4..7; stage A(kt+3); counted vmcnt at tile end
#pragma unroll
    for (int q = 0; q < 4; ++q) afr[q] = *(const bf16x8*)(ArdBase + slot + (4 + q) * 512);
    if (kt + 3 < NT) stageA(kt + 3);
    BAR();
    LGKM0();
    __builtin_amdgcn_sched_barrier(0);
    __builtin_amdgcn_s_setprio(1);
#pragma unroll
    for (int m = 0; m < 4; ++m)
#pragma unroll
      for (int n = 0; n < 4; ++n) mfma16(acc[4 + m][n], afr[m], bfr[n]);
    __builtin_amdgcn_s_setprio(0);
    if (kt < NT - 1) {
      int rem = NT - 2 - kt;
      if (rem >= 2)      asm volatile("s_waitcnt vmcnt(6)" ::: "memory");
      else if (rem == 1) asm volatile("s_waitcnt vmcnt(4)" ::: "memory");
      else               asm volatile("s_waitcnt vmcnt(0)" ::: "memory");
    }
    BAR();
  }

  asm volatile("s_nop 7\n\ts_nop 7");
  const int lr4 = (lane >> 4) << 2, lc = lane & 15;
#pragma unroll
  for (int m = 0; m < 8; ++m) {
#pragma unroll
    for (int n = 0; n < 4; ++n) {
      int col = bn0 + wc * 64 + n * 16 + lc;
      float bv = 0.0f;
      if constexpr (BIAS) bv = bias[col];
#pragma unroll
      for (int j = 0; j < 4; ++j) {
        int row = bm0 + wr * 128 + m * 16 + lr4 + j;
        float v = acc[m][n][j] + bv;
        if constexpr (ACT == 1) v = silu_f(v);
        if constexpr (ACT == 2) v = mish_f(v);
        if constexpr (OUTBF16) Cb[(size_t)row * N + col] = __float2bfloat16(v);
        else Cf[(size_t)row * N + col] = v;
      }
    }
  }
}

// ---------------- 128x128 bf16 MFMA GEMM (kept for 512-block shapes + tiny M) ----------
template <int ACT, bool OUTBF16, bool BIAS>
__global__ __launch_bounds__(256) void gemm_tn(const bf16* __restrict__ A,
                                               const bf16* __restrict__ Bt,
                                               const float* __restrict__ bias,
                                               float* __restrict__ Cf, bf16* __restrict__ Cb,
                                               int M, int N, int K) {
  __shared__ __align__(128) short As[128 * 32];
  __shared__ __align__(128) short Bs[128 * 32];
  int t = threadIdx.x;
  int lane = t & 63, wave = t >> 6;
  int m0 = blockIdx.y * 128, n0 = blockIdx.x * 128;
  int wr = wave >> 1, wc = wave & 1;
  int fr = lane & 15;
  int fk = (lane >> 4) << 3;

  f32x4 acc[4][4] = {};

  int c0 = t, row0 = c0 >> 2, ko0 = (c0 & 3) << 3;
  int c1 = 256 + t, row1 = c1 >> 2, ko1 = (c1 & 3) << 3;
  short* lpA0 = As + (size_t)(wave * 64) * 8;
  short* lpA1 = As + (size_t)(256 + wave * 64) * 8;
  short* lpB0 = Bs + (size_t)(wave * 64) * 8;
  short* lpB1 = Bs + (size_t)(256 + wave * 64) * 8;

  const short* ArdBase = As + ((wr * 64 + fr) * 32 + fk);
  const short* BrdBase = Bs + ((wc * 64 + fr) * 32 + fk);

  const bf16* Ag0 = A + (size_t)(m0 + row0) * K + ko0;
  const bf16* Ag1 = A + (size_t)(m0 + row1) * K + ko1;
  const bf16* Bg0 = Bt + (size_t)(n0 + row0) * K + ko0;
  const bf16* Bg1 = Bt + (size_t)(n0 + row1) * K + ko1;

  int nk = K >> 5;
  for (int kt = 0; kt < nk; ++kt) {
    int k0 = kt << 5;
    GLOAD_LDS16(Ag0 + k0, lpA0);
    GLOAD_LDS16(Ag1 + k0, lpA1);
    GLOAD_LDS16(Bg0 + k0, lpB0);
    GLOAD_LDS16(Bg1 + k0, lpB1);
    __syncthreads();
    bf16x8 af[4], bfv[4];
#pragma unroll
    for (int a = 0; a < 4; ++a) af[a] = *(const bf16x8*)(ArdBase + a * 512);
#pragma unroll
    for (int b = 0; b < 4; ++b) bfv[b] = *(const bf16x8*)(BrdBase + b * 512);
#pragma unroll
    for (int a = 0; a < 4; ++a)
#pragma unroll
      for (int b = 0; b < 4; ++b) mfma16(acc[a][b], af[a], bfv[b]);
    __syncthreads();
  }
  asm volatile("s_nop 7\n\ts_nop 7");
  int lr = (lane >> 4) << 2;
  int lc = lane & 15;
#pragma unroll
  for (int a = 0; a < 4; ++a) {
#pragma unroll
    for (int b = 0; b < 4; ++b) {
      int col = n0 + wc * 64 + b * 16 + lc;
      float bv = 0.0f;
      if constexpr (BIAS) bv = bias[col];
#pragma unroll
      for (int j = 0; j < 4; ++j) {
        int rowi = m0 + wr * 64 + a * 16 + lr + j;
        float v = acc[a][b][j] + bv;
        if constexpr (ACT == 1) v = silu_f(v);
        if constexpr (ACT == 2) v = mish_f(v);
        if constexpr (OUTBF16) Cb[(size_t)rowi * N + col] = __float2bfloat16(v);
        else Cf[(size_t)rowi * N + col] = v;
      }
    }
  }
}

// ---------------- c = x @ sc_w : [8192,1024]f32 @ [1024,32]f32 -> [8192,32]f32 ---------
__global__ __launch_bounds__(256) void c_kernel(const float* __restrict__ x,
                                                const float* __restrict__ scw,
                                                float* __restrict__ cout) {
  __shared__ float Xs[8][1024];
  int t = threadIdx.x;
  int row0 = blockIdx.x * 8;
#pragma unroll
  for (int i = 0; i < 32; ++i) {
    int idx = t + i * 256;
    Xs[idx >> 10][idx & 1023] = x[(size_t)row0 * 1024 + idx];
  }
  __syncthreads();
  int r = t >> 5, n = t & 31;
  float acc = 0.0f;
#pragma unroll 4
  for (int k = 0; k < 1024; ++k) acc += Xs[r][k] * scw[k * 32 + n];
  cout[(size_t)(row0 + r) * 32 + n] = acc;
}

// ---------------- h = LN(silu(c @ sh1_w + b)) : [128,2048]@[2048,256] -> bf16[128,256] -
__global__ __launch_bounds__(256) void h_kernel(const float* __restrict__ c,
                                                const float* __restrict__ w,
                                                const float* __restrict__ bias,
                                                const float* __restrict__ gam,
                                                const float* __restrict__ bet,
                                                bf16* __restrict__ hb) {
  __shared__ float Cs[2048];
  __shared__ float rsm[4], rs2[4], st2[2];
  int t = threadIdx.x, row = blockIdx.x;
#pragma unroll
  for (int i = 0; i < 8; ++i) Cs[t + i * 256] = c[(size_t)row * 2048 + t + i * 256];
  __syncthreads();
  float acc = bias[t];
#pragma unroll 4
  for (int k = 0; k < 2048; ++k) acc += Cs[k] * w[(size_t)k * 256 + t];
  float sv = silu_f(acc);
  float s = sv, s2 = sv * sv;
#pragma unroll
  for (int o = 32; o > 0; o >>= 1) { s += __shfl_down(s, o); s2 += __shfl_down(s2, o); }
  if ((t & 63) == 0) { rsm[t >> 6] = s; rs2[t >> 6] = s2; }
  __syncthreads();
  if (t == 0) {
    float a = rsm[0] + rsm[1] + rsm[2] + rsm[3];
    float b2 = rs2[0] + rs2[1] + rs2[2] + rs2[3];
    float m = a * (1.0f / 256.0f);
    st2[0] = m;
    st2[1] = rsqrtf(b2 * (1.0f / 256.0f) - m * m + LN_EPS);
  }
  __syncthreads();
  float y = (sv - st2[0]) * st2[1] * gam[t] + bet[t];
  hb[(size_t)row * 256 + t] = __float2bfloat16(y);
}

// ---------------- LN over 8192 cols (smolgen g) -> bf16 --------------------------------
__global__ __launch_bounds__(1024) void ln8192_kernel(const float* __restrict__ gpre,
                                                      const float* __restrict__ gam,
                                                      const float* __restrict__ bet,
                                                      bf16* __restrict__ gb) {
  __shared__ float rsm[16], rs2[16], st2[2];
  int t = threadIdx.x, row = blockIdx.x;
  const float* p = gpre + (size_t)row * 8192;
  float v[8];
  float s = 0.0f, s2 = 0.0f;
#pragma unroll
  for (int i = 0; i < 8; ++i) {
    v[i] = p[t + i * 1024];
    s += v[i];
    s2 += v[i] * v[i];
  }
#pragma unroll
  for (int o = 32; o > 0; o >>= 1) { s += __shfl_down(s, o); s2 += __shfl_down(s2, o); }
  int lane = t & 63, w = t >> 6;
  if (lane == 0) { rsm[w] = s; rs2[w] = s2; }
  __syncthreads();
  if (t == 0) {
    float a = 0.0f, b2 = 0.0f;
#pragma unroll
    for (int i = 0; i < 16; ++i) { a += rsm[i]; b2 += rs2[i]; }
    float m = a * (1.0f / 8192.0f);
    st2[0] = m;
    st2[1] = rsqrtf(b2 * (1.0f / 8192.0f) - m * m + LN_EPS);
  }
  __syncthreads();
  float m = st2[0], r = st2[1];
#pragma unroll
  for (int i = 0; i < 8; ++i) {
    int n = t + i * 1024;
    gb[(size_t)row * 8192 + n] = __float2bfloat16((v[i] - m) * r * gam[n] + bet[n]);
  }
}

// ---------------- residual + LN over 1024 cols: out = LN(base + delta*ALPHA) -----------
__global__ __launch_bounds__(256) void ln_residual_kernel(const float* __restrict__ base,
                                                          const float* __restrict__ delta,
                                                          const float* __restrict__ gam,
                                                          const float* __restrict__ bet,
                                                          float* __restrict__ outf,
                                                          bf16* __restrict__ outb) {
  __shared__ float rsm[4], rs2[4], st2[2];
  int t = threadIdx.x, row = blockIdx.x;
  const float* bp = base + (size_t)row * 1024;
  const float* dp = delta + (size_t)row * 1024;
  float v[4];
  float s = 0.0f, s2 = 0.0f;
#pragma unroll
  for (int i = 0; i < 4; ++i) {
    int cc = t + i * 256;
    v[i] = bp[cc] + dp[cc] * ALPHA_F;
    s += v[i];
    s2 += v[i] * v[i];
  }
#pragma unroll
  for (int o = 32; o > 0; o >>= 1) { s += __shfl_down(s, o); s2 += __shfl_down(s2, o); }
  if ((t & 63) == 0) { rsm[t >> 6] = s; rs2[t >> 6] = s2; }
  __syncthreads();
  if (t == 0) {
    float a = rsm[0] + rsm[1] + rsm[2] + rsm[3];
    float b2 = rs2[0] + rs2[1] + rs2[2] + rs2[3];
    float m = a * (1.0f / 1024.0f);
    st2[0] = m;
    st2[1] = rsqrtf(b2 * (1.0f / 1024.0f) - m * m + LN_EPS);
  }
  __syncthreads();
  float m = st2[0], r = st2[1];
  float* of = outf + (size_t)row * 1024;
  bf16* ob = outb + (size_t)row * 1024;
#pragma unroll
  for (int i = 0; i < 4; ++i) {
    int cc = t + i * 256;
    float y = (v[i] - m) * r * gam[cc] + bet[cc];
    of[cc] = y;
    ob[cc] = __float2bfloat16(y);
  }
}

// ---------------- fused attention per (b,h): S=QK^T/sqrt(32)+sw, softmax, AV -----------
__global__ __launch_bounds__(256) void attn_kernel(const bf16* __restrict__ qkv,
                                                   const bf16* __restrict__ sw,
                                                   bf16* __restrict__ avb) {
  __shared__ float Qs[64][33], Ks[64][33], Vs[64][33];
  __shared__ float S[64][65];
  __shared__ float rowr[64];
  int t = threadIdx.x;
  int bh = blockIdx.x;
  int b = bh >> 5, h = bh & 31;
  size_t qbase = (size_t)b * 64 * 3072 + h * 32;
#pragma unroll
  for (int i = 0; i < 8; ++i) {
    int idx = t + i * 256;  // 0..2047
    int q = idx >> 5, d = idx & 31;
    size_t g = qbase + (size_t)q * 3072 + d;
    Qs[q][d] = __bfloat162float(qkv[g]);
    Ks[q][d] = __bfloat162float(qkv[g + 1024]);
    Vs[q][d] = __bfloat162float(qkv[g + 2048]);
  }
  __syncthreads();
  const bf16* swrow = sw + (size_t)bh * 4096;
#pragma unroll
  for (int i = 0; i < 16; ++i) {
    int idx = t + i * 256;
    int q = idx >> 6, k = idx & 63;
    float s = 0.0f;
#pragma unroll
    for (int d = 0; d < 32; ++d) s += Qs[q][d] * Ks[k][d];
    S[q][k] = s * 0.17677669529663687f + __bfloat162float(swrow[idx]);
  }
  __syncthreads();
  // wave-parallel softmax: 4 lanes per row
  {
    int r = t >> 2, sub = t & 3;
    float mx = -1e30f;
#pragma unroll
    for (int kk = 0; kk < 16; ++kk) mx = fmaxf(mx, S[r][sub * 16 + kk]);
    mx = fmaxf(mx, __shfl_xor(mx, 1));
    mx = fmaxf(mx, __shfl_xor(mx, 2));
    float sum = 0.0f;
#pragma unroll
    for (int kk = 0; kk < 16; ++kk) {
      float e = __expf(S[r][sub * 16 + kk] - mx);
      S[r][sub * 16 + kk] = e;
      sum += e;
    }
    sum += __shfl_xor(sum, 1);
    sum += __shfl_xor(sum, 2);
    if (sub == 0) rowr[r] = 1.0f / sum;
  }
  __syncthreads();
#pragma unroll
  for (int i = 0; i < 8; ++i) {
    int idx = t + i * 256;
    int q = idx >> 5, d = idx & 31;
    float rcp = rowr[q];
    float s = 0.0f;
#pragma unroll
    for (int k = 0; k < 64; ++k) s += S[q][k] * Vs[k][d];
    avb[(size_t)(b * 64 + q) * 1024 + h * 32 + d] = __float2bfloat16(s * rcp);
  }
}

extern "C" void kernel_launch(void* const* d_in, const int* in_sizes, int n_in,
                              void* d_out, int out_size, void* d_ws, size_t ws_size,
                              hipStream_t stream) {
  const float* x_in   = (const float*)d_in[0];
  const float* wq_w   = (const float*)d_in[1];
  const float* wq_b   = (const float*)d_in[2];
  const float* wk_w   = (const float*)d_in[3];
  const float* wk_b   = (const float*)d_in[4];
  const float* wv_w   = (const float*)d_in[5];
  const float* wv_b   = (const float*)d_in[6];
  const float* wo_w   = (const float*)d_in[7];
  const float* wo_b   = (const float*)d_in[8];
  const float* sc_w   = (const float*)d_in[9];
  const float* sh1_w  = (const float*)d_in[10];
  const float* sh1_b  = (const float*)d_in[11];
  const float* sln1_g = (const float*)d_in[12];
  const float* sln1_b = (const float*)d_in[13];
  const float* sgf_w  = (const float*)d_in[14];
  const float* sgf_b  = (const float*)d_in[15];
  const float* sln2_g = (const float*)d_in[16];
  const float* sln2_b = (const float*)d_in[17];
  const float* swg_w  = (const float*)d_in[18];
  const float* ffn1_w = (const float*)d_in[19];
  const float* ffn1_b = (const float*)d_in[20];
  const float* ffn2_w = (const float*)d_in[21];
  const float* ffn2_b = (const float*)d_in[22];
  const float* n1_g   = (const float*)d_in[23];
  const float* n1_b   = (const float*)d_in[24];
  const float* n2_g   = (const float*)d_in[25];
  const float* n2_b   = (const float*)d_in[26];

  char* ws = (char*)d_ws;
  size_t off = 0;
  auto alloc = [&](size_t bytes) -> void* {
    void* p = ws + off;
    off += (bytes + 255) & ~(size_t)255;
    return p;
  };
  bf16*  xb    = (bf16*)alloc(8192ULL * 1024 * 2);
  float* P0    = (float*)alloc(8192ULL * 1024 * 4);
  float* P1    = (float*)alloc(8192ULL * 1024 * 4);
  float* Tbuf  = (float*)alloc(8192ULL * 1024 * 4);
  bf16*  Wqkv  = (bf16*)alloc(3072ULL * 1024 * 2);
  float* bqkv  = (float*)alloc(3072ULL * 4);
  bf16*  Wo    = (bf16*)alloc(1024ULL * 1024 * 2);
  bf16*  Wf1   = (bf16*)alloc(1536ULL * 1024 * 2);
  bf16*  Wf2   = (bf16*)alloc(1024ULL * 1536 * 2);
  bf16*  Wsgf  = (bf16*)alloc(8192ULL * 256 * 2);
  bf16*  Wswg  = (bf16*)alloc(4096ULL * 256 * 2);
  bf16*  qkvb  = (bf16*)alloc(8192ULL * 3072 * 2);
  float* cbuf  = (float*)alloc(8192ULL * 32 * 4);
  bf16*  hbb   = (bf16*)alloc(128ULL * 256 * 2);
  float* gpre  = (float*)alloc(128ULL * 8192 * 4);
  bf16*  gbb   = (bf16*)alloc(128ULL * 8192 * 2);
  bf16*  swb   = (bf16*)alloc(4096ULL * 4096 * 2);
  bf16*  avb   = (bf16*)alloc(8192ULL * 1024 * 2);
  bf16*  out1b = (bf16*)alloc(8192ULL * 1024 * 2);
  bf16*  f1b   = (bf16*)alloc(8192ULL * 1536 * 2);
  if (off > ws_size) {
    sentinel_k<<<1, 1, 0, stream>>>((float*)d_out);
    return;
  }

  cvt_f32_bf16_k<<<8192, 256, 0, stream>>>(x_in, xb, 8192LL * 1024);

  for (int l = 0; l < 15; ++l) {
    const float* wq   = wq_w + (size_t)l * 1024 * 1024;
    const float* wk   = wk_w + (size_t)l * 1024 * 1024;
    const float* wv   = wv_w + (size_t)l * 1024 * 1024;
    const float* wo   = wo_w + (size_t)l * 1024 * 1024;
    const float* f1w  = ffn1_w + (size_t)l * 1024 * 1536;
    const float* f2w  = ffn2_w + (size_t)l * 1536 * 1024;
    const float* sgf  = sgf_w + (size_t)l * 256 * 8192;
    const float* swg  = swg_w + (size_t)l * 256 * 4096;
    const float* scw  = sc_w + (size_t)l * 1024 * 32;
    const float* sh1w = sh1_w + (size_t)l * 2048 * 256;

    transpose_layer<<<10240, 256, 0, stream>>>(wq, wk, wv, wo, f1w, f2w, sgf, swg,
                                               Wqkv, Wo, Wf1, Wf2, Wsgf, Wswg);
    pack3_k<<<12, 256, 0, stream>>>(wq_b + l * 1024, wk_b + l * 1024, wv_b + l * 1024, bqkv);

    const float* xc = (l == 0) ? x_in : ((l & 1) ? P0 : P1);
    float* Pout = (l & 1) ? P1 : P0;

    // QKV projection (256^2 pipelined)
    gemm256<0, true, true><<<384, 512, 0, stream>>>(xb, Wqkv, bqkv, nullptr, qkvb,
                                                    8192, 3072, 1024);
    // smolgen chain
    c_kernel<<<1024, 256, 0, stream>>>(xc, scw, cbuf);
    h_kernel<<<128, 256, 0, stream>>>(cbuf, sh1w, sh1_b + l * 256, sln1_g + l * 256,
                                      sln1_b + l * 256, hbb);
    gemm_tn<1, false, true><<<dim3(64, 1), 256, 0, stream>>>(hbb, Wsgf, sgf_b + (size_t)l * 8192,
                                                             gpre, nullptr, 128, 8192, 256);
    ln8192_kernel<<<128, 1024, 0, stream>>>(gpre, sln2_g + (size_t)l * 8192,
                                            sln2_b + (size_t)l * 8192, gbb);
    gemm256<0, true, false><<<256, 512, 0, stream>>>(gbb, Wswg, nullptr, nullptr, swb,
                                                     4096, 4096, 256);
    // attention
    attn_kernel<<<4096, 256, 0, stream>>>(qkvb, swb, avb);
    // output projection + LN1
    gemm_tn<0, false, true><<<dim3(8, 64), 256, 0, stream>>>(avb, Wo, wo_b + l * 1024, Tbuf,
                                                             nullptr, 8192, 1024, 1024);
    ln_residual_kernel<<<8192, 256, 0, stream>>>(xc, Tbuf, n1_g + l * 1024, n1_b + l * 1024,
                                                 Pout, out1b);
    // FFN + LN2
    gemm256<2, true, true><<<192, 512, 0, stream>>>(out1b, Wf1, ffn1_b + l * 1536,
                                                    nullptr, f1b, 8192, 1536, 1024);
    gemm_tn<0, false, true><<<dim3(8, 64), 256, 0, stream>>>(f1b, Wf2, ffn2_b + l * 1024, Tbuf,
                                                             nullptr, 8192, 1024, 1536);
    float* xnext = (l == 14) ? (float*)d_out : Pout;
    ln_residual_kernel<<<8192, 256, 0, stream>>>(Pout, Tbuf, n2_g + l * 1024, n2_b + l * 1024,
                                                 xnext, xb);
  }
}

// Round 4
// 16476.974 us; speedup vs baseline: 1.0148x; 1.0148x over previous
//
#include <hip/hip_runtime.h>
#include <hip/hip_bf16.h>

typedef __attribute__((ext_vector_type(8))) short bf16x8;
typedef __attribute__((ext_vector_type(4))) float f32x4;
typedef __hip_bfloat16 bf16;

#define ALPHA_F 0.42728713f
#define LN_EPS 1e-3f

__device__ __forceinline__ float silu_f(float x) { return x / (1.0f + __expf(-x)); }
__device__ __forceinline__ float mish_f(float x) {
  float sp = (x > 20.0f) ? x : log1pf(__expf(x));
  return x * tanhf(sp);
}

// Builtin MFMA (NOT inline asm): LLVM sees real dataflow -> acc lives in AGPRs.
// R2/R3 lesson: asm-constraint MFMA ("+v"/"+a") defeated SROA; acc went through
// scratch around every MFMA cluster -> 78 TF, MfmaUtil 3%.
#define MFMA16(acc, a, b) \
  (acc) = __builtin_amdgcn_mfma_f32_16x16x32_bf16((a), (b), (acc), 0, 0, 0)

#define GLOAD_LDS16(gp, lp)                                                              \
  __builtin_amdgcn_global_load_lds((__attribute__((address_space(1))) void*)(void*)(gp), \
                                   (__attribute__((address_space(3))) void*)(void*)(lp), \
                                   16, 0, 0)

#define BAR() asm volatile("s_barrier" ::: "memory")

// ---------------- batched per-layer weight transpose: W[K,N] f32 -> Wt[N,K] bf16 -------
__global__ __launch_bounds__(256) void transpose_layer(
    const float* __restrict__ wq, const float* __restrict__ wk, const float* __restrict__ wv,
    const float* __restrict__ wo, const float* __restrict__ f1, const float* __restrict__ f2,
    const float* __restrict__ sgf, const float* __restrict__ swg,
    bf16* __restrict__ Wqkv, bf16* __restrict__ Wo, bf16* __restrict__ Wf1,
    bf16* __restrict__ Wf2, bf16* __restrict__ Wsgf, bf16* __restrict__ Wswg) {
  __shared__ float tile[32][33];
  int b = blockIdx.x;
  const float* W;
  bf16* Wt;
  int K, N, tb;
  if (b < 3072) {
    int m = b >> 10;
    W = (m == 0) ? wq : ((m == 1) ? wk : wv);
    Wt = Wqkv + (size_t)m * 1024 * 1024;
    K = 1024; N = 1024; tb = b & 1023;
  } else if (b < 4096) { W = wo;  Wt = Wo;   K = 1024; N = 1024; tb = b - 3072; }
  else if (b < 5632)   { W = f1;  Wt = Wf1;  K = 1024; N = 1536; tb = b - 4096; }
  else if (b < 7168)   { W = f2;  Wt = Wf2;  K = 1536; N = 1024; tb = b - 5632; }
  else if (b < 9216)   { W = sgf; Wt = Wsgf; K = 256;  N = 8192; tb = b - 7168; }
  else                 { W = swg; Wt = Wswg; K = 256;  N = 4096; tb = b - 9216; }
  int ntx = N >> 5;
  int ty_ = tb / ntx, tx_ = tb - ty_ * ntx;
  int nb = tx_ * 32, kb = ty_ * 32;
  int tx = threadIdx.x & 31, ty = threadIdx.x >> 5;
#pragma unroll
  for (int i = 0; i < 4; ++i)
    tile[ty + i * 8][tx] = W[(size_t)(kb + ty + i * 8) * N + nb + tx];
  __syncthreads();
#pragma unroll
  for (int i = 0; i < 4; ++i)
    Wt[(size_t)(nb + ty + i * 8) * K + kb + tx] = __float2bfloat16(tile[tx][ty + i * 8]);
}

__global__ __launch_bounds__(256) void cvt_f32_bf16_k(const float* __restrict__ in,
                                                      bf16* __restrict__ out, long long n) {
  long long i = ((long long)blockIdx.x * 256 + threadIdx.x) * 4;
  if (i + 3 < n) {
    float4 v = *(const float4*)(in + i);
    out[i + 0] = __float2bfloat16(v.x);
    out[i + 1] = __float2bfloat16(v.y);
    out[i + 2] = __float2bfloat16(v.z);
    out[i + 3] = __float2bfloat16(v.w);
  }
}

__global__ __launch_bounds__(256) void pack3_k(const float* __restrict__ a,
                                               const float* __restrict__ b,
                                               const float* __restrict__ c,
                                               float* __restrict__ o) {
  int i = blockIdx.x * 256 + threadIdx.x;
  if (i < 1024) o[i] = a[i];
  else if (i < 2048) o[i] = b[i - 1024];
  else if (i < 3072) o[i] = c[i - 2048];
}

__global__ __launch_bounds__(1) void sentinel_k(float* __restrict__ o) { o[0] = 1.2345e7f; }

// =======================================================================================
// 256x256-tile phase-pipelined bf16 GEMM: C[M,N] = A[M,K] @ Bt[N,K]^T (+bias, act)
// BK=32, 4-deep LDS ring per operand (128 KiB total), 2 phases/K-tile, counted vmcnt,
// raw s_barrier, setprio around MFMA, XOR-swizzled LDS (inverse-swizzled global source).
// Requires: M%256==0, N%256==0, K%32==0, K/32 >= 4.
// =======================================================================================
template <int ACT, bool OUTBF16, bool BIAS>
__global__ __launch_bounds__(512, 2) void gemm256(const bf16* __restrict__ A,
                                                  const bf16* __restrict__ Bt,
                                                  const float* __restrict__ bias,
                                                  float* __restrict__ Cf,
                                                  bf16* __restrict__ Cb,
                                                  int M, int N, int K) {
  __shared__ __align__(128) short lds[65536];  // A ring: [0,32768) shorts, B ring: [32768,65536)
  const int t = threadIdx.x;
  const int lane = t & 63, wave = t >> 6;
  const int wr = wave >> 2, wc = wave & 3;

  // grid: 1D, XCD-swizzled
  const int nbx = N >> 8, nby = M >> 8;
  int nwg = nbx * nby;
  int bid = blockIdx.x;
  if ((nwg & 7) == 0) bid = (bid & 7) * (nwg >> 3) + (bid >> 3);
  const int by = bid / nbx, bx = bid - by * nbx;
  const int bm0 = by << 8, bn0 = bx << 8;

  const int NT = K >> 5;

  // ---- staging addressing (per thread): phys lds slot p = t&3 holds logical k-slot
  // slog = p ^ ((R>>1)&3); global source pre-inverse-swizzled so swizzled read is linear.
  const int slog8 = (((t & 3) ^ ((t >> 3) & 3)) << 3);  // logical k element offset
  const bf16* Abase = A + (size_t)bm0 * K;
  const bf16* Bbase = Bt + (size_t)bn0 * K;

  auto stageA = [&](int T) {
    int col = (T << 5) + slog8;
#pragma unroll
    for (int j = 0; j < 2; ++j) {
      const bf16* src = Abase + (size_t)(j * 128 + (t >> 2)) * K + col;
      short* dst = lds + ((T & 3) * 8192) + j * 4096 + t * 8;
      GLOAD_LDS16(src, dst);
    }
  };
  auto stageB = [&](int T) {
    int col = (T << 5) + slog8;
#pragma unroll
    for (int j = 0; j < 2; ++j) {
      const bf16* src = Bbase + (size_t)(j * 128 + (t >> 2)) * K + col;
      short* dst = lds + 32768 + ((T & 3) * 8192) + j * 4096 + t * 8;
      GLOAD_LDS16(src, dst);
    }
  };

  // ---- fragment read bases (per lane; swizzle bits constant across frag index)
  const int fr = lane & 15, s = lane >> 4;
  const int scol_sh = ((s ^ ((fr >> 1) & 3)) << 3);  // shorts
  const short* ArdBase = lds + (wr * 128 + fr) * 32 + scol_sh;
  const short* BrdBase = lds + 32768 + (wc * 64 + fr) * 32 + scol_sh;

  f32x4 acc[8][4] = {};

  // ---- prologue: stage units 0..4 = A0,B0,A1,B1,A2; wait for tile 0 (vmcnt 6)
  stageA(0); stageB(0); stageA(1); stageB(1); stageA(2);
  asm volatile("s_waitcnt vmcnt(6)" ::: "memory");
  BAR();

  for (int kt = 0; kt < NT; ++kt) {
    const int slot = (kt & 3) * 8192;
    bf16x8 bfr[4], afr[4];
    // ---- phase 0: read all B + A frags 0..3; stage B(kt+2)
#pragma unroll
    for (int n = 0; n < 4; ++n) bfr[n] = *(const bf16x8*)(BrdBase + slot + n * 512);
#pragma unroll
    for (int q = 0; q < 4; ++q) afr[q] = *(const bf16x8*)(ArdBase + slot + q * 512);
    if (kt + 2 < NT) stageB(kt + 2);
    __builtin_amdgcn_s_setprio(1);
#pragma unroll
    for (int m = 0; m < 4; ++m)
#pragma unroll
      for (int n = 0; n < 4; ++n) MFMA16(acc[m][n], afr[m], bfr[n]);
    __builtin_amdgcn_s_setprio(0);
    BAR();
    // ---- phase 1: read A frags 4..7; stage A(kt+3); counted vmcnt at tile end
#pragma unroll
    for (int q = 0; q < 4; ++q) afr[q] = *(const bf16x8*)(ArdBase + slot + (4 + q) * 512);
    if (kt + 3 < NT) stageA(kt + 3);
    __builtin_amdgcn_s_setprio(1);
#pragma unroll
    for (int m = 0; m < 4; ++m)
#pragma unroll
      for (int n = 0; n < 4; ++n) MFMA16(acc[4 + m][n], afr[m], bfr[n]);
    __builtin_amdgcn_s_setprio(0);
    if (kt < NT - 1) {
      int rem = NT - 2 - kt;
      if (rem >= 2)      asm volatile("s_waitcnt vmcnt(6)" ::: "memory");
      else if (rem == 1) asm volatile("s_waitcnt vmcnt(4)" ::: "memory");
      else               asm volatile("s_waitcnt vmcnt(0)" ::: "memory");
    }
    BAR();
  }

  const int lr4 = (lane >> 4) << 2, lc = lane & 15;
#pragma unroll
  for (int m = 0; m < 8; ++m) {
#pragma unroll
    for (int n = 0; n < 4; ++n) {
      int col = bn0 + wc * 64 + n * 16 + lc;
      float bv = 0.0f;
      if constexpr (BIAS) bv = bias[col];
#pragma unroll
      for (int j = 0; j < 4; ++j) {
        int row = bm0 + wr * 128 + m * 16 + lr4 + j;
        float v = acc[m][n][j] + bv;
        if constexpr (ACT == 1) v = silu_f(v);
        if constexpr (ACT == 2) v = mish_f(v);
        if constexpr (OUTBF16) Cb[(size_t)row * N + col] = __float2bfloat16(v);
        else Cf[(size_t)row * N + col] = v;
      }
    }
  }
}

// ---------------- 128x128 bf16 MFMA GEMM (for 512-block shapes + tiny M) ---------------
template <int ACT, bool OUTBF16, bool BIAS>
__global__ __launch_bounds__(256) void gemm_tn(const bf16* __restrict__ A,
                                               const bf16* __restrict__ Bt,
                                               const float* __restrict__ bias,
                                               float* __restrict__ Cf, bf16* __restrict__ Cb,
                                               int M, int N, int K) {
  __shared__ __align__(128) short As[128 * 32];
  __shared__ __align__(128) short Bs[128 * 32];
  int t = threadIdx.x;
  int lane = t & 63, wave = t >> 6;
  int m0 = blockIdx.y * 128, n0 = blockIdx.x * 128;
  int wr = wave >> 1, wc = wave & 1;
  int fr = lane & 15;
  int fk = (lane >> 4) << 3;

  f32x4 acc[4][4] = {};

  int c0 = t, row0 = c0 >> 2, ko0 = (c0 & 3) << 3;
  int c1 = 256 + t, row1 = c1 >> 2, ko1 = (c1 & 3) << 3;
  short* lpA0 = As + (size_t)(wave * 64) * 8;
  short* lpA1 = As + (size_t)(256 + wave * 64) * 8;
  short* lpB0 = Bs + (size_t)(wave * 64) * 8;
  short* lpB1 = Bs + (size_t)(256 + wave * 64) * 8;

  const short* ArdBase = As + ((wr * 64 + fr) * 32 + fk);
  const short* BrdBase = Bs + ((wc * 64 + fr) * 32 + fk);

  const bf16* Ag0 = A + (size_t)(m0 + row0) * K + ko0;
  const bf16* Ag1 = A + (size_t)(m0 + row1) * K + ko1;
  const bf16* Bg0 = Bt + (size_t)(n0 + row0) * K + ko0;
  const bf16* Bg1 = Bt + (size_t)(n0 + row1) * K + ko1;

  int nk = K >> 5;
  for (int kt = 0; kt < nk; ++kt) {
    int k0 = kt << 5;
    GLOAD_LDS16(Ag0 + k0, lpA0);
    GLOAD_LDS16(Ag1 + k0, lpA1);
    GLOAD_LDS16(Bg0 + k0, lpB0);
    GLOAD_LDS16(Bg1 + k0, lpB1);
    __syncthreads();
    bf16x8 af[4], bfv[4];
#pragma unroll
    for (int a = 0; a < 4; ++a) af[a] = *(const bf16x8*)(ArdBase + a * 512);
#pragma unroll
    for (int b = 0; b < 4; ++b) bfv[b] = *(const bf16x8*)(BrdBase + b * 512);
#pragma unroll
    for (int a = 0; a < 4; ++a)
#pragma unroll
      for (int b = 0; b < 4; ++b) MFMA16(acc[a][b], af[a], bfv[b]);
    __syncthreads();
  }
  int lr = (lane >> 4) << 2;
  int lc = lane & 15;
#pragma unroll
  for (int a = 0; a < 4; ++a) {
#pragma unroll
    for (int b = 0; b < 4; ++b) {
      int col = n0 + wc * 64 + b * 16 + lc;
      float bv = 0.0f;
      if constexpr (BIAS) bv = bias[col];
#pragma unroll
      for (int j = 0; j < 4; ++j) {
        int rowi = m0 + wr * 64 + a * 16 + lr + j;
        float v = acc[a][b][j] + bv;
        if constexpr (ACT == 1) v = silu_f(v);
        if constexpr (ACT == 2) v = mish_f(v);
        if constexpr (OUTBF16) Cb[(size_t)rowi * N + col] = __float2bfloat16(v);
        else Cf[(size_t)rowi * N + col] = v;
      }
    }
  }
}

// ---------------- c = x @ sc_w : [8192,1024]f32 @ [1024,32]f32 -> [8192,32]f32 ---------
__global__ __launch_bounds__(256) void c_kernel(const float* __restrict__ x,
                                                const float* __restrict__ scw,
                                                float* __restrict__ cout) {
  __shared__ float Xs[8][1024];
  int t = threadIdx.x;
  int row0 = blockIdx.x * 8;
#pragma unroll
  for (int i = 0; i < 32; ++i) {
    int idx = t + i * 256;
    Xs[idx >> 10][idx & 1023] = x[(size_t)row0 * 1024 + idx];
  }
  __syncthreads();
  int r = t >> 5, n = t & 31;
  float acc = 0.0f;
#pragma unroll 4
  for (int k = 0; k < 1024; ++k) acc += Xs[r][k] * scw[k * 32 + n];
  cout[(size_t)(row0 + r) * 32 + n] = acc;
}

// ---------------- h = LN(silu(c @ sh1_w + b)) : [128,2048]@[2048,256] -> bf16[128,256] -
__global__ __launch_bounds__(256) void h_kernel(const float* __restrict__ c,
                                                const float* __restrict__ w,
                                                const float* __restrict__ bias,
                                                const float* __restrict__ gam,
                                                const float* __restrict__ bet,
                                                bf16* __restrict__ hb) {
  __shared__ float Cs[2048];
  __shared__ float rsm[4], rs2[4], st2[2];
  int t = threadIdx.x, row = blockIdx.x;
#pragma unroll
  for (int i = 0; i < 8; ++i) Cs[t + i * 256] = c[(size_t)row * 2048 + t + i * 256];
  __syncthreads();
  float acc = bias[t];
#pragma unroll 4
  for (int k = 0; k < 2048; ++k) acc += Cs[k] * w[(size_t)k * 256 + t];
  float sv = silu_f(acc);
  float s = sv, s2 = sv * sv;
#pragma unroll
  for (int o = 32; o > 0; o >>= 1) { s += __shfl_down(s, o); s2 += __shfl_down(s2, o); }
  if ((t & 63) == 0) { rsm[t >> 6] = s; rs2[t >> 6] = s2; }
  __syncthreads();
  if (t == 0) {
    float a = rsm[0] + rsm[1] + rsm[2] + rsm[3];
    float b2 = rs2[0] + rs2[1] + rs2[2] + rs2[3];
    float m = a * (1.0f / 256.0f);
    st2[0] = m;
    st2[1] = rsqrtf(b2 * (1.0f / 256.0f) - m * m + LN_EPS);
  }
  __syncthreads();
  float y = (sv - st2[0]) * st2[1] * gam[t] + bet[t];
  hb[(size_t)row * 256 + t] = __float2bfloat16(y);
}

// ---------------- LN over 8192 cols (smolgen g) -> bf16 --------------------------------
__global__ __launch_bounds__(1024) void ln8192_kernel(const float* __restrict__ gpre,
                                                      const float* __restrict__ gam,
                                                      const float* __restrict__ bet,
                                                      bf16* __restrict__ gb) {
  __shared__ float rsm[16], rs2[16], st2[2];
  int t = threadIdx.x, row = blockIdx.x;
  const float* p = gpre + (size_t)row * 8192;
  float v[8];
  float s = 0.0f, s2 = 0.0f;
#pragma unroll
  for (int i = 0; i < 8; ++i) {
    v[i] = p[t + i * 1024];
    s += v[i];
    s2 += v[i] * v[i];
  }
#pragma unroll
  for (int o = 32; o > 0; o >>= 1) { s += __shfl_down(s, o); s2 += __shfl_down(s2, o); }
  int lane = t & 63, w = t >> 6;
  if (lane == 0) { rsm[w] = s; rs2[w] = s2; }
  __syncthreads();
  if (t == 0) {
    float a = 0.0f, b2 = 0.0f;
#pragma unroll
    for (int i = 0; i < 16; ++i) { a += rsm[i]; b2 += rs2[i]; }
    float m = a * (1.0f / 8192.0f);
    st2[0] = m;
    st2[1] = rsqrtf(b2 * (1.0f / 8192.0f) - m * m + LN_EPS);
  }
  __syncthreads();
  float m = st2[0], r = st2[1];
#pragma unroll
  for (int i = 0; i < 8; ++i) {
    int n = t + i * 1024;
    gb[(size_t)row * 8192 + n] = __float2bfloat16((v[i] - m) * r * gam[n] + bet[n]);
  }
}

// ---------------- residual + LN over 1024 cols: out = LN(base + delta*ALPHA) -----------
__global__ __launch_bounds__(256) void ln_residual_kernel(const float* __restrict__ base,
                                                          const float* __restrict__ delta,
                                                          const float* __restrict__ gam,
                                                          const float* __restrict__ bet,
                                                          float* __restrict__ outf,
                                                          bf16* __restrict__ outb) {
  __shared__ float rsm[4], rs2[4], st2[2];
  int t = threadIdx.x, row = blockIdx.x;
  const float* bp = base + (size_t)row * 1024;
  const float* dp = delta + (size_t)row * 1024;
  float v[4];
  float s = 0.0f, s2 = 0.0f;
#pragma unroll
  for (int i = 0; i < 4; ++i) {
    int cc = t + i * 256;
    v[i] = bp[cc] + dp[cc] * ALPHA_F;
    s += v[i];
    s2 += v[i] * v[i];
  }
#pragma unroll
  for (int o = 32; o > 0; o >>= 1) { s += __shfl_down(s, o); s2 += __shfl_down(s2, o); }
  if ((t & 63) == 0) { rsm[t >> 6] = s; rs2[t >> 6] = s2; }
  __syncthreads();
  if (t == 0) {
    float a = rsm[0] + rsm[1] + rsm[2] + rsm[3];
    float b2 = rs2[0] + rs2[1] + rs2[2] + rs2[3];
    float m = a * (1.0f / 1024.0f);
    st2[0] = m;
    st2[1] = rsqrtf(b2 * (1.0f / 1024.0f) - m * m + LN_EPS);
  }
  __syncthreads();
  float m = st2[0], r = st2[1];
  float* of = outf + (size_t)row * 1024;
  bf16* ob = outb + (size_t)row * 1024;
#pragma unroll
  for (int i = 0; i < 4; ++i) {
    int cc = t + i * 256;
    float y = (v[i] - m) * r * gam[cc] + bet[cc];
    of[cc] = y;
    ob[cc] = __float2bfloat16(y);
  }
}

// ---------------- fused attention per (b,h): S=QK^T/sqrt(32)+sw, softmax, AV -----------
__global__ __launch_bounds__(256) void attn_kernel(const bf16* __restrict__ qkv,
                                                   const bf16* __restrict__ sw,
                                                   bf16* __restrict__ avb) {
  __shared__ float Qs[64][33], Ks[64][33], Vs[64][33];
  __shared__ float S[64][65];
  __shared__ float rowr[64];
  int t = threadIdx.x;
  int bh = blockIdx.x;
  int b = bh >> 5, h = bh & 31;
  size_t qbase = (size_t)b * 64 * 3072 + h * 32;
#pragma unroll
  for (int i = 0; i < 8; ++i) {
    int idx = t + i * 256;  // 0..2047
    int q = idx >> 5, d = idx & 31;
    size_t g = qbase + (size_t)q * 3072 + d;
    Qs[q][d] = __bfloat162float(qkv[g]);
    Ks[q][d] = __bfloat162float(qkv[g + 1024]);
    Vs[q][d] = __bfloat162float(qkv[g + 2048]);
  }
  __syncthreads();
  const bf16* swrow = sw + (size_t)bh * 4096;
#pragma unroll
  for (int i = 0; i < 16; ++i) {
    int idx = t + i * 256;
    int q = idx >> 6, k = idx & 63;
    float s = 0.0f;
#pragma unroll
    for (int d = 0; d < 32; ++d) s += Qs[q][d] * Ks[k][d];
    S[q][k] = s * 0.17677669529663687f + __bfloat162float(swrow[idx]);
  }
  __syncthreads();
  // wave-parallel softmax: 4 lanes per row
  {
    int r = t >> 2, sub = t & 3;
    float mx = -1e30f;
#pragma unroll
    for (int kk = 0; kk < 16; ++kk) mx = fmaxf(mx, S[r][sub * 16 + kk]);
    mx = fmaxf(mx, __shfl_xor(mx, 1));
    mx = fmaxf(mx, __shfl_xor(mx, 2));
    float sum = 0.0f;
#pragma unroll
    for (int kk = 0; kk < 16; ++kk) {
      float e = __expf(S[r][sub * 16 + kk] - mx);
      S[r][sub * 16 + kk] = e;
      sum += e;
    }
    sum += __shfl_xor(sum, 1);
    sum += __shfl_xor(sum, 2);
    if (sub == 0) rowr[r] = 1.0f / sum;
  }
  __syncthreads();
#pragma unroll
  for (int i = 0; i < 8; ++i) {
    int idx = t + i * 256;
    int q = idx >> 5, d = idx & 31;
    float rcp = rowr[q];
    float s = 0.0f;
#pragma unroll
    for (int k = 0; k < 64; ++k) s += S[q][k] * Vs[k][d];
    avb[(size_t)(b * 64 + q) * 1024 + h * 32 + d] = __float2bfloat16(s * rcp);
  }
}

extern "C" void kernel_launch(void* const* d_in, const int* in_sizes, int n_in,
                              void* d_out, int out_size, void* d_ws, size_t ws_size,
                              hipStream_t stream) {
  const float* x_in   = (const float*)d_in[0];
  const float* wq_w   = (const float*)d_in[1];
  const float* wq_b   = (const float*)d_in[2];
  const float* wk_w   = (const float*)d_in[3];
  const float* wk_b   = (const float*)d_in[4];
  const float* wv_w   = (const float*)d_in[5];
  const float* wv_b   = (const float*)d_in[6];
  const float* wo_w   = (const float*)d_in[7];
  const float* wo_b   = (const float*)d_in[8];
  const float* sc_w   = (const float*)d_in[9];
  const float* sh1_w  = (const float*)d_in[10];
  const float* sh1_b  = (const float*)d_in[11];
  const float* sln1_g = (const float*)d_in[12];
  const float* sln1_b = (const float*)d_in[13];
  const float* sgf_w  = (const float*)d_in[14];
  const float* sgf_b  = (const float*)d_in[15];
  const float* sln2_g = (const float*)d_in[16];
  const float* sln2_b = (const float*)d_in[17];
  const float* swg_w  = (const float*)d_in[18];
  const float* ffn1_w = (const float*)d_in[19];
  const float* ffn1_b = (const float*)d_in[20];
  const float* ffn2_w = (const float*)d_in[21];
  const float* ffn2_b = (const float*)d_in[22];
  const float* n1_g   = (const float*)d_in[23];
  const float* n1_b   = (const float*)d_in[24];
  const float* n2_g   = (const float*)d_in[25];
  const float* n2_b   = (const float*)d_in[26];

  char* ws = (char*)d_ws;
  size_t off = 0;
  auto alloc = [&](size_t bytes) -> void* {
    void* p = ws + off;
    off += (bytes + 255) & ~(size_t)255;
    return p;
  };
  bf16*  xb    = (bf16*)alloc(8192ULL * 1024 * 2);
  float* P0    = (float*)alloc(8192ULL * 1024 * 4);
  float* P1    = (float*)alloc(8192ULL * 1024 * 4);
  float* Tbuf  = (float*)alloc(8192ULL * 1024 * 4);
  bf16*  Wqkv  = (bf16*)alloc(3072ULL * 1024 * 2);
  float* bqkv  = (float*)alloc(3072ULL * 4);
  bf16*  Wo    = (bf16*)alloc(1024ULL * 1024 * 2);
  bf16*  Wf1   = (bf16*)alloc(1536ULL * 1024 * 2);
  bf16*  Wf2   = (bf16*)alloc(1024ULL * 1536 * 2);
  bf16*  Wsgf  = (bf16*)alloc(8192ULL * 256 * 2);
  bf16*  Wswg  = (bf16*)alloc(4096ULL * 256 * 2);
  bf16*  qkvb  = (bf16*)alloc(8192ULL * 3072 * 2);
  float* cbuf  = (float*)alloc(8192ULL * 32 * 4);
  bf16*  hbb   = (bf16*)alloc(128ULL * 256 * 2);
  float* gpre  = (float*)alloc(128ULL * 8192 * 4);
  bf16*  gbb   = (bf16*)alloc(128ULL * 8192 * 2);
  bf16*  swb   = (bf16*)alloc(4096ULL * 4096 * 2);
  bf16*  avb   = (bf16*)alloc(8192ULL * 1024 * 2);
  bf16*  out1b = (bf16*)alloc(8192ULL * 1024 * 2);
  bf16*  f1b   = (bf16*)alloc(8192ULL * 1536 * 2);
  if (off > ws_size) {
    sentinel_k<<<1, 1, 0, stream>>>((float*)d_out);
    return;
  }

  cvt_f32_bf16_k<<<8192, 256, 0, stream>>>(x_in, xb, 8192LL * 1024);

  for (int l = 0; l < 15; ++l) {
    const float* wq   = wq_w + (size_t)l * 1024 * 1024;
    const float* wk   = wk_w + (size_t)l * 1024 * 1024;
    const float* wv   = wv_w + (size_t)l * 1024 * 1024;
    const float* wo   = wo_w + (size_t)l * 1024 * 1024;
    const float* f1w  = ffn1_w + (size_t)l * 1024 * 1536;
    const float* f2w  = ffn2_w + (size_t)l * 1536 * 1024;
    const float* sgf  = sgf_w + (size_t)l * 256 * 8192;
    const float* swg  = swg_w + (size_t)l * 256 * 4096;
    const float* scw  = sc_w + (size_t)l * 1024 * 32;
    const float* sh1w = sh1_w + (size_t)l * 2048 * 256;

    transpose_layer<<<10240, 256, 0, stream>>>(wq, wk, wv, wo, f1w, f2w, sgf, swg,
                                               Wqkv, Wo, Wf1, Wf2, Wsgf, Wswg);
    pack3_k<<<12, 256, 0, stream>>>(wq_b + l * 1024, wk_b + l * 1024, wv_b + l * 1024, bqkv);

    const float* xc = (l == 0) ? x_in : ((l & 1) ? P0 : P1);
    float* Pout = (l & 1) ? P1 : P0;

    // QKV projection (256^2 pipelined)
    gemm256<0, true, true><<<384, 512, 0, stream>>>(xb, Wqkv, bqkv, nullptr, qkvb,
                                                    8192, 3072, 1024);
    // smolgen chain
    c_kernel<<<1024, 256, 0, stream>>>(xc, scw, cbuf);
    h_kernel<<<128, 256, 0, stream>>>(cbuf, sh1w, sh1_b + l * 256, sln1_g + l * 256,
                                      sln1_b + l * 256, hbb);
    gemm_tn<1, false, true><<<dim3(64, 1), 256, 0, stream>>>(hbb, Wsgf, sgf_b + (size_t)l * 8192,
                                                             gpre, nullptr, 128, 8192, 256);
    ln8192_kernel<<<128, 1024, 0, stream>>>(gpre, sln2_g + (size_t)l * 8192,
                                            sln2_b + (size_t)l * 8192, gbb);
    gemm256<0, true, false><<<256, 512, 0, stream>>>(gbb, Wswg, nullptr, nullptr, swb,
                                                     4096, 4096, 256);
    // attention
    attn_kernel<<<4096, 256, 0, stream>>>(qkvb, swb, avb);
    // output projection + LN1
    gemm_tn<0, false, true><<<dim3(8, 64), 256, 0, stream>>>(avb, Wo, wo_b + l * 1024, Tbuf,
                                                             nullptr, 8192, 1024, 1024);
    ln_residual_kernel<<<8192, 256, 0, stream>>>(xc, Tbuf, n1_g + l * 1024, n1_b + l * 1024,
                                                 Pout, out1b);
    // FFN + LN2
    gemm256<2, true, true><<<192, 512, 0, stream>>>(out1b, Wf1, ffn1_b + l * 1536,
                                                    nullptr, f1b, 8192, 1536, 1024);
    gemm_tn<0, false, true><<<dim3(8, 64), 256, 0, stream>>>(f1b, Wf2, ffn2_b + l * 1024, Tbuf,
                                                             nullptr, 8192, 1024, 1536);
    float* xnext = (l == 14) ? (float*)d_out : Pout;
    ln_residual_kernel<<<8192, 256, 0, stream>>>(Pout, Tbuf, n2_g + l * 1024, n2_b + l * 1024,
                                                 xnext, xb);
  }
}

// Round 5
// 16424.414 us; speedup vs baseline: 1.0180x; 1.0032x over previous
//
#include <hip/hip_runtime.h>
#include <hip/hip_bf16.h>

typedef __attribute__((ext_vector_type(8))) short bf16x8;
typedef __attribute__((ext_vector_type(4))) float f32x4;
typedef __hip_bfloat16 bf16;

#define ALPHA_F 0.42728713f
#define LN_EPS 1e-3f

__device__ __forceinline__ float silu_f(float x) { return x / (1.0f + __expf(-x)); }
__device__ __forceinline__ float mish_f(float x) {
  float sp = (x > 20.0f) ? x : log1pf(__expf(x));
  return x * tanhf(sp);
}

// Builtin MFMA: LLVM sees real dataflow -> acc lives in AGPRs.
#define MFMA16(acc, a, b) \
  (acc) = __builtin_amdgcn_mfma_f32_16x16x32_bf16((a), (b), (acc), 0, 0, 0)

#define GLOAD_LDS16(gp, lp)                                                              \
  __builtin_amdgcn_global_load_lds((__attribute__((address_space(1))) void*)(void*)(gp), \
                                   (__attribute__((address_space(3))) void*)(void*)(lp), \
                                   16, 0, 0)

// ---------------- batched per-layer weight transpose: W[K,N] f32 -> Wt[N,K] bf16 -------
__global__ __launch_bounds__(256) void transpose_layer(
    const float* __restrict__ wq, const float* __restrict__ wk, const float* __restrict__ wv,
    const float* __restrict__ wo, const float* __restrict__ f1, const float* __restrict__ f2,
    const float* __restrict__ sgf, const float* __restrict__ swg,
    bf16* __restrict__ Wqkv, bf16* __restrict__ Wo, bf16* __restrict__ Wf1,
    bf16* __restrict__ Wf2, bf16* __restrict__ Wsgf, bf16* __restrict__ Wswg) {
  __shared__ float tile[32][33];
  int b = blockIdx.x;
  const float* W;
  bf16* Wt;
  int K, N, tb;
  if (b < 3072) {
    int m = b >> 10;
    W = (m == 0) ? wq : ((m == 1) ? wk : wv);
    Wt = Wqkv + (size_t)m * 1024 * 1024;
    K = 1024; N = 1024; tb = b & 1023;
  } else if (b < 4096) { W = wo;  Wt = Wo;   K = 1024; N = 1024; tb = b - 3072; }
  else if (b < 5632)   { W = f1;  Wt = Wf1;  K = 1024; N = 1536; tb = b - 4096; }
  else if (b < 7168)   { W = f2;  Wt = Wf2;  K = 1536; N = 1024; tb = b - 5632; }
  else if (b < 9216)   { W = sgf; Wt = Wsgf; K = 256;  N = 8192; tb = b - 7168; }
  else                 { W = swg; Wt = Wswg; K = 256;  N = 4096; tb = b - 9216; }
  int ntx = N >> 5;
  int ty_ = tb / ntx, tx_ = tb - ty_ * ntx;
  int nb = tx_ * 32, kb = ty_ * 32;
  int tx = threadIdx.x & 31, ty = threadIdx.x >> 5;
#pragma unroll
  for (int i = 0; i < 4; ++i)
    tile[ty + i * 8][tx] = W[(size_t)(kb + ty + i * 8) * N + nb + tx];
  __syncthreads();
#pragma unroll
  for (int i = 0; i < 4; ++i)
    Wt[(size_t)(nb + ty + i * 8) * K + kb + tx] = __float2bfloat16(tile[tx][ty + i * 8]);
}

__global__ __launch_bounds__(256) void cvt_f32_bf16_k(const float* __restrict__ in,
                                                      bf16* __restrict__ out, long long n) {
  long long i = ((long long)blockIdx.x * 256 + threadIdx.x) * 4;
  if (i + 3 < n) {
    float4 v = *(const float4*)(in + i);
    out[i + 0] = __float2bfloat16(v.x);
    out[i + 1] = __float2bfloat16(v.y);
    out[i + 2] = __float2bfloat16(v.z);
    out[i + 3] = __float2bfloat16(v.w);
  }
}

__global__ __launch_bounds__(256) void pack3_k(const float* __restrict__ a,
                                               const float* __restrict__ b,
                                               const float* __restrict__ c,
                                               float* __restrict__ o) {
  int i = blockIdx.x * 256 + threadIdx.x;
  if (i < 1024) o[i] = a[i];
  else if (i < 2048) o[i] = b[i - 1024];
  else if (i < 3072) o[i] = c[i - 2048];
}

__global__ __launch_bounds__(1) void sentinel_k(float* __restrict__ o) { o[0] = 1.2345e7f; }

// =======================================================================================
// 256x256-tile phase-pipelined bf16 GEMM: C[M,N] = A[M,K] @ Bt[N,K]^T (+bias, act)
// BK=32, 4-deep LDS ring per operand (128 KiB total), 2 phases/K-tile, counted vmcnt,
// builtin s_barrier, setprio around MFMA, XOR-swizzled LDS (inverse-swizzled global src).
// CRITICAL (R4 fix): global_load_lds LDS dst must be WAVE-UNIFORM (HW adds lane*16B);
// a per-lane dst makes LLVM emit a 64-iteration waterfall loop per load (R2-R4: 24k
// cycles/K-tile, MfmaUtil 3%, MFMA-codegen-invariant).
// Requires: M%256==0, N%256==0, K%32==0, K/32 >= 4.
// =======================================================================================
template <int ACT, bool OUTBF16, bool BIAS>
__global__ __launch_bounds__(512, 2) void gemm256(const bf16* __restrict__ A,
                                                  const bf16* __restrict__ Bt,
                                                  const float* __restrict__ bias,
                                                  float* __restrict__ Cf,
                                                  bf16* __restrict__ Cb,
                                                  int M, int N, int K) {
  __shared__ __align__(128) short lds[65536];  // A ring: [0,32768) shorts, B ring: [32768,65536)
  const int t = threadIdx.x;
  const int lane = t & 63, wave = t >> 6;
  const int wr = wave >> 2, wc = wave & 3;

  // grid: 1D, XCD-swizzled
  const int nbx = N >> 8, nby = M >> 8;
  int nwg = nbx * nby;
  int bid = blockIdx.x;
  if ((nwg & 7) == 0) bid = (bid & 7) * (nwg >> 3) + (bid >> 3);
  const int by = bid / nbx, bx = bid - by * nbx;
  const int bm0 = by << 8, bn0 = bx << 8;

  const int NT = K >> 5;

  // ---- staging addressing: phys lds k-octet p = t&3 holds logical octet p^((row>>1)&3);
  // achieved by pre-inverse-swizzling the per-lane GLOBAL source (LDS write stays linear).
  const int slog8 = (((t & 3) ^ ((t >> 3) & 3)) << 3);  // logical k element offset
  const bf16* Abase = A + (size_t)bm0 * K;
  const bf16* Bbase = Bt + (size_t)bn0 * K;

  auto stageA = [&](int T) {
    int col = (T << 5) + slog8;
#pragma unroll
    for (int j = 0; j < 2; ++j) {
      const bf16* src = Abase + (size_t)(j * 128 + (t >> 2)) * K + col;
      short* dst = lds + ((T & 3) * 8192) + j * 4096 + (wave << 9);  // wave-uniform
      GLOAD_LDS16(src, dst);
    }
  };
  auto stageB = [&](int T) {
    int col = (T << 5) + slog8;
#pragma unroll
    for (int j = 0; j < 2; ++j) {
      const bf16* src = Bbase + (size_t)(j * 128 + (t >> 2)) * K + col;
      short* dst = lds + 32768 + ((T & 3) * 8192) + j * 4096 + (wave << 9);  // wave-uniform
      GLOAD_LDS16(src, dst);
    }
  };

  // ---- fragment read bases (per lane; swizzle bits constant across frag index)
  const int fr = lane & 15, s = lane >> 4;
  const int scol_sh = ((s ^ ((fr >> 1) & 3)) << 3);  // shorts
  const short* ArdBase = lds + (wr * 128 + fr) * 32 + scol_sh;
  const short* BrdBase = lds + 32768 + (wc * 64 + fr) * 32 + scol_sh;

  f32x4 acc[8][4] = {};

  // ---- prologue: stage units A0,B0,A1,B1,A2; wait for tile 0 (vmcnt 6)
  stageA(0); stageB(0); stageA(1); stageB(1); stageA(2);
  asm volatile("s_waitcnt vmcnt(6)");
  __builtin_amdgcn_s_barrier();

  for (int kt = 0; kt < NT; ++kt) {
    const int slot = (kt & 3) * 8192;
    bf16x8 bfr[4], afr[4];
    // ---- phase 0: read all B + A frags 0..3; stage B(kt+2)
#pragma unroll
    for (int n = 0; n < 4; ++n) bfr[n] = *(const bf16x8*)(BrdBase + slot + n * 512);
#pragma unroll
    for (int q = 0; q < 4; ++q) afr[q] = *(const bf16x8*)(ArdBase + slot + q * 512);
    if (kt + 2 < NT) stageB(kt + 2);
    __builtin_amdgcn_s_setprio(1);
#pragma unroll
    for (int m = 0; m < 4; ++m)
#pragma unroll
      for (int n = 0; n < 4; ++n) MFMA16(acc[m][n], afr[m], bfr[n]);
    __builtin_amdgcn_s_setprio(0);
    __builtin_amdgcn_s_barrier();
    // ---- phase 1: read A frags 4..7; stage A(kt+3); counted vmcnt at tile end
#pragma unroll
    for (int q = 0; q < 4; ++q) afr[q] = *(const bf16x8*)(ArdBase + slot + (4 + q) * 512);
    if (kt + 3 < NT) stageA(kt + 3);
    __builtin_amdgcn_s_setprio(1);
#pragma unroll
    for (int m = 0; m < 4; ++m)
#pragma unroll
      for (int n = 0; n < 4; ++n) MFMA16(acc[4 + m][n], afr[m], bfr[n]);
    __builtin_amdgcn_s_setprio(0);
    if (kt < NT - 1) {
      int rem = NT - 2 - kt;
      if (rem >= 2)      asm volatile("s_waitcnt vmcnt(6)");
      else if (rem == 1) asm volatile("s_waitcnt vmcnt(4)");
      else               asm volatile("s_waitcnt vmcnt(0)");
    }
    __builtin_amdgcn_s_barrier();
  }

  const int lr4 = (lane >> 4) << 2, lc = lane & 15;
#pragma unroll
  for (int m = 0; m < 8; ++m) {
#pragma unroll
    for (int n = 0; n < 4; ++n) {
      int col = bn0 + wc * 64 + n * 16 + lc;
      float bv = 0.0f;
      if constexpr (BIAS) bv = bias[col];
#pragma unroll
      for (int j = 0; j < 4; ++j) {
        int row = bm0 + wr * 128 + m * 16 + lr4 + j;
        float v = acc[m][n][j] + bv;
        if constexpr (ACT == 1) v = silu_f(v);
        if constexpr (ACT == 2) v = mish_f(v);
        if constexpr (OUTBF16) Cb[(size_t)row * N + col] = __float2bfloat16(v);
        else Cf[(size_t)row * N + col] = v;
      }
    }
  }
}

// ---------------- 128x128 bf16 MFMA GEMM (for 512-block shapes + tiny M) ---------------
template <int ACT, bool OUTBF16, bool BIAS>
__global__ __launch_bounds__(256) void gemm_tn(const bf16* __restrict__ A,
                                               const bf16* __restrict__ Bt,
                                               const float* __restrict__ bias,
                                               float* __restrict__ Cf, bf16* __restrict__ Cb,
                                               int M, int N, int K) {
  __shared__ __align__(128) short As[128 * 32];
  __shared__ __align__(128) short Bs[128 * 32];
  int t = threadIdx.x;
  int lane = t & 63, wave = t >> 6;
  int m0 = blockIdx.y * 128, n0 = blockIdx.x * 128;
  int wr = wave >> 1, wc = wave & 1;
  int fr = lane & 15;
  int fk = (lane >> 4) << 3;

  f32x4 acc[4][4] = {};

  int c0 = t, row0 = c0 >> 2, ko0 = (c0 & 3) << 3;
  int c1 = 256 + t, row1 = c1 >> 2, ko1 = (c1 & 3) << 3;
  short* lpA0 = As + (size_t)(wave * 64) * 8;
  short* lpA1 = As + (size_t)(256 + wave * 64) * 8;
  short* lpB0 = Bs + (size_t)(wave * 64) * 8;
  short* lpB1 = Bs + (size_t)(256 + wave * 64) * 8;

  const short* ArdBase = As + ((wr * 64 + fr) * 32 + fk);
  const short* BrdBase = Bs + ((wc * 64 + fr) * 32 + fk);

  const bf16* Ag0 = A + (size_t)(m0 + row0) * K + ko0;
  const bf16* Ag1 = A + (size_t)(m0 + row1) * K + ko1;
  const bf16* Bg0 = Bt + (size_t)(n0 + row0) * K + ko0;
  const bf16* Bg1 = Bt + (size_t)(n0 + row1) * K + ko1;

  int nk = K >> 5;
  for (int kt = 0; kt < nk; ++kt) {
    int k0 = kt << 5;
    GLOAD_LDS16(Ag0 + k0, lpA0);
    GLOAD_LDS16(Ag1 + k0, lpA1);
    GLOAD_LDS16(Bg0 + k0, lpB0);
    GLOAD_LDS16(Bg1 + k0, lpB1);
    __syncthreads();
    bf16x8 af[4], bfv[4];
#pragma unroll
    for (int a = 0; a < 4; ++a) af[a] = *(const bf16x8*)(ArdBase + a * 512);
#pragma unroll
    for (int b = 0; b < 4; ++b) bfv[b] = *(const bf16x8*)(BrdBase + b * 512);
#pragma unroll
    for (int a = 0; a < 4; ++a)
#pragma unroll
      for (int b = 0; b < 4; ++b) MFMA16(acc[a][b], af[a], bfv[b]);
    __syncthreads();
  }
  int lr = (lane >> 4) << 2;
  int lc = lane & 15;
#pragma unroll
  for (int a = 0; a < 4; ++a) {
#pragma unroll
    for (int b = 0; b < 4; ++b) {
      int col = n0 + wc * 64 + b * 16 + lc;
      float bv = 0.0f;
      if constexpr (BIAS) bv = bias[col];
#pragma unroll
      for (int j = 0; j < 4; ++j) {
        int rowi = m0 + wr * 64 + a * 16 + lr + j;
        float v = acc[a][b][j] + bv;
        if constexpr (ACT == 1) v = silu_f(v);
        if constexpr (ACT == 2) v = mish_f(v);
        if constexpr (OUTBF16) Cb[(size_t)rowi * N + col] = __float2bfloat16(v);
        else Cf[(size_t)rowi * N + col] = v;
      }
    }
  }
}

// ---------------- c = x @ sc_w : [8192,1024]f32 @ [1024,32]f32 -> [8192,32]f32 ---------
__global__ __launch_bounds__(256) void c_kernel(const float* __restrict__ x,
                                                const float* __restrict__ scw,
                                                float* __restrict__ cout) {
  __shared__ float Xs[8][1024];
  int t = threadIdx.x;
  int row0 = blockIdx.x * 8;
#pragma unroll
  for (int i = 0; i < 32; ++i) {
    int idx = t + i * 256;
    Xs[idx >> 10][idx & 1023] = x[(size_t)row0 * 1024 + idx];
  }
  __syncthreads();
  int r = t >> 5, n = t & 31;
  float acc = 0.0f;
#pragma unroll 4
  for (int k = 0; k < 1024; ++k) acc += Xs[r][k] * scw[k * 32 + n];
  cout[(size_t)(row0 + r) * 32 + n] = acc;
}

// ---------------- h = LN(silu(c @ sh1_w + b)) : [128,2048]@[2048,256] -> bf16[128,256] -
__global__ __launch_bounds__(256) void h_kernel(const float* __restrict__ c,
                                                const float* __restrict__ w,
                                                const float* __restrict__ bias,
                                                const float* __restrict__ gam,
                                                const float* __restrict__ bet,
                                                bf16* __restrict__ hb) {
  __shared__ float Cs[2048];
  __shared__ float rsm[4], rs2[4], st2[2];
  int t = threadIdx.x, row = blockIdx.x;
#pragma unroll
  for (int i = 0; i < 8; ++i) Cs[t + i * 256] = c[(size_t)row * 2048 + t + i * 256];
  __syncthreads();
  float acc = bias[t];
#pragma unroll 4
  for (int k = 0; k < 2048; ++k) acc += Cs[k] * w[(size_t)k * 256 + t];
  float sv = silu_f(acc);
  float s = sv, s2 = sv * sv;
#pragma unroll
  for (int o = 32; o > 0; o >>= 1) { s += __shfl_down(s, o); s2 += __shfl_down(s2, o); }
  if ((t & 63) == 0) { rsm[t >> 6] = s; rs2[t >> 6] = s2; }
  __syncthreads();
  if (t == 0) {
    float a = rsm[0] + rsm[1] + rsm[2] + rsm[3];
    float b2 = rs2[0] + rs2[1] + rs2[2] + rs2[3];
    float m = a * (1.0f / 256.0f);
    st2[0] = m;
    st2[1] = rsqrtf(b2 * (1.0f / 256.0f) - m * m + LN_EPS);
  }
  __syncthreads();
  float y = (sv - st2[0]) * st2[1] * gam[t] + bet[t];
  hb[(size_t)row * 256 + t] = __float2bfloat16(y);
}

// ---------------- LN over 8192 cols (smolgen g) -> bf16 --------------------------------
__global__ __launch_bounds__(1024) void ln8192_kernel(const float* __restrict__ gpre,
                                                      const float* __restrict__ gam,
                                                      const float* __restrict__ bet,
                                                      bf16* __restrict__ gb) {
  __shared__ float rsm[16], rs2[16], st2[2];
  int t = threadIdx.x, row = blockIdx.x;
  const float* p = gpre + (size_t)row * 8192;
  float v[8];
  float s = 0.0f, s2 = 0.0f;
#pragma unroll
  for (int i = 0; i < 8; ++i) {
    v[i] = p[t + i * 1024];
    s += v[i];
    s2 += v[i] * v[i];
  }
#pragma unroll
  for (int o = 32; o > 0; o >>= 1) { s += __shfl_down(s, o); s2 += __shfl_down(s2, o); }
  int lane = t & 63, w = t >> 6;
  if (lane == 0) { rsm[w] = s; rs2[w] = s2; }
  __syncthreads();
  if (t == 0) {
    float a = 0.0f, b2 = 0.0f;
#pragma unroll
    for (int i = 0; i < 16; ++i) { a += rsm[i]; b2 += rs2[i]; }
    float m = a * (1.0f / 8192.0f);
    st2[0] = m;
    st2[1] = rsqrtf(b2 * (1.0f / 8192.0f) - m * m + LN_EPS);
  }
  __syncthreads();
  float m = st2[0], r = st2[1];
#pragma unroll
  for (int i = 0; i < 8; ++i) {
    int n = t + i * 1024;
    gb[(size_t)row * 8192 + n] = __float2bfloat16((v[i] - m) * r * gam[n] + bet[n]);
  }
}

// ---------------- residual + LN over 1024 cols: out = LN(base + delta*ALPHA) -----------
__global__ __launch_bounds__(256) void ln_residual_kernel(const float* __restrict__ base,
                                                          const float* __restrict__ delta,
                                                          const float* __restrict__ gam,
                                                          const float* __restrict__ bet,
                                                          float* __restrict__ outf,
                                                          bf16* __restrict__ outb) {
  __shared__ float rsm[4], rs2[4], st2[2];
  int t = threadIdx.x, row = blockIdx.x;
  const float* bp = base + (size_t)row * 1024;
  const float* dp = delta + (size_t)row * 1024;
  float v[4];
  float s = 0.0f, s2 = 0.0f;
#pragma unroll
  for (int i = 0; i < 4; ++i) {
    int cc = t + i * 256;
    v[i] = bp[cc] + dp[cc] * ALPHA_F;
    s += v[i];
    s2 += v[i] * v[i];
  }
#pragma unroll
  for (int o = 32; o > 0; o >>= 1) { s += __shfl_down(s, o); s2 += __shfl_down(s2, o); }
  if ((t & 63) == 0) { rsm[t >> 6] = s; rs2[t >> 6] = s2; }
  __syncthreads();
  if (t == 0) {
    float a = rsm[0] + rsm[1] + rsm[2] + rsm[3];
    float b2 = rs2[0] + rs2[1] + rs2[2] + rs2[3];
    float m = a * (1.0f / 1024.0f);
    st2[0] = m;
    st2[1] = rsqrtf(b2 * (1.0f / 1024.0f) - m * m + LN_EPS);
  }
  __syncthreads();
  float m = st2[0], r = st2[1];
  float* of = outf + (size_t)row * 1024;
  bf16* ob = outb + (size_t)row * 1024;
#pragma unroll
  for (int i = 0; i < 4; ++i) {
    int cc = t + i * 256;
    float y = (v[i] - m) * r * gam[cc] + bet[cc];
    of[cc] = y;
    ob[cc] = __float2bfloat16(y);
  }
}

// ---------------- fused attention per (b,h): S=QK^T/sqrt(32)+sw, softmax, AV -----------
__global__ __launch_bounds__(256) void attn_kernel(const bf16* __restrict__ qkv,
                                                   const bf16* __restrict__ sw,
                                                   bf16* __restrict__ avb) {
  __shared__ float Qs[64][33], Ks[64][33], Vs[64][33];
  __shared__ float S[64][65];
  __shared__ float rowr[64];
  int t = threadIdx.x;
  int bh = blockIdx.x;
  int b = bh >> 5, h = bh & 31;
  size_t qbase = (size_t)b * 64 * 3072 + h * 32;
#pragma unroll
  for (int i = 0; i < 8; ++i) {
    int idx = t + i * 256;  // 0..2047
    int q = idx >> 5, d = idx & 31;
    size_t g = qbase + (size_t)q * 3072 + d;
    Qs[q][d] = __bfloat162float(qkv[g]);
    Ks[q][d] = __bfloat162float(qkv[g + 1024]);
    Vs[q][d] = __bfloat162float(qkv[g + 2048]);
  }
  __syncthreads();
  const bf16* swrow = sw + (size_t)bh * 4096;
#pragma unroll
  for (int i = 0; i < 16; ++i) {
    int idx = t + i * 256;
    int q = idx >> 6, k = idx & 63;
    float s = 0.0f;
#pragma unroll
    for (int d = 0; d < 32; ++d) s += Qs[q][d] * Ks[k][d];
    S[q][k] = s * 0.17677669529663687f + __bfloat162float(swrow[idx]);
  }
  __syncthreads();
  // wave-parallel softmax: 4 lanes per row
  {
    int r = t >> 2, sub = t & 3;
    float mx = -1e30f;
#pragma unroll
    for (int kk = 0; kk < 16; ++kk) mx = fmaxf(mx, S[r][sub * 16 + kk]);
    mx = fmaxf(mx, __shfl_xor(mx, 1));
    mx = fmaxf(mx, __shfl_xor(mx, 2));
    float sum = 0.0f;
#pragma unroll
    for (int kk = 0; kk < 16; ++kk) {
      float e = __expf(S[r][sub * 16 + kk] - mx);
      S[r][sub * 16 + kk] = e;
      sum += e;
    }
    sum += __shfl_xor(sum, 1);
    sum += __shfl_xor(sum, 2);
    if (sub == 0) rowr[r] = 1.0f / sum;
  }
  __syncthreads();
#pragma unroll
  for (int i = 0; i < 8; ++i) {
    int idx = t + i * 256;
    int q = idx >> 5, d = idx & 31;
    float rcp = rowr[q];
    float s = 0.0f;
#pragma unroll
    for (int k = 0; k < 64; ++k) s += S[q][k] * Vs[k][d];
    avb[(size_t)(b * 64 + q) * 1024 + h * 32 + d] = __float2bfloat16(s * rcp);
  }
}

extern "C" void kernel_launch(void* const* d_in, const int* in_sizes, int n_in,
                              void* d_out, int out_size, void* d_ws, size_t ws_size,
                              hipStream_t stream) {
  const float* x_in   = (const float*)d_in[0];
  const float* wq_w   = (const float*)d_in[1];
  const float* wq_b   = (const float*)d_in[2];
  const float* wk_w   = (const float*)d_in[3];
  const float* wk_b   = (const float*)d_in[4];
  const float* wv_w   = (const float*)d_in[5];
  const float* wv_b   = (const float*)d_in[6];
  const float* wo_w   = (const float*)d_in[7];
  const float* wo_b   = (const float*)d_in[8];
  const float* sc_w   = (const float*)d_in[9];
  const float* sh1_w  = (const float*)d_in[10];
  const float* sh1_b  = (const float*)d_in[11];
  const float* sln1_g = (const float*)d_in[12];
  const float* sln1_b = (const float*)d_in[13];
  const float* sgf_w  = (const float*)d_in[14];
  const float* sgf_b  = (const float*)d_in[15];
  const float* sln2_g = (const float*)d_in[16];
  const float* sln2_b = (const float*)d_in[17];
  const float* swg_w  = (const float*)d_in[18];
  const float* ffn1_w = (const float*)d_in[19];
  const float* ffn1_b = (const float*)d_in[20];
  const float* ffn2_w = (const float*)d_in[21];
  const float* ffn2_b = (const float*)d_in[22];
  const float* n1_g   = (const float*)d_in[23];
  const float* n1_b   = (const float*)d_in[24];
  const float* n2_g   = (const float*)d_in[25];
  const float* n2_b   = (const float*)d_in[26];

  char* ws = (char*)d_ws;
  size_t off = 0;
  auto alloc = [&](size_t bytes) -> void* {
    void* p = ws + off;
    off += (bytes + 255) & ~(size_t)255;
    return p;
  };
  bf16*  xb    = (bf16*)alloc(8192ULL * 1024 * 2);
  float* P0    = (float*)alloc(8192ULL * 1024 * 4);
  float* P1    = (float*)alloc(8192ULL * 1024 * 4);
  float* Tbuf  = (float*)alloc(8192ULL * 1024 * 4);
  bf16*  Wqkv  = (bf16*)alloc(3072ULL * 1024 * 2);
  float* bqkv  = (float*)alloc(3072ULL * 4);
  bf16*  Wo    = (bf16*)alloc(1024ULL * 1024 * 2);
  bf16*  Wf1   = (bf16*)alloc(1536ULL * 1024 * 2);
  bf16*  Wf2   = (bf16*)alloc(1024ULL * 1536 * 2);
  bf16*  Wsgf  = (bf16*)alloc(8192ULL * 256 * 2);
  bf16*  Wswg  = (bf16*)alloc(4096ULL * 256 * 2);
  bf16*  qkvb  = (bf16*)alloc(8192ULL * 3072 * 2);
  float* cbuf  = (float*)alloc(8192ULL * 32 * 4);
  bf16*  hbb   = (bf16*)alloc(128ULL * 256 * 2);
  float* gpre  = (float*)alloc(128ULL * 8192 * 4);
  bf16*  gbb   = (bf16*)alloc(128ULL * 8192 * 2);
  bf16*  swb   = (bf16*)alloc(4096ULL * 4096 * 2);
  bf16*  avb   = (bf16*)alloc(8192ULL * 1024 * 2);
  bf16*  out1b = (bf16*)alloc(8192ULL * 1024 * 2);
  bf16*  f1b   = (bf16*)alloc(8192ULL * 1536 * 2);
  if (off > ws_size) {
    sentinel_k<<<1, 1, 0, stream>>>((float*)d_out);
    return;
  }

  cvt_f32_bf16_k<<<8192, 256, 0, stream>>>(x_in, xb, 8192LL * 1024);

  for (int l = 0; l < 15; ++l) {
    const float* wq   = wq_w + (size_t)l * 1024 * 1024;
    const float* wk   = wk_w + (size_t)l * 1024 * 1024;
    const float* wv   = wv_w + (size_t)l * 1024 * 1024;
    const float* wo   = wo_w + (size_t)l * 1024 * 1024;
    const float* f1w  = ffn1_w + (size_t)l * 1024 * 1536;
    const float* f2w  = ffn2_w + (size_t)l * 1536 * 1024;
    const float* sgf  = sgf_w + (size_t)l * 256 * 8192;
    const float* swg  = swg_w + (size_t)l * 256 * 4096;
    const float* scw  = sc_w + (size_t)l * 1024 * 32;
    const float* sh1w = sh1_w + (size_t)l * 2048 * 256;

    transpose_layer<<<10240, 256, 0, stream>>>(wq, wk, wv, wo, f1w, f2w, sgf, swg,
                                               Wqkv, Wo, Wf1, Wf2, Wsgf, Wswg);
    pack3_k<<<12, 256, 0, stream>>>(wq_b + l * 1024, wk_b + l * 1024, wv_b + l * 1024, bqkv);

    const float* xc = (l == 0) ? x_in : ((l & 1) ? P0 : P1);
    float* Pout = (l & 1) ? P1 : P0;

    // QKV projection (256^2 pipelined)
    gemm256<0, true, true><<<384, 512, 0, stream>>>(xb, Wqkv, bqkv, nullptr, qkvb,
                                                    8192, 3072, 1024);
    // smolgen chain
    c_kernel<<<1024, 256, 0, stream>>>(xc, scw, cbuf);
    h_kernel<<<128, 256, 0, stream>>>(cbuf, sh1w, sh1_b + l * 256, sln1_g + l * 256,
                                      sln1_b + l * 256, hbb);
    gemm_tn<1, false, true><<<dim3(64, 1), 256, 0, stream>>>(hbb, Wsgf, sgf_b + (size_t)l * 8192,
                                                             gpre, nullptr, 128, 8192, 256);
    ln8192_kernel<<<128, 1024, 0, stream>>>(gpre, sln2_g + (size_t)l * 8192,
                                            sln2_b + (size_t)l * 8192, gbb);
    gemm256<0, true, false><<<256, 512, 0, stream>>>(gbb, Wswg, nullptr, nullptr, swb,
                                                     4096, 4096, 256);
    // attention
    attn_kernel<<<4096, 256, 0, stream>>>(qkvb, swb, avb);
    // output projection + LN1
    gemm_tn<0, false, true><<<dim3(8, 64), 256, 0, stream>>>(avb, Wo, wo_b + l * 1024, Tbuf,
                                                             nullptr, 8192, 1024, 1024);
    ln_residual_kernel<<<8192, 256, 0, stream>>>(xc, Tbuf, n1_g + l * 1024, n1_b + l * 1024,
                                                 Pout, out1b);
    // FFN + LN2
    gemm256<2, true, true><<<192, 512, 0, stream>>>(out1b, Wf1, ffn1_b + l * 1536,
                                                    nullptr, f1b, 8192, 1536, 1024);
    gemm_tn<0, false, true><<<dim3(8, 64), 256, 0, stream>>>(f1b, Wf2, ffn2_b + l * 1024, Tbuf,
                                                             nullptr, 8192, 1024, 1536);
    float* xnext = (l == 14) ? (float*)d_out : Pout;
    ln_residual_kernel<<<8192, 256, 0, stream>>>(Pout, Tbuf, n2_g + l * 1024, n2_b + l * 1024,
                                                 xnext, xb);
  }
}

// Round 6
// 14506.387 us; speedup vs baseline: 1.1526x; 1.1322x over previous
//
#include <hip/hip_runtime.h>
#include <hip/hip_bf16.h>

typedef __attribute__((ext_vector_type(8))) short bf16x8;
typedef __attribute__((ext_vector_type(4))) float f32x4;
typedef __hip_bfloat16 bf16;

#define ALPHA_F 0.42728713f
#define LN_EPS 1e-3f

__device__ __forceinline__ float silu_f(float x) { return x / (1.0f + __expf(-x)); }
__device__ __forceinline__ float mish_f(float x) {
  float sp = (x > 20.0f) ? x : log1pf(__expf(x));
  return x * tanhf(sp);
}

// Builtin MFMA: LLVM sees real dataflow -> acc lives in AGPRs.
#define MFMA16(acc, a, b) \
  (acc) = __builtin_amdgcn_mfma_f32_16x16x32_bf16((a), (b), (acc), 0, 0, 0)

#define GLOAD_LDS16(gp, lp)                                                              \
  __builtin_amdgcn_global_load_lds((__attribute__((address_space(1))) void*)(void*)(gp), \
                                   (__attribute__((address_space(3))) void*)(void*)(lp), \
                                   16, 0, 0)

// ---------------- batched per-layer weight transpose: W[K,N] f32 -> Wt[N,K] bf16 -------
__global__ __launch_bounds__(256) void transpose_layer(
    const float* __restrict__ wq, const float* __restrict__ wk, const float* __restrict__ wv,
    const float* __restrict__ wo, const float* __restrict__ f1, const float* __restrict__ f2,
    const float* __restrict__ sgf, const float* __restrict__ swg,
    bf16* __restrict__ Wqkv, bf16* __restrict__ Wo, bf16* __restrict__ Wf1,
    bf16* __restrict__ Wf2, bf16* __restrict__ Wsgf, bf16* __restrict__ Wswg) {
  __shared__ float tile[32][33];
  int b = blockIdx.x;
  const float* W;
  bf16* Wt;
  int K, N, tb;
  if (b < 3072) {
    int m = b >> 10;
    W = (m == 0) ? wq : ((m == 1) ? wk : wv);
    Wt = Wqkv + (size_t)m * 1024 * 1024;
    K = 1024; N = 1024; tb = b & 1023;
  } else if (b < 4096) { W = wo;  Wt = Wo;   K = 1024; N = 1024; tb = b - 3072; }
  else if (b < 5632)   { W = f1;  Wt = Wf1;  K = 1024; N = 1536; tb = b - 4096; }
  else if (b < 7168)   { W = f2;  Wt = Wf2;  K = 1536; N = 1024; tb = b - 5632; }
  else if (b < 9216)   { W = sgf; Wt = Wsgf; K = 256;  N = 8192; tb = b - 7168; }
  else                 { W = swg; Wt = Wswg; K = 256;  N = 4096; tb = b - 9216; }
  int ntx = N >> 5;
  int ty_ = tb / ntx, tx_ = tb - ty_ * ntx;
  int nb = tx_ * 32, kb = ty_ * 32;
  int tx = threadIdx.x & 31, ty = threadIdx.x >> 5;
#pragma unroll
  for (int i = 0; i < 4; ++i)
    tile[ty + i * 8][tx] = W[(size_t)(kb + ty + i * 8) * N + nb + tx];
  __syncthreads();
#pragma unroll
  for (int i = 0; i < 4; ++i)
    Wt[(size_t)(nb + ty + i * 8) * K + kb + tx] = __float2bfloat16(tile[tx][ty + i * 8]);
}

__global__ __launch_bounds__(256) void cvt_f32_bf16_k(const float* __restrict__ in,
                                                      bf16* __restrict__ out, long long n) {
  long long i = ((long long)blockIdx.x * 256 + threadIdx.x) * 4;
  if (i + 3 < n) {
    float4 v = *(const float4*)(in + i);
    out[i + 0] = __float2bfloat16(v.x);
    out[i + 1] = __float2bfloat16(v.y);
    out[i + 2] = __float2bfloat16(v.z);
    out[i + 3] = __float2bfloat16(v.w);
  }
}

__global__ __launch_bounds__(256) void pack3_k(const float* __restrict__ a,
                                               const float* __restrict__ b,
                                               const float* __restrict__ c,
                                               float* __restrict__ o) {
  int i = blockIdx.x * 256 + threadIdx.x;
  if (i < 1024) o[i] = a[i];
  else if (i < 2048) o[i] = b[i - 1024];
  else if (i < 3072) o[i] = c[i - 2048];
}

__global__ __launch_bounds__(1) void sentinel_k(float* __restrict__ o) { o[0] = 1.2345e7f; }

// ---------------- 128x128 bf16 MFMA GEMM (m97 structure; THE workhorse) ----------------
// C[M,N] = A[M,K] @ Bt[N,K]^T (+bias, act). Linear monotonic global_load_lds staging:
// per-lane src row=t>>2, kcol=(t&3)*8 -> LDS short addr t*8 (= wave base + lane*16B).
// R5 lesson: gemm256's lane-PERMUTED global src for global_load_lds serialized staging
// (~24k cy/K-tile, codegen-invariant); monotonic staging here runs ~700 TF.
template <int ACT, bool OUTBF16, bool BIAS>
__global__ __launch_bounds__(256) void gemm_tn(const bf16* __restrict__ A,
                                               const bf16* __restrict__ Bt,
                                               const float* __restrict__ bias,
                                               float* __restrict__ Cf, bf16* __restrict__ Cb,
                                               int M, int N, int K) {
  __shared__ __align__(128) short As[128 * 32];
  __shared__ __align__(128) short Bs[128 * 32];
  int t = threadIdx.x;
  int lane = t & 63, wave = t >> 6;
  int m0 = blockIdx.y * 128, n0 = blockIdx.x * 128;
  int wr = wave >> 1, wc = wave & 1;
  int fr = lane & 15;
  int fk = (lane >> 4) << 3;

  f32x4 acc[4][4] = {};

  int row0 = t >> 2, ko0 = (t & 3) << 3;
  int row1 = 64 + (t >> 2), ko1 = ko0;
  short* lpA0 = As + (size_t)(wave * 64) * 8;
  short* lpA1 = As + (size_t)(256 + wave * 64) * 8;
  short* lpB0 = Bs + (size_t)(wave * 64) * 8;
  short* lpB1 = Bs + (size_t)(256 + wave * 64) * 8;

  const short* ArdBase = As + ((wr * 64 + fr) * 32 + fk);
  const short* BrdBase = Bs + ((wc * 64 + fr) * 32 + fk);

  const bf16* Ag0 = A + (size_t)(m0 + row0) * K + ko0;
  const bf16* Ag1 = A + (size_t)(m0 + row1) * K + ko1;
  const bf16* Bg0 = Bt + (size_t)(n0 + row0) * K + ko0;
  const bf16* Bg1 = Bt + (size_t)(n0 + row1) * K + ko1;

  int nk = K >> 5;
  for (int kt = 0; kt < nk; ++kt) {
    int k0 = kt << 5;
    GLOAD_LDS16(Ag0 + k0, lpA0);
    GLOAD_LDS16(Ag1 + k0, lpA1);
    GLOAD_LDS16(Bg0 + k0, lpB0);
    GLOAD_LDS16(Bg1 + k0, lpB1);
    __syncthreads();
    bf16x8 af[4], bfv[4];
#pragma unroll
    for (int a = 0; a < 4; ++a) af[a] = *(const bf16x8*)(ArdBase + a * 512);
#pragma unroll
    for (int b = 0; b < 4; ++b) bfv[b] = *(const bf16x8*)(BrdBase + b * 512);
#pragma unroll
    for (int a = 0; a < 4; ++a)
#pragma unroll
      for (int b = 0; b < 4; ++b) MFMA16(acc[a][b], af[a], bfv[b]);
    __syncthreads();
  }
  int lr = (lane >> 4) << 2;
  int lc = lane & 15;
#pragma unroll
  for (int a = 0; a < 4; ++a) {
#pragma unroll
    for (int b = 0; b < 4; ++b) {
      int col = n0 + wc * 64 + b * 16 + lc;
      float bv = 0.0f;
      if constexpr (BIAS) bv = bias[col];
#pragma unroll
      for (int j = 0; j < 4; ++j) {
        int rowi = m0 + wr * 64 + a * 16 + lr + j;
        float v = acc[a][b][j] + bv;
        if constexpr (ACT == 1) v = silu_f(v);
        if constexpr (ACT == 2) v = mish_f(v);
        if constexpr (OUTBF16) Cb[(size_t)rowi * N + col] = __float2bfloat16(v);
        else Cf[(size_t)rowi * N + col] = v;
      }
    }
  }
}

// ---------------- c = x @ sc_w : [8192,1024]f32 @ [1024,32]f32 -> [8192,32]f32 ---------
__global__ __launch_bounds__(256) void c_kernel(const float* __restrict__ x,
                                                const float* __restrict__ scw,
                                                float* __restrict__ cout) {
  __shared__ float Xs[8][1024];
  int t = threadIdx.x;
  int row0 = blockIdx.x * 8;
#pragma unroll
  for (int i = 0; i < 32; ++i) {
    int idx = t + i * 256;
    Xs[idx >> 10][idx & 1023] = x[(size_t)row0 * 1024 + idx];
  }
  __syncthreads();
  int r = t >> 5, n = t & 31;
  float acc = 0.0f;
#pragma unroll 4
  for (int k = 0; k < 1024; ++k) acc += Xs[r][k] * scw[k * 32 + n];
  cout[(size_t)(row0 + r) * 32 + n] = acc;
}

// ---------------- h = LN(silu(c @ sh1_w + b)) : [128,2048]@[2048,256] -> bf16[128,256] -
__global__ __launch_bounds__(256) void h_kernel(const float* __restrict__ c,
                                                const float* __restrict__ w,
                                                const float* __restrict__ bias,
                                                const float* __restrict__ gam,
                                                const float* __restrict__ bet,
                                                bf16* __restrict__ hb) {
  __shared__ float Cs[2048];
  __shared__ float rsm[4], rs2[4], st2[2];
  int t = threadIdx.x, row = blockIdx.x;
#pragma unroll
  for (int i = 0; i < 8; ++i) Cs[t + i * 256] = c[(size_t)row * 2048 + t + i * 256];
  __syncthreads();
  float acc = bias[t];
#pragma unroll 4
  for (int k = 0; k < 2048; ++k) acc += Cs[k] * w[(size_t)k * 256 + t];
  float sv = silu_f(acc);
  float s = sv, s2 = sv * sv;
#pragma unroll
  for (int o = 32; o > 0; o >>= 1) { s += __shfl_down(s, o); s2 += __shfl_down(s2, o); }
  if ((t & 63) == 0) { rsm[t >> 6] = s; rs2[t >> 6] = s2; }
  __syncthreads();
  if (t == 0) {
    float a = rsm[0] + rsm[1] + rsm[2] + rsm[3];
    float b2 = rs2[0] + rs2[1] + rs2[2] + rs2[3];
    float m = a * (1.0f / 256.0f);
    st2[0] = m;
    st2[1] = rsqrtf(b2 * (1.0f / 256.0f) - m * m + LN_EPS);
  }
  __syncthreads();
  float y = (sv - st2[0]) * st2[1] * gam[t] + bet[t];
  hb[(size_t)row * 256 + t] = __float2bfloat16(y);
}

// ---------------- LN over 8192 cols (smolgen g) -> bf16 --------------------------------
__global__ __launch_bounds__(1024) void ln8192_kernel(const float* __restrict__ gpre,
                                                      const float* __restrict__ gam,
                                                      const float* __restrict__ bet,
                                                      bf16* __restrict__ gb) {
  __shared__ float rsm[16], rs2[16], st2[2];
  int t = threadIdx.x, row = blockIdx.x;
  const float* p = gpre + (size_t)row * 8192;
  float v[8];
  float s = 0.0f, s2 = 0.0f;
#pragma unroll
  for (int i = 0; i < 8; ++i) {
    v[i] = p[t + i * 1024];
    s += v[i];
    s2 += v[i] * v[i];
  }
#pragma unroll
  for (int o = 32; o > 0; o >>= 1) { s += __shfl_down(s, o); s2 += __shfl_down(s2, o); }
  int lane = t & 63, w = t >> 6;
  if (lane == 0) { rsm[w] = s; rs2[w] = s2; }
  __syncthreads();
  if (t == 0) {
    float a = 0.0f, b2 = 0.0f;
#pragma unroll
    for (int i = 0; i < 16; ++i) { a += rsm[i]; b2 += rs2[i]; }
    float m = a * (1.0f / 8192.0f);
    st2[0] = m;
    st2[1] = rsqrtf(b2 * (1.0f / 8192.0f) - m * m + LN_EPS);
  }
  __syncthreads();
  float m = st2[0], r = st2[1];
#pragma unroll
  for (int i = 0; i < 8; ++i) {
    int n = t + i * 1024;
    gb[(size_t)row * 8192 + n] = __float2bfloat16((v[i] - m) * r * gam[n] + bet[n]);
  }
}

// ---------------- residual + LN over 1024 cols: out = LN(base + delta*ALPHA) -----------
__global__ __launch_bounds__(256) void ln_residual_kernel(const float* __restrict__ base,
                                                          const float* __restrict__ delta,
                                                          const float* __restrict__ gam,
                                                          const float* __restrict__ bet,
                                                          float* __restrict__ outf,
                                                          bf16* __restrict__ outb) {
  __shared__ float rsm[4], rs2[4], st2[2];
  int t = threadIdx.x, row = blockIdx.x;
  const float* bp = base + (size_t)row * 1024;
  const float* dp = delta + (size_t)row * 1024;
  float v[4];
  float s = 0.0f, s2 = 0.0f;
#pragma unroll
  for (int i = 0; i < 4; ++i) {
    int cc = t + i * 256;
    v[i] = bp[cc] + dp[cc] * ALPHA_F;
    s += v[i];
    s2 += v[i] * v[i];
  }
#pragma unroll
  for (int o = 32; o > 0; o >>= 1) { s += __shfl_down(s, o); s2 += __shfl_down(s2, o); }
  if ((t & 63) == 0) { rsm[t >> 6] = s; rs2[t >> 6] = s2; }
  __syncthreads();
  if (t == 0) {
    float a = rsm[0] + rsm[1] + rsm[2] + rsm[3];
    float b2 = rs2[0] + rs2[1] + rs2[2] + rs2[3];
    float m = a * (1.0f / 1024.0f);
    st2[0] = m;
    st2[1] = rsqrtf(b2 * (1.0f / 1024.0f) - m * m + LN_EPS);
  }
  __syncthreads();
  float m = st2[0], r = st2[1];
  float* of = outf + (size_t)row * 1024;
  bf16* ob = outb + (size_t)row * 1024;
#pragma unroll
  for (int i = 0; i < 4; ++i) {
    int cc = t + i * 256;
    float y = (v[i] - m) * r * gam[cc] + bet[cc];
    of[cc] = y;
    ob[cc] = __float2bfloat16(y);
  }
}

// ---------------- fused attention per (b,h): S=QK^T/sqrt(32)+sw, softmax, AV -----------
__global__ __launch_bounds__(256) void attn_kernel(const bf16* __restrict__ qkv,
                                                   const bf16* __restrict__ sw,
                                                   bf16* __restrict__ avb) {
  __shared__ float Qs[64][33], Ks[64][33], Vs[64][33];
  __shared__ float S[64][65];
  __shared__ float rowr[64];
  int t = threadIdx.x;
  int bh = blockIdx.x;
  int b = bh >> 5, h = bh & 31;
  size_t qbase = (size_t)b * 64 * 3072 + h * 32;
#pragma unroll
  for (int i = 0; i < 8; ++i) {
    int idx = t + i * 256;  // 0..2047
    int q = idx >> 5, d = idx & 31;
    size_t g = qbase + (size_t)q * 3072 + d;
    Qs[q][d] = __bfloat162float(qkv[g]);
    Ks[q][d] = __bfloat162float(qkv[g + 1024]);
    Vs[q][d] = __bfloat162float(qkv[g + 2048]);
  }
  __syncthreads();
  const bf16* swrow = sw + (size_t)bh * 4096;
#pragma unroll
  for (int i = 0; i < 16; ++i) {
    int idx = t + i * 256;
    int q = idx >> 6, k = idx & 63;
    float s = 0.0f;
#pragma unroll
    for (int d = 0; d < 32; ++d) s += Qs[q][d] * Ks[k][d];
    S[q][k] = s * 0.17677669529663687f + __bfloat162float(swrow[idx]);
  }
  __syncthreads();
  // wave-parallel softmax: 4 lanes per row
  {
    int r = t >> 2, sub = t & 3;
    float mx = -1e30f;
#pragma unroll
    for (int kk = 0; kk < 16; ++kk) mx = fmaxf(mx, S[r][sub * 16 + kk]);
    mx = fmaxf(mx, __shfl_xor(mx, 1));
    mx = fmaxf(mx, __shfl_xor(mx, 2));
    float sum = 0.0f;
#pragma unroll
    for (int kk = 0; kk < 16; ++kk) {
      float e = __expf(S[r][sub * 16 + kk] - mx);
      S[r][sub * 16 + kk] = e;
      sum += e;
    }
    sum += __shfl_xor(sum, 1);
    sum += __shfl_xor(sum, 2);
    if (sub == 0) rowr[r] = 1.0f / sum;
  }
  __syncthreads();
#pragma unroll
  for (int i = 0; i < 8; ++i) {
    int idx = t + i * 256;
    int q = idx >> 5, d = idx & 31;
    float rcp = rowr[q];
    float s = 0.0f;
#pragma unroll
    for (int k = 0; k < 64; ++k) s += S[q][k] * Vs[k][d];
    avb[(size_t)(b * 64 + q) * 1024 + h * 32 + d] = __float2bfloat16(s * rcp);
  }
}

extern "C" void kernel_launch(void* const* d_in, const int* in_sizes, int n_in,
                              void* d_out, int out_size, void* d_ws, size_t ws_size,
                              hipStream_t stream) {
  const float* x_in   = (const float*)d_in[0];
  const float* wq_w   = (const float*)d_in[1];
  const float* wq_b   = (const float*)d_in[2];
  const float* wk_w   = (const float*)d_in[3];
  const float* wk_b   = (const float*)d_in[4];
  const float* wv_w   = (const float*)d_in[5];
  const float* wv_b   = (const float*)d_in[6];
  const float* wo_w   = (const float*)d_in[7];
  const float* wo_b   = (const float*)d_in[8];
  const float* sc_w   = (const float*)d_in[9];
  const float* sh1_w  = (const float*)d_in[10];
  const float* sh1_b  = (const float*)d_in[11];
  const float* sln1_g = (const float*)d_in[12];
  const float* sln1_b = (const float*)d_in[13];
  const float* sgf_w  = (const float*)d_in[14];
  const float* sgf_b  = (const float*)d_in[15];
  const float* sln2_g = (const float*)d_in[16];
  const float* sln2_b = (const float*)d_in[17];
  const float* swg_w  = (const float*)d_in[18];
  const float* ffn1_w = (const float*)d_in[19];
  const float* ffn1_b = (const float*)d_in[20];
  const float* ffn2_w = (const float*)d_in[21];
  const float* ffn2_b = (const float*)d_in[22];
  const float* n1_g   = (const float*)d_in[23];
  const float* n1_b   = (const float*)d_in[24];
  const float* n2_g   = (const float*)d_in[25];
  const float* n2_b   = (const float*)d_in[26];

  char* ws = (char*)d_ws;
  size_t off = 0;
  auto alloc = [&](size_t bytes) -> void* {
    void* p = ws + off;
    off += (bytes + 255) & ~(size_t)255;
    return p;
  };
  bf16*  xb    = (bf16*)alloc(8192ULL * 1024 * 2);
  float* P0    = (float*)alloc(8192ULL * 1024 * 4);
  float* P1    = (float*)alloc(8192ULL * 1024 * 4);
  float* Tbuf  = (float*)alloc(8192ULL * 1024 * 4);
  bf16*  Wqkv  = (bf16*)alloc(3072ULL * 1024 * 2);
  float* bqkv  = (float*)alloc(3072ULL * 4);
  bf16*  Wo    = (bf16*)alloc(1024ULL * 1024 * 2);
  bf16*  Wf1   = (bf16*)alloc(1536ULL * 1024 * 2);
  bf16*  Wf2   = (bf16*)alloc(1024ULL * 1536 * 2);
  bf16*  Wsgf  = (bf16*)alloc(8192ULL * 256 * 2);
  bf16*  Wswg  = (bf16*)alloc(4096ULL * 256 * 2);
  bf16*  qkvb  = (bf16*)alloc(8192ULL * 3072 * 2);
  float* cbuf  = (float*)alloc(8192ULL * 32 * 4);
  bf16*  hbb   = (bf16*)alloc(128ULL * 256 * 2);
  float* gpre  = (float*)alloc(128ULL * 8192 * 4);
  bf16*  gbb   = (bf16*)alloc(128ULL * 8192 * 2);
  bf16*  swb   = (bf16*)alloc(4096ULL * 4096 * 2);
  bf16*  avb   = (bf16*)alloc(8192ULL * 1024 * 2);
  bf16*  out1b = (bf16*)alloc(8192ULL * 1024 * 2);
  bf16*  f1b   = (bf16*)alloc(8192ULL * 1536 * 2);
  if (off > ws_size) {
    sentinel_k<<<1, 1, 0, stream>>>((float*)d_out);
    return;
  }

  cvt_f32_bf16_k<<<8192, 256, 0, stream>>>(x_in, xb, 8192LL * 1024);

  for (int l = 0; l < 15; ++l) {
    const float* wq   = wq_w + (size_t)l * 1024 * 1024;
    const float* wk   = wk_w + (size_t)l * 1024 * 1024;
    const float* wv   = wv_w + (size_t)l * 1024 * 1024;
    const float* wo   = wo_w + (size_t)l * 1024 * 1024;
    const float* f1w  = ffn1_w + (size_t)l * 1024 * 1536;
    const float* f2w  = ffn2_w + (size_t)l * 1536 * 1024;
    const float* sgf  = sgf_w + (size_t)l * 256 * 8192;
    const float* swg  = swg_w + (size_t)l * 256 * 4096;
    const float* scw  = sc_w + (size_t)l * 1024 * 32;
    const float* sh1w = sh1_w + (size_t)l * 2048 * 256;

    transpose_layer<<<10240, 256, 0, stream>>>(wq, wk, wv, wo, f1w, f2w, sgf, swg,
                                               Wqkv, Wo, Wf1, Wf2, Wsgf, Wswg);
    pack3_k<<<12, 256, 0, stream>>>(wq_b + l * 1024, wk_b + l * 1024, wv_b + l * 1024, bqkv);

    const float* xc = (l == 0) ? x_in : ((l & 1) ? P0 : P1);
    float* Pout = (l & 1) ? P1 : P0;

    // QKV projection
    gemm_tn<0, true, true><<<dim3(24, 64), 256, 0, stream>>>(xb, Wqkv, bqkv, nullptr, qkvb,
                                                             8192, 3072, 1024);
    // smolgen chain
    c_kernel<<<1024, 256, 0, stream>>>(xc, scw, cbuf);
    h_kernel<<<128, 256, 0, stream>>>(cbuf, sh1w, sh1_b + l * 256, sln1_g + l * 256,
                                      sln1_b + l * 256, hbb);
    gemm_tn<1, false, true><<<dim3(64, 1), 256, 0, stream>>>(hbb, Wsgf, sgf_b + (size_t)l * 8192,
                                                             gpre, nullptr, 128, 8192, 256);
    ln8192_kernel<<<128, 1024, 0, stream>>>(gpre, sln2_g + (size_t)l * 8192,
                                            sln2_b + (size_t)l * 8192, gbb);
    gemm_tn<0, true, false><<<dim3(32, 32), 256, 0, stream>>>(gbb, Wswg, nullptr, nullptr, swb,
                                                              4096, 4096, 256);
    // attention
    attn_kernel<<<4096, 256, 0, stream>>>(qkvb, swb, avb);
    // output projection + LN1
    gemm_tn<0, false, true><<<dim3(8, 64), 256, 0, stream>>>(avb, Wo, wo_b + l * 1024, Tbuf,
                                                             nullptr, 8192, 1024, 1024);
    ln_residual_kernel<<<8192, 256, 0, stream>>>(xc, Tbuf, n1_g + l * 1024, n1_b + l * 1024,
                                                 Pout, out1b);
    // FFN + LN2
    gemm_tn<2, true, true><<<dim3(12, 64), 256, 0, stream>>>(out1b, Wf1, ffn1_b + l * 1536,
                                                             nullptr, f1b, 8192, 1536, 1024);
    gemm_tn<0, false, true><<<dim3(8, 64), 256, 0, stream>>>(f1b, Wf2, ffn2_b + l * 1024, Tbuf,
                                                             nullptr, 8192, 1024, 1536);
    float* xnext = (l == 14) ? (float*)d_out : Pout;
    ln_residual_kernel<<<8192, 256, 0, stream>>>(Pout, Tbuf, n2_g + l * 1024, n2_b + l * 1024,
                                                 xnext, xb);
  }
}

// Round 7
// 11443.266 us; speedup vs baseline: 1.4612x; 1.2677x over previous
//
#include <hip/hip_runtime.h>
#include <hip/hip_bf16.h>

typedef __attribute__((ext_vector_type(8))) short bf16x8;
typedef __attribute__((ext_vector_type(4))) float f32x4;
typedef __hip_bfloat16 bf16;

#define ALPHA_F 0.42728713f
#define LN_EPS 1e-3f

__device__ __forceinline__ float silu_f(float x) { return x / (1.0f + __expf(-x)); }
__device__ __forceinline__ float mish_f(float x) {
  float sp = (x > 20.0f) ? x : log1pf(__expf(x));
  return x * tanhf(sp);
}
__device__ __forceinline__ unsigned short f2bfu(float x) {
  bf16 h = __float2bfloat16(x);
  return *(unsigned short*)&h;
}

// Builtin MFMA: LLVM sees real dataflow -> acc lives in AGPRs.
#define MFMA16(acc, a, b) \
  (acc) = __builtin_amdgcn_mfma_f32_16x16x32_bf16((a), (b), (acc), 0, 0, 0)

#define GLOAD_LDS16(gp, lp)                                                              \
  __builtin_amdgcn_global_load_lds((__attribute__((address_space(1))) void*)(void*)(gp), \
                                   (__attribute__((address_space(3))) void*)(void*)(lp), \
                                   16, 0, 0)

// ---------------- batched per-layer weight transpose: W[K,N] f32 -> Wt[N,K] bf16 -------
__global__ __launch_bounds__(256) void transpose_layer(
    const float* __restrict__ wq, const float* __restrict__ wk, const float* __restrict__ wv,
    const float* __restrict__ wo, const float* __restrict__ f1, const float* __restrict__ f2,
    const float* __restrict__ sgf, const float* __restrict__ swg,
    bf16* __restrict__ Wqkv, bf16* __restrict__ Wo, bf16* __restrict__ Wf1,
    bf16* __restrict__ Wf2, bf16* __restrict__ Wsgf, bf16* __restrict__ Wswg) {
  __shared__ float tile[32][33];
  int b = blockIdx.x;
  const float* W;
  bf16* Wt;
  int K, N, tb;
  if (b < 3072) {
    int m = b >> 10;
    W = (m == 0) ? wq : ((m == 1) ? wk : wv);
    Wt = Wqkv + (size_t)m * 1024 * 1024;
    K = 1024; N = 1024; tb = b & 1023;
  } else if (b < 4096) { W = wo;  Wt = Wo;   K = 1024; N = 1024; tb = b - 3072; }
  else if (b < 5632)   { W = f1;  Wt = Wf1;  K = 1024; N = 1536; tb = b - 4096; }
  else if (b < 7168)   { W = f2;  Wt = Wf2;  K = 1536; N = 1024; tb = b - 5632; }
  else if (b < 9216)   { W = sgf; Wt = Wsgf; K = 256;  N = 8192; tb = b - 7168; }
  else                 { W = swg; Wt = Wswg; K = 256;  N = 4096; tb = b - 9216; }
  int ntx = N >> 5;
  int ty_ = tb / ntx, tx_ = tb - ty_ * ntx;
  int nb = tx_ * 32, kb = ty_ * 32;
  int tx = threadIdx.x & 31, ty = threadIdx.x >> 5;
#pragma unroll
  for (int i = 0; i < 4; ++i)
    tile[ty + i * 8][tx] = W[(size_t)(kb + ty + i * 8) * N + nb + tx];
  __syncthreads();
#pragma unroll
  for (int i = 0; i < 4; ++i)
    Wt[(size_t)(nb + ty + i * 8) * K + kb + tx] = __float2bfloat16(tile[tx][ty + i * 8]);
}

__global__ __launch_bounds__(256) void cvt_f32_bf16_k(const float* __restrict__ in,
                                                      bf16* __restrict__ out, long long n) {
  long long i = ((long long)blockIdx.x * 256 + threadIdx.x) * 4;
  if (i + 3 < n) {
    float4 v = *(const float4*)(in + i);
    out[i + 0] = __float2bfloat16(v.x);
    out[i + 1] = __float2bfloat16(v.y);
    out[i + 2] = __float2bfloat16(v.z);
    out[i + 3] = __float2bfloat16(v.w);
  }
}

__global__ __launch_bounds__(256) void pack3_k(const float* __restrict__ a,
                                               const float* __restrict__ b,
                                               const float* __restrict__ c,
                                               float* __restrict__ o) {
  int i = blockIdx.x * 256 + threadIdx.x;
  if (i < 1024) o[i] = a[i];
  else if (i < 2048) o[i] = b[i - 1024];
  else if (i < 3072) o[i] = c[i - 2048];
}

__global__ __launch_bounds__(1) void sentinel_k(float* __restrict__ o) { o[0] = 1.2345e7f; }

// ---------------- 128x128 bf16 MFMA GEMM (m97 structure; THE workhorse) ----------------
template <int ACT, bool OUTBF16, bool BIAS>
__global__ __launch_bounds__(256) void gemm_tn(const bf16* __restrict__ A,
                                               const bf16* __restrict__ Bt,
                                               const float* __restrict__ bias,
                                               float* __restrict__ Cf, bf16* __restrict__ Cb,
                                               int M, int N, int K) {
  __shared__ __align__(128) short As[128 * 32];
  __shared__ __align__(128) short Bs[128 * 32];
  int t = threadIdx.x;
  int lane = t & 63, wave = t >> 6;
  int m0 = blockIdx.y * 128, n0 = blockIdx.x * 128;
  int wr = wave >> 1, wc = wave & 1;
  int fr = lane & 15;
  int fk = (lane >> 4) << 3;

  f32x4 acc[4][4] = {};

  int row0 = t >> 2, ko0 = (t & 3) << 3;
  int row1 = 64 + (t >> 2), ko1 = ko0;
  short* lpA0 = As + (size_t)(wave * 64) * 8;
  short* lpA1 = As + (size_t)(256 + wave * 64) * 8;
  short* lpB0 = Bs + (size_t)(wave * 64) * 8;
  short* lpB1 = Bs + (size_t)(256 + wave * 64) * 8;

  const short* ArdBase = As + ((wr * 64 + fr) * 32 + fk);
  const short* BrdBase = Bs + ((wc * 64 + fr) * 32 + fk);

  const bf16* Ag0 = A + (size_t)(m0 + row0) * K + ko0;
  const bf16* Ag1 = A + (size_t)(m0 + row1) * K + ko1;
  const bf16* Bg0 = Bt + (size_t)(n0 + row0) * K + ko0;
  const bf16* Bg1 = Bt + (size_t)(n0 + row1) * K + ko1;

  int nk = K >> 5;
  for (int kt = 0; kt < nk; ++kt) {
    int k0 = kt << 5;
    GLOAD_LDS16(Ag0 + k0, lpA0);
    GLOAD_LDS16(Ag1 + k0, lpA1);
    GLOAD_LDS16(Bg0 + k0, lpB0);
    GLOAD_LDS16(Bg1 + k0, lpB1);
    __syncthreads();
    bf16x8 af[4], bfv[4];
#pragma unroll
    for (int a = 0; a < 4; ++a) af[a] = *(const bf16x8*)(ArdBase + a * 512);
#pragma unroll
    for (int b = 0; b < 4; ++b) bfv[b] = *(const bf16x8*)(BrdBase + b * 512);
#pragma unroll
    for (int a = 0; a < 4; ++a)
#pragma unroll
      for (int b = 0; b < 4; ++b) MFMA16(acc[a][b], af[a], bfv[b]);
    __syncthreads();
  }
  int lr = (lane >> 4) << 2;
  int lc = lane & 15;
#pragma unroll
  for (int a = 0; a < 4; ++a) {
#pragma unroll
    for (int b = 0; b < 4; ++b) {
      int col = n0 + wc * 64 + b * 16 + lc;
      float bv = 0.0f;
      if constexpr (BIAS) bv = bias[col];
#pragma unroll
      for (int j = 0; j < 4; ++j) {
        int rowi = m0 + wr * 64 + a * 16 + lr + j;
        float v = acc[a][b][j] + bv;
        if constexpr (ACT == 1) v = silu_f(v);
        if constexpr (ACT == 2) v = mish_f(v);
        if constexpr (OUTBF16) Cb[(size_t)rowi * N + col] = __float2bfloat16(v);
        else Cf[(size_t)rowi * N + col] = v;
      }
    }
  }
}

// ---------------- c = x @ sc_w : [8192,1024]f32 @ [1024,32]f32 -> [8192,32]f32 ---------
__global__ __launch_bounds__(256) void c_kernel(const float* __restrict__ x,
                                                const float* __restrict__ scw,
                                                float* __restrict__ cout) {
  __shared__ float Xs[8][1024];
  int t = threadIdx.x;
  int row0 = blockIdx.x * 8;
#pragma unroll
  for (int i = 0; i < 32; ++i) {
    int idx = t + i * 256;
    Xs[idx >> 10][idx & 1023] = x[(size_t)row0 * 1024 + idx];
  }
  __syncthreads();
  int r = t >> 5, n = t & 31;
  float acc = 0.0f;
#pragma unroll 4
  for (int k = 0; k < 1024; ++k) acc += Xs[r][k] * scw[k * 32 + n];
  cout[(size_t)(row0 + r) * 32 + n] = acc;
}

// ---------------- h = LN(silu(c @ sh1_w + b)) : [128,2048]@[2048,256] -> bf16[128,256] -
__global__ __launch_bounds__(256) void h_kernel(const float* __restrict__ c,
                                                const float* __restrict__ w,
                                                const float* __restrict__ bias,
                                                const float* __restrict__ gam,
                                                const float* __restrict__ bet,
                                                bf16* __restrict__ hb) {
  __shared__ float Cs[2048];
  __shared__ float rsm[4], rs2[4], st2[2];
  int t = threadIdx.x, row = blockIdx.x;
#pragma unroll
  for (int i = 0; i < 8; ++i) Cs[t + i * 256] = c[(size_t)row * 2048 + t + i * 256];
  __syncthreads();
  float acc = bias[t];
#pragma unroll 4
  for (int k = 0; k < 2048; ++k) acc += Cs[k] * w[(size_t)k * 256 + t];
  float sv = silu_f(acc);
  float s = sv, s2 = sv * sv;
#pragma unroll
  for (int o = 32; o > 0; o >>= 1) { s += __shfl_down(s, o); s2 += __shfl_down(s2, o); }
  if ((t & 63) == 0) { rsm[t >> 6] = s; rs2[t >> 6] = s2; }
  __syncthreads();
  if (t == 0) {
    float a = rsm[0] + rsm[1] + rsm[2] + rsm[3];
    float b2 = rs2[0] + rs2[1] + rs2[2] + rs2[3];
    float m = a * (1.0f / 256.0f);
    st2[0] = m;
    st2[1] = rsqrtf(b2 * (1.0f / 256.0f) - m * m + LN_EPS);
  }
  __syncthreads();
  float y = (sv - st2[0]) * st2[1] * gam[t] + bet[t];
  hb[(size_t)row * 256 + t] = __float2bfloat16(y);
}

// ---------------- LN over 8192 cols (smolgen g) -> bf16 --------------------------------
__global__ __launch_bounds__(1024) void ln8192_kernel(const float* __restrict__ gpre,
                                                      const float* __restrict__ gam,
                                                      const float* __restrict__ bet,
                                                      bf16* __restrict__ gb) {
  __shared__ float rsm[16], rs2[16], st2[2];
  int t = threadIdx.x, row = blockIdx.x;
  const float* p = gpre + (size_t)row * 8192;
  float v[8];
  float s = 0.0f, s2 = 0.0f;
#pragma unroll
  for (int i = 0; i < 8; ++i) {
    v[i] = p[t + i * 1024];
    s += v[i];
    s2 += v[i] * v[i];
  }
#pragma unroll
  for (int o = 32; o > 0; o >>= 1) { s += __shfl_down(s, o); s2 += __shfl_down(s2, o); }
  int lane = t & 63, w = t >> 6;
  if (lane == 0) { rsm[w] = s; rs2[w] = s2; }
  __syncthreads();
  if (t == 0) {
    float a = 0.0f, b2 = 0.0f;
#pragma unroll
    for (int i = 0; i < 16; ++i) { a += rsm[i]; b2 += rs2[i]; }
    float m = a * (1.0f / 8192.0f);
    st2[0] = m;
    st2[1] = rsqrtf(b2 * (1.0f / 8192.0f) - m * m + LN_EPS);
  }
  __syncthreads();
  float m = st2[0], r = st2[1];
#pragma unroll
  for (int i = 0; i < 8; ++i) {
    int n = t + i * 1024;
    gb[(size_t)row * 8192 + n] = __float2bfloat16((v[i] - m) * r * gam[n] + bet[n]);
  }
}

// ---------------- residual + LN over 1024 cols (float4-vectorized) ---------------------
__global__ __launch_bounds__(256) void ln_residual_kernel(const float* __restrict__ base,
                                                          const float* __restrict__ delta,
                                                          const float* __restrict__ gam,
                                                          const float* __restrict__ bet,
                                                          float* __restrict__ outf,
                                                          bf16* __restrict__ outb) {
  __shared__ float rsm[4], rs2[4], st2[2];
  int t = threadIdx.x, row = blockIdx.x;
  float4 bv = ((const float4*)(base + (size_t)row * 1024))[t];
  float4 dv = ((const float4*)(delta + (size_t)row * 1024))[t];
  float4 v;
  v.x = bv.x + dv.x * ALPHA_F;
  v.y = bv.y + dv.y * ALPHA_F;
  v.z = bv.z + dv.z * ALPHA_F;
  v.w = bv.w + dv.w * ALPHA_F;
  float s = v.x + v.y + v.z + v.w;
  float s2 = v.x * v.x + v.y * v.y + v.z * v.z + v.w * v.w;
#pragma unroll
  for (int o = 32; o > 0; o >>= 1) { s += __shfl_down(s, o); s2 += __shfl_down(s2, o); }
  if ((t & 63) == 0) { rsm[t >> 6] = s; rs2[t >> 6] = s2; }
  __syncthreads();
  if (t == 0) {
    float a = rsm[0] + rsm[1] + rsm[2] + rsm[3];
    float b2 = rs2[0] + rs2[1] + rs2[2] + rs2[3];
    float m = a * (1.0f / 1024.0f);
    st2[0] = m;
    st2[1] = rsqrtf(b2 * (1.0f / 1024.0f) - m * m + LN_EPS);
  }
  __syncthreads();
  float m = st2[0], r = st2[1];
  float4 g4 = ((const float4*)gam)[t];
  float4 b4 = ((const float4*)bet)[t];
  float4 y;
  y.x = (v.x - m) * r * g4.x + b4.x;
  y.y = (v.y - m) * r * g4.y + b4.y;
  y.z = (v.z - m) * r * g4.z + b4.z;
  y.w = (v.w - m) * r * g4.w + b4.w;
  ((float4*)(outf + (size_t)row * 1024))[t] = y;
  ushort4 o4;
  o4.x = f2bfu(y.x); o4.y = f2bfu(y.y); o4.z = f2bfu(y.z); o4.w = f2bfu(y.w);
  ((ushort4*)(outb + (size_t)row * 1024))[t] = o4;
}

// ---------------- MFMA fused attention per (b,h) ---------------------------------------
// Wave w owns q-rows 16w..16w+15. QK^T: A(Q)/B(K) frags loaded straight from global
// (row = fr-lane, k = s4*8). S += sw (LDS-staged); softmax via 16-lane shfl_xor reduce
// (C-layout rows live in the lc group). P (unnormalized exp, bf16) -> LDS [64][72];
// V staged transposed Vt[d][k] [32][72]; PV = 4 MFMAs/wave; epilogue * 1/sum.
__global__ __launch_bounds__(256) void attn_kernel(const bf16* __restrict__ qkv,
                                                   const bf16* __restrict__ sw,
                                                   bf16* __restrict__ avb) {
  __shared__ __align__(16) short Vt[32 * 72];
  __shared__ __align__(16) short Sw[64 * 64];
  __shared__ __align__(16) short Pl[64 * 72];
  const int t = threadIdx.x, lane = t & 63, w = t >> 6;
  const int fr = lane & 15, s4 = lane >> 4;
  const int bh = blockIdx.x, b = bh >> 5, h = bh & 31;
  const size_t qb = (size_t)b * 64 * 3072 + h * 32;
  // stage V transposed: Vt[d][k]
  {
    int k = t >> 2, d0 = (t & 3) * 8;
    bf16x8 v = *(const bf16x8*)(qkv + qb + (size_t)k * 3072 + 2048 + d0);
#pragma unroll
    for (int i = 0; i < 8; ++i) Vt[(d0 + i) * 72 + k] = v[i];
  }
  // stage sw bias [64][64]
  {
    const bf16* swp = sw + (size_t)bh * 4096;
    *(bf16x8*)(Sw + t * 8) = *(const bf16x8*)(swp + t * 8);
    *(bf16x8*)(Sw + 2048 + t * 8) = *(const bf16x8*)(swp + 2048 + t * 8);
  }
  __syncthreads();
  // QK^T: S[16 rows][64 cols] per wave
  f32x4 acc[4] = {};
  {
    bf16x8 aq = *(const bf16x8*)(qkv + qb + (size_t)(16 * w + fr) * 3072 + s4 * 8);
#pragma unroll
    for (int n = 0; n < 4; ++n) {
      bf16x8 bk = *(const bf16x8*)(qkv + qb + (size_t)(n * 16 + fr) * 3072 + 1024 + s4 * 8);
      acc[n] = __builtin_amdgcn_mfma_f32_16x16x32_bf16(aq, bk, acc[n], 0, 0, 0);
    }
  }
  // softmax over k for rows q = 16w + s4*4 + j (cols n*16+fr per lane)
  float rinv[4];
#pragma unroll
  for (int j = 0; j < 4; ++j) {
    int q = 16 * w + s4 * 4 + j;
    float pv[4];
    float mx = -1e30f;
#pragma unroll
    for (int n = 0; n < 4; ++n) {
      float v = acc[n][j] * 0.17677669529663687f +
                __bfloat162float(((const bf16*)Sw)[q * 64 + n * 16 + fr]);
      pv[n] = v;
      mx = fmaxf(mx, v);
    }
    mx = fmaxf(mx, __shfl_xor(mx, 1));
    mx = fmaxf(mx, __shfl_xor(mx, 2));
    mx = fmaxf(mx, __shfl_xor(mx, 4));
    mx = fmaxf(mx, __shfl_xor(mx, 8));
    float sum = 0.0f;
#pragma unroll
    for (int n = 0; n < 4; ++n) {
      float e = __expf(pv[n] - mx);
      sum += e;
      ((bf16*)Pl)[q * 72 + n * 16 + fr] = __float2bfloat16(e);
    }
    sum += __shfl_xor(sum, 1);
    sum += __shfl_xor(sum, 2);
    sum += __shfl_xor(sum, 4);
    sum += __shfl_xor(sum, 8);
    rinv[j] = 1.0f / sum;
  }
  __syncthreads();
  // PV: out[16 rows][32 d] per wave
  f32x4 acc2[2] = {};
#pragma unroll
  for (int kt = 0; kt < 2; ++kt) {
    bf16x8 ap = *(const bf16x8*)(Pl + (16 * w + fr) * 72 + kt * 32 + s4 * 8);
#pragma unroll
    for (int n2 = 0; n2 < 2; ++n2) {
      bf16x8 bv = *(const bf16x8*)(Vt + (n2 * 16 + fr) * 72 + kt * 32 + s4 * 8);
      acc2[n2] = __builtin_amdgcn_mfma_f32_16x16x32_bf16(ap, bv, acc2[n2], 0, 0, 0);
    }
  }
#pragma unroll
  for (int n2 = 0; n2 < 2; ++n2) {
#pragma unroll
    for (int j = 0; j < 4; ++j) {
      int q = 16 * w + s4 * 4 + j;
      int d = n2 * 16 + fr;
      avb[(size_t)(b * 64 + q) * 1024 + h * 32 + d] =
          __float2bfloat16(acc2[n2][j] * rinv[j]);
    }
  }
}

extern "C" void kernel_launch(void* const* d_in, const int* in_sizes, int n_in,
                              void* d_out, int out_size, void* d_ws, size_t ws_size,
                              hipStream_t stream) {
  const float* x_in   = (const float*)d_in[0];
  const float* wq_w   = (const float*)d_in[1];
  const float* wq_b   = (const float*)d_in[2];
  const float* wk_w   = (const float*)d_in[3];
  const float* wk_b   = (const float*)d_in[4];
  const float* wv_w   = (const float*)d_in[5];
  const float* wv_b   = (const float*)d_in[6];
  const float* wo_w   = (const float*)d_in[7];
  const float* wo_b   = (const float*)d_in[8];
  const float* sc_w   = (const float*)d_in[9];
  const float* sh1_w  = (const float*)d_in[10];
  const float* sh1_b  = (const float*)d_in[11];
  const float* sln1_g = (const float*)d_in[12];
  const float* sln1_b = (const float*)d_in[13];
  const float* sgf_w  = (const float*)d_in[14];
  const float* sgf_b  = (const float*)d_in[15];
  const float* sln2_g = (const float*)d_in[16];
  const float* sln2_b = (const float*)d_in[17];
  const float* swg_w  = (const float*)d_in[18];
  const float* ffn1_w = (const float*)d_in[19];
  const float* ffn1_b = (const float*)d_in[20];
  const float* ffn2_w = (const float*)d_in[21];
  const float* ffn2_b = (const float*)d_in[22];
  const float* n1_g   = (const float*)d_in[23];
  const float* n1_b   = (const float*)d_in[24];
  const float* n2_g   = (const float*)d_in[25];
  const float* n2_b   = (const float*)d_in[26];

  char* ws = (char*)d_ws;
  size_t off = 0;
  auto alloc = [&](size_t bytes) -> void* {
    void* p = ws + off;
    off += (bytes + 255) & ~(size_t)255;
    return p;
  };
  bf16*  xb    = (bf16*)alloc(8192ULL * 1024 * 2);
  float* P0    = (float*)alloc(8192ULL * 1024 * 4);
  float* P1    = (float*)alloc(8192ULL * 1024 * 4);
  float* Tbuf  = (float*)alloc(8192ULL * 1024 * 4);
  bf16*  Wqkv  = (bf16*)alloc(3072ULL * 1024 * 2);
  float* bqkv  = (float*)alloc(3072ULL * 4);
  bf16*  Wo    = (bf16*)alloc(1024ULL * 1024 * 2);
  bf16*  Wf1   = (bf16*)alloc(1536ULL * 1024 * 2);
  bf16*  Wf2   = (bf16*)alloc(1024ULL * 1536 * 2);
  bf16*  Wsgf  = (bf16*)alloc(8192ULL * 256 * 2);
  bf16*  Wswg  = (bf16*)alloc(4096ULL * 256 * 2);
  bf16*  qkvb  = (bf16*)alloc(8192ULL * 3072 * 2);
  float* cbuf  = (float*)alloc(8192ULL * 32 * 4);
  bf16*  hbb   = (bf16*)alloc(128ULL * 256 * 2);
  float* gpre  = (float*)alloc(128ULL * 8192 * 4);
  bf16*  gbb   = (bf16*)alloc(128ULL * 8192 * 2);
  bf16*  swb   = (bf16*)alloc(4096ULL * 4096 * 2);
  bf16*  avb   = (bf16*)alloc(8192ULL * 1024 * 2);
  bf16*  out1b = (bf16*)alloc(8192ULL * 1024 * 2);
  bf16*  f1b   = (bf16*)alloc(8192ULL * 1536 * 2);
  if (off > ws_size) {
    sentinel_k<<<1, 1, 0, stream>>>((float*)d_out);
    return;
  }

  cvt_f32_bf16_k<<<8192, 256, 0, stream>>>(x_in, xb, 8192LL * 1024);

  for (int l = 0; l < 15; ++l) {
    const float* wq   = wq_w + (size_t)l * 1024 * 1024;
    const float* wk   = wk_w + (size_t)l * 1024 * 1024;
    const float* wv   = wv_w + (size_t)l * 1024 * 1024;
    const float* wo   = wo_w + (size_t)l * 1024 * 1024;
    const float* f1w  = ffn1_w + (size_t)l * 1024 * 1536;
    const float* f2w  = ffn2_w + (size_t)l * 1536 * 1024;
    const float* sgf  = sgf_w + (size_t)l * 256 * 8192;
    const float* swg  = swg_w + (size_t)l * 256 * 4096;
    const float* scw  = sc_w + (size_t)l * 1024 * 32;
    const float* sh1w = sh1_w + (size_t)l * 2048 * 256;

    transpose_layer<<<10240, 256, 0, stream>>>(wq, wk, wv, wo, f1w, f2w, sgf, swg,
                                               Wqkv, Wo, Wf1, Wf2, Wsgf, Wswg);
    pack3_k<<<12, 256, 0, stream>>>(wq_b + l * 1024, wk_b + l * 1024, wv_b + l * 1024, bqkv);

    const float* xc = (l == 0) ? x_in : ((l & 1) ? P0 : P1);
    float* Pout = (l & 1) ? P1 : P0;

    // QKV projection
    gemm_tn<0, true, true><<<dim3(24, 64), 256, 0, stream>>>(xb, Wqkv, bqkv, nullptr, qkvb,
                                                             8192, 3072, 1024);
    // smolgen chain
    c_kernel<<<1024, 256, 0, stream>>>(xc, scw, cbuf);
    h_kernel<<<128, 256, 0, stream>>>(cbuf, sh1w, sh1_b + l * 256, sln1_g + l * 256,
                                      sln1_b + l * 256, hbb);
    gemm_tn<1, false, true><<<dim3(64, 1), 256, 0, stream>>>(hbb, Wsgf, sgf_b + (size_t)l * 8192,
                                                             gpre, nullptr, 128, 8192, 256);
    ln8192_kernel<<<128, 1024, 0, stream>>>(gpre, sln2_g + (size_t)l * 8192,
                                            sln2_b + (size_t)l * 8192, gbb);
    gemm_tn<0, true, false><<<dim3(32, 32), 256, 0, stream>>>(gbb, Wswg, nullptr, nullptr, swb,
                                                              4096, 4096, 256);
    // attention (MFMA)
    attn_kernel<<<4096, 256, 0, stream>>>(qkvb, swb, avb);
    // output projection + LN1
    gemm_tn<0, false, true><<<dim3(8, 64), 256, 0, stream>>>(avb, Wo, wo_b + l * 1024, Tbuf,
                                                             nullptr, 8192, 1024, 1024);
    ln_residual_kernel<<<8192, 256, 0, stream>>>(xc, Tbuf, n1_g + l * 1024, n1_b + l * 1024,
                                                 Pout, out1b);
    // FFN + LN2
    gemm_tn<2, true, true><<<dim3(12, 64), 256, 0, stream>>>(out1b, Wf1, ffn1_b + l * 1536,
                                                             nullptr, f1b, 8192, 1536, 1024);
    gemm_tn<0, false, true><<<dim3(8, 64), 256, 0, stream>>>(f1b, Wf2, ffn2_b + l * 1024, Tbuf,
                                                             nullptr, 8192, 1024, 1536);
    float* xnext = (l == 14) ? (float*)d_out : Pout;
    ln_residual_kernel<<<8192, 256, 0, stream>>>(Pout, Tbuf, n2_g + l * 1024, n2_b + l * 1024,
                                                 xnext, xb);
  }
}

// Round 8
// 9329.928 us; speedup vs baseline: 1.7921x; 1.2265x over previous
//
#include <hip/hip_runtime.h>
#include <hip/hip_bf16.h>

typedef __attribute__((ext_vector_type(8))) short bf16x8;
typedef __attribute__((ext_vector_type(4))) float f32x4;
typedef __hip_bfloat16 bf16;

#define ALPHA_F 0.42728713f
#define LN_EPS 1e-3f

__device__ __forceinline__ float silu_f(float x) { return x / (1.0f + __expf(-x)); }
__device__ __forceinline__ float mish_f(float x) {
  float sp = (x > 20.0f) ? x : log1pf(__expf(x));
  return x * tanhf(sp);
}
__device__ __forceinline__ unsigned short f2bfu(float x) {
  bf16 h = __float2bfloat16(x);
  return *(unsigned short*)&h;
}

// Builtin MFMA: LLVM sees real dataflow -> acc lives in AGPRs.
#define MFMA16(acc, a, b) \
  (acc) = __builtin_amdgcn_mfma_f32_16x16x32_bf16((a), (b), (acc), 0, 0, 0)

#define GLOAD_LDS16(gp, lp)                                                              \
  __builtin_amdgcn_global_load_lds((__attribute__((address_space(1))) void*)(void*)(gp), \
                                   (__attribute__((address_space(3))) void*)(void*)(lp), \
                                   16, 0, 0)

// ---------------- batched per-layer weight transpose: W[K,N] f32 -> Wt[N,K] bf16 -------
__global__ __launch_bounds__(256) void transpose_layer(
    const float* __restrict__ wq, const float* __restrict__ wk, const float* __restrict__ wv,
    const float* __restrict__ wo, const float* __restrict__ f1, const float* __restrict__ f2,
    const float* __restrict__ sgf, const float* __restrict__ swg, const float* __restrict__ sh1,
    bf16* __restrict__ Wqkv, bf16* __restrict__ Wo, bf16* __restrict__ Wf1,
    bf16* __restrict__ Wf2, bf16* __restrict__ Wsgf, bf16* __restrict__ Wswg,
    bf16* __restrict__ Wsh1) {
  __shared__ float tile[32][33];
  int b = blockIdx.x;
  const float* W;
  bf16* Wt;
  int K, N, tb;
  if (b < 3072) {
    int m = b >> 10;
    W = (m == 0) ? wq : ((m == 1) ? wk : wv);
    Wt = Wqkv + (size_t)m * 1024 * 1024;
    K = 1024; N = 1024; tb = b & 1023;
  } else if (b < 4096)  { W = wo;  Wt = Wo;   K = 1024; N = 1024; tb = b - 3072; }
  else if (b < 5632)    { W = f1;  Wt = Wf1;  K = 1024; N = 1536; tb = b - 4096; }
  else if (b < 7168)    { W = f2;  Wt = Wf2;  K = 1536; N = 1024; tb = b - 5632; }
  else if (b < 9216)    { W = sgf; Wt = Wsgf; K = 256;  N = 8192; tb = b - 7168; }
  else if (b < 10240)   { W = swg; Wt = Wswg; K = 256;  N = 4096; tb = b - 9216; }
  else                  { W = sh1; Wt = Wsh1; K = 2048; N = 256;  tb = b - 10240; }
  int ntx = N >> 5;
  int ty_ = tb / ntx, tx_ = tb - ty_ * ntx;
  int nb = tx_ * 32, kb = ty_ * 32;
  int tx = threadIdx.x & 31, ty = threadIdx.x >> 5;
#pragma unroll
  for (int i = 0; i < 4; ++i)
    tile[ty + i * 8][tx] = W[(size_t)(kb + ty + i * 8) * N + nb + tx];
  __syncthreads();
#pragma unroll
  for (int i = 0; i < 4; ++i)
    Wt[(size_t)(nb + ty + i * 8) * K + kb + tx] = __float2bfloat16(tile[tx][ty + i * 8]);
}

__global__ __launch_bounds__(256) void cvt_f32_bf16_k(const float* __restrict__ in,
                                                      bf16* __restrict__ out, long long n) {
  long long i = ((long long)blockIdx.x * 256 + threadIdx.x) * 4;
  if (i + 3 < n) {
    float4 v = *(const float4*)(in + i);
    out[i + 0] = __float2bfloat16(v.x);
    out[i + 1] = __float2bfloat16(v.y);
    out[i + 2] = __float2bfloat16(v.z);
    out[i + 3] = __float2bfloat16(v.w);
  }
}

__global__ __launch_bounds__(256) void pack3_k(const float* __restrict__ a,
                                               const float* __restrict__ b,
                                               const float* __restrict__ c,
                                               float* __restrict__ o) {
  int i = blockIdx.x * 256 + threadIdx.x;
  if (i < 1024) o[i] = a[i];
  else if (i < 2048) o[i] = b[i - 1024];
  else if (i < 3072) o[i] = c[i - 2048];
}

__global__ __launch_bounds__(1) void sentinel_k(float* __restrict__ o) { o[0] = 1.2345e7f; }

// ---------------- 128x128 bf16 MFMA GEMM (m97 structure; THE workhorse) ----------------
template <int ACT, bool OUTBF16, bool BIAS>
__global__ __launch_bounds__(256) void gemm_tn(const bf16* __restrict__ A,
                                               const bf16* __restrict__ Bt,
                                               const float* __restrict__ bias,
                                               float* __restrict__ Cf, bf16* __restrict__ Cb,
                                               int M, int N, int K) {
  __shared__ __align__(128) short As[128 * 32];
  __shared__ __align__(128) short Bs[128 * 32];
  int t = threadIdx.x;
  int lane = t & 63, wave = t >> 6;
  int m0 = blockIdx.y * 128, n0 = blockIdx.x * 128;
  int wr = wave >> 1, wc = wave & 1;
  int fr = lane & 15;
  int fk = (lane >> 4) << 3;

  f32x4 acc[4][4] = {};

  int row0 = t >> 2, ko0 = (t & 3) << 3;
  int row1 = 64 + (t >> 2), ko1 = ko0;
  short* lpA0 = As + (size_t)(wave * 64) * 8;
  short* lpA1 = As + (size_t)(256 + wave * 64) * 8;
  short* lpB0 = Bs + (size_t)(wave * 64) * 8;
  short* lpB1 = Bs + (size_t)(256 + wave * 64) * 8;

  const short* ArdBase = As + ((wr * 64 + fr) * 32 + fk);
  const short* BrdBase = Bs + ((wc * 64 + fr) * 32 + fk);

  const bf16* Ag0 = A + (size_t)(m0 + row0) * K + ko0;
  const bf16* Ag1 = A + (size_t)(m0 + row1) * K + ko1;
  const bf16* Bg0 = Bt + (size_t)(n0 + row0) * K + ko0;
  const bf16* Bg1 = Bt + (size_t)(n0 + row1) * K + ko1;

  int nk = K >> 5;
  for (int kt = 0; kt < nk; ++kt) {
    int k0 = kt << 5;
    GLOAD_LDS16(Ag0 + k0, lpA0);
    GLOAD_LDS16(Ag1 + k0, lpA1);
    GLOAD_LDS16(Bg0 + k0, lpB0);
    GLOAD_LDS16(Bg1 + k0, lpB1);
    __syncthreads();
    bf16x8 af[4], bfv[4];
#pragma unroll
    for (int a = 0; a < 4; ++a) af[a] = *(const bf16x8*)(ArdBase + a * 512);
#pragma unroll
    for (int b = 0; b < 4; ++b) bfv[b] = *(const bf16x8*)(BrdBase + b * 512);
#pragma unroll
    for (int a = 0; a < 4; ++a)
#pragma unroll
      for (int b = 0; b < 4; ++b) MFMA16(acc[a][b], af[a], bfv[b]);
    __syncthreads();
  }
  int lr = (lane >> 4) << 2;
  int lc = lane & 15;
#pragma unroll
  for (int a = 0; a < 4; ++a) {
#pragma unroll
    for (int b = 0; b < 4; ++b) {
      int col = n0 + wc * 64 + b * 16 + lc;
      float bv = 0.0f;
      if constexpr (BIAS) bv = bias[col];
#pragma unroll
      for (int j = 0; j < 4; ++j) {
        int rowi = m0 + wr * 64 + a * 16 + lr + j;
        float v = acc[a][b][j] + bv;
        if constexpr (ACT == 1) v = silu_f(v);
        if constexpr (ACT == 2) v = mish_f(v);
        if constexpr (OUTBF16) Cb[(size_t)rowi * N + col] = __float2bfloat16(v);
        else Cf[(size_t)rowi * N + col] = v;
      }
    }
  }
}

// ---------------- c = x @ sc_w : [8192,1024]f32 @ [1024,32]f32 -> bf16 [8192,32] -------
__global__ __launch_bounds__(256) void c_kernel(const float* __restrict__ x,
                                                const float* __restrict__ scw,
                                                bf16* __restrict__ cout) {
  __shared__ float Xs[8][1024];
  int t = threadIdx.x;
  int row0 = blockIdx.x * 8;
#pragma unroll
  for (int i = 0; i < 32; ++i) {
    int idx = t + i * 256;
    Xs[idx >> 10][idx & 1023] = x[(size_t)row0 * 1024 + idx];
  }
  __syncthreads();
  int r = t >> 5, n = t & 31;
  float acc = 0.0f;
#pragma unroll 4
  for (int k = 0; k < 1024; ++k) acc += Xs[r][k] * scw[k * 32 + n];
  cout[(size_t)(row0 + r) * 32 + n] = __float2bfloat16(acc);
}

// ---------------- LN over 256 cols: hb = LN(hpre) -> bf16 ------------------------------
__global__ __launch_bounds__(256) void ln256_kernel(const float* __restrict__ hpre,
                                                    const float* __restrict__ gam,
                                                    const float* __restrict__ bet,
                                                    bf16* __restrict__ hb) {
  __shared__ float rsm[4], rs2[4], st2[2];
  int t = threadIdx.x, row = blockIdx.x;
  float sv = hpre[(size_t)row * 256 + t];
  float s = sv, s2 = sv * sv;
#pragma unroll
  for (int o = 32; o > 0; o >>= 1) { s += __shfl_down(s, o); s2 += __shfl_down(s2, o); }
  if ((t & 63) == 0) { rsm[t >> 6] = s; rs2[t >> 6] = s2; }
  __syncthreads();
  if (t == 0) {
    float a = rsm[0] + rsm[1] + rsm[2] + rsm[3];
    float b2 = rs2[0] + rs2[1] + rs2[2] + rs2[3];
    float m = a * (1.0f / 256.0f);
    st2[0] = m;
    st2[1] = rsqrtf(b2 * (1.0f / 256.0f) - m * m + LN_EPS);
  }
  __syncthreads();
  float y = (sv - st2[0]) * st2[1] * gam[t] + bet[t];
  hb[(size_t)row * 256 + t] = __float2bfloat16(y);
}

// ---------------- LN over 8192 cols (smolgen g) -> bf16 --------------------------------
__global__ __launch_bounds__(1024) void ln8192_kernel(const float* __restrict__ gpre,
                                                      const float* __restrict__ gam,
                                                      const float* __restrict__ bet,
                                                      bf16* __restrict__ gb) {
  __shared__ float rsm[16], rs2[16], st2[2];
  int t = threadIdx.x, row = blockIdx.x;
  const float* p = gpre + (size_t)row * 8192;
  float v[8];
  float s = 0.0f, s2 = 0.0f;
#pragma unroll
  for (int i = 0; i < 8; ++i) {
    v[i] = p[t + i * 1024];
    s += v[i];
    s2 += v[i] * v[i];
  }
#pragma unroll
  for (int o = 32; o > 0; o >>= 1) { s += __shfl_down(s, o); s2 += __shfl_down(s2, o); }
  int lane = t & 63, w = t >> 6;
  if (lane == 0) { rsm[w] = s; rs2[w] = s2; }
  __syncthreads();
  if (t == 0) {
    float a = 0.0f, b2 = 0.0f;
#pragma unroll
    for (int i = 0; i < 16; ++i) { a += rsm[i]; b2 += rs2[i]; }
    float m = a * (1.0f / 8192.0f);
    st2[0] = m;
    st2[1] = rsqrtf(b2 * (1.0f / 8192.0f) - m * m + LN_EPS);
  }
  __syncthreads();
  float m = st2[0], r = st2[1];
#pragma unroll
  for (int i = 0; i < 8; ++i) {
    int n = t + i * 1024;
    gb[(size_t)row * 8192 + n] = __float2bfloat16((v[i] - m) * r * gam[n] + bet[n]);
  }
}

// ---------------- residual + LN over 1024 cols (float4-vectorized) ---------------------
__global__ __launch_bounds__(256) void ln_residual_kernel(const float* __restrict__ base,
                                                          const float* __restrict__ delta,
                                                          const float* __restrict__ gam,
                                                          const float* __restrict__ bet,
                                                          float* __restrict__ outf,
                                                          bf16* __restrict__ outb) {
  __shared__ float rsm[4], rs2[4], st2[2];
  int t = threadIdx.x, row = blockIdx.x;
  float4 bv = ((const float4*)(base + (size_t)row * 1024))[t];
  float4 dv = ((const float4*)(delta + (size_t)row * 1024))[t];
  float4 v;
  v.x = bv.x + dv.x * ALPHA_F;
  v.y = bv.y + dv.y * ALPHA_F;
  v.z = bv.z + dv.z * ALPHA_F;
  v.w = bv.w + dv.w * ALPHA_F;
  float s = v.x + v.y + v.z + v.w;
  float s2 = v.x * v.x + v.y * v.y + v.z * v.z + v.w * v.w;
#pragma unroll
  for (int o = 32; o > 0; o >>= 1) { s += __shfl_down(s, o); s2 += __shfl_down(s2, o); }
  if ((t & 63) == 0) { rsm[t >> 6] = s; rs2[t >> 6] = s2; }
  __syncthreads();
  if (t == 0) {
    float a = rsm[0] + rsm[1] + rsm[2] + rsm[3];
    float b2 = rs2[0] + rs2[1] + rs2[2] + rs2[3];
    float m = a * (1.0f / 1024.0f);
    st2[0] = m;
    st2[1] = rsqrtf(b2 * (1.0f / 1024.0f) - m * m + LN_EPS);
  }
  __syncthreads();
  float m = st2[0], r = st2[1];
  float4 g4 = ((const float4*)gam)[t];
  float4 b4 = ((const float4*)bet)[t];
  float4 y;
  y.x = (v.x - m) * r * g4.x + b4.x;
  y.y = (v.y - m) * r * g4.y + b4.y;
  y.z = (v.z - m) * r * g4.z + b4.z;
  y.w = (v.w - m) * r * g4.w + b4.w;
  ((float4*)(outf + (size_t)row * 1024))[t] = y;
  ushort4 o4;
  o4.x = f2bfu(y.x); o4.y = f2bfu(y.y); o4.z = f2bfu(y.z); o4.w = f2bfu(y.w);
  ((ushort4*)(outb + (size_t)row * 1024))[t] = o4;
}

// ---------------- MFMA fused attention per (b,h) ---------------------------------------
__global__ __launch_bounds__(256) void attn_kernel(const bf16* __restrict__ qkv,
                                                   const bf16* __restrict__ sw,
                                                   bf16* __restrict__ avb) {
  __shared__ __align__(16) short Vt[32 * 72];
  __shared__ __align__(16) short Sw[64 * 64];
  __shared__ __align__(16) short Pl[64 * 72];
  const int t = threadIdx.x, lane = t & 63, w = t >> 6;
  const int fr = lane & 15, s4 = lane >> 4;
  const int bh = blockIdx.x, b = bh >> 5, h = bh & 31;
  const size_t qb = (size_t)b * 64 * 3072 + h * 32;
  // stage V transposed: Vt[d][k]
  {
    int k = t >> 2, d0 = (t & 3) * 8;
    bf16x8 v = *(const bf16x8*)(qkv + qb + (size_t)k * 3072 + 2048 + d0);
#pragma unroll
    for (int i = 0; i < 8; ++i) Vt[(d0 + i) * 72 + k] = v[i];
  }
  // stage sw bias [64][64]
  {
    const bf16* swp = sw + (size_t)bh * 4096;
    *(bf16x8*)(Sw + t * 8) = *(const bf16x8*)(swp + t * 8);
    *(bf16x8*)(Sw + 2048 + t * 8) = *(const bf16x8*)(swp + 2048 + t * 8);
  }
  __syncthreads();
  // QK^T: S[16 rows][64 cols] per wave
  f32x4 acc[4] = {};
  {
    bf16x8 aq = *(const bf16x8*)(qkv + qb + (size_t)(16 * w + fr) * 3072 + s4 * 8);
#pragma unroll
    for (int n = 0; n < 4; ++n) {
      bf16x8 bk = *(const bf16x8*)(qkv + qb + (size_t)(n * 16 + fr) * 3072 + 1024 + s4 * 8);
      acc[n] = __builtin_amdgcn_mfma_f32_16x16x32_bf16(aq, bk, acc[n], 0, 0, 0);
    }
  }
  // softmax over k for rows q = 16w + s4*4 + j (cols n*16+fr per lane)
  float rinv[4];
#pragma unroll
  for (int j = 0; j < 4; ++j) {
    int q = 16 * w + s4 * 4 + j;
    float pv[4];
    float mx = -1e30f;
#pragma unroll
    for (int n = 0; n < 4; ++n) {
      float v = acc[n][j] * 0.17677669529663687f +
                __bfloat162float(((const bf16*)Sw)[q * 64 + n * 16 + fr]);
      pv[n] = v;
      mx = fmaxf(mx, v);
    }
    mx = fmaxf(mx, __shfl_xor(mx, 1));
    mx = fmaxf(mx, __shfl_xor(mx, 2));
    mx = fmaxf(mx, __shfl_xor(mx, 4));
    mx = fmaxf(mx, __shfl_xor(mx, 8));
    float sum = 0.0f;
#pragma unroll
    for (int n = 0; n < 4; ++n) {
      float e = __expf(pv[n] - mx);
      sum += e;
      ((bf16*)Pl)[q * 72 + n * 16 + fr] = __float2bfloat16(e);
    }
    sum += __shfl_xor(sum, 1);
    sum += __shfl_xor(sum, 2);
    sum += __shfl_xor(sum, 4);
    sum += __shfl_xor(sum, 8);
    rinv[j] = 1.0f / sum;
  }
  __syncthreads();
  // PV: out[16 rows][32 d] per wave
  f32x4 acc2[2] = {};
#pragma unroll
  for (int kt = 0; kt < 2; ++kt) {
    bf16x8 ap = *(const bf16x8*)(Pl + (16 * w + fr) * 72 + kt * 32 + s4 * 8);
#pragma unroll
    for (int n2 = 0; n2 < 2; ++n2) {
      bf16x8 bv = *(const bf16x8*)(Vt + (n2 * 16 + fr) * 72 + kt * 32 + s4 * 8);
      acc2[n2] = __builtin_amdgcn_mfma_f32_16x16x32_bf16(ap, bv, acc2[n2], 0, 0, 0);
    }
  }
#pragma unroll
  for (int n2 = 0; n2 < 2; ++n2) {
#pragma unroll
    for (int j = 0; j < 4; ++j) {
      int q = 16 * w + s4 * 4 + j;
      int d = n2 * 16 + fr;
      avb[(size_t)(b * 64 + q) * 1024 + h * 32 + d] =
          __float2bfloat16(acc2[n2][j] * rinv[j]);
    }
  }
}

extern "C" void kernel_launch(void* const* d_in, const int* in_sizes, int n_in,
                              void* d_out, int out_size, void* d_ws, size_t ws_size,
                              hipStream_t stream) {
  const float* x_in   = (const float*)d_in[0];
  const float* wq_w   = (const float*)d_in[1];
  const float* wq_b   = (const float*)d_in[2];
  const float* wk_w   = (const float*)d_in[3];
  const float* wk_b   = (const float*)d_in[4];
  const float* wv_w   = (const float*)d_in[5];
  const float* wv_b   = (const float*)d_in[6];
  const float* wo_w   = (const float*)d_in[7];
  const float* wo_b   = (const float*)d_in[8];
  const float* sc_w   = (const float*)d_in[9];
  const float* sh1_w  = (const float*)d_in[10];
  const float* sh1_b  = (const float*)d_in[11];
  const float* sln1_g = (const float*)d_in[12];
  const float* sln1_b = (const float*)d_in[13];
  const float* sgf_w  = (const float*)d_in[14];
  const float* sgf_b  = (const float*)d_in[15];
  const float* sln2_g = (const float*)d_in[16];
  const float* sln2_b = (const float*)d_in[17];
  const float* swg_w  = (const float*)d_in[18];
  const float* ffn1_w = (const float*)d_in[19];
  const float* ffn1_b = (const float*)d_in[20];
  const float* ffn2_w = (const float*)d_in[21];
  const float* ffn2_b = (const float*)d_in[22];
  const float* n1_g   = (const float*)d_in[23];
  const float* n1_b   = (const float*)d_in[24];
  const float* n2_g   = (const float*)d_in[25];
  const float* n2_b   = (const float*)d_in[26];

  char* ws = (char*)d_ws;
  size_t off = 0;
  auto alloc = [&](size_t bytes) -> void* {
    void* p = ws + off;
    off += (bytes + 255) & ~(size_t)255;
    return p;
  };
  bf16*  xb    = (bf16*)alloc(8192ULL * 1024 * 2);
  float* P0    = (float*)alloc(8192ULL * 1024 * 4);
  float* P1    = (float*)alloc(8192ULL * 1024 * 4);
  float* Tbuf  = (float*)alloc(8192ULL * 1024 * 4);
  bf16*  Wqkv  = (bf16*)alloc(3072ULL * 1024 * 2);
  float* bqkv  = (float*)alloc(3072ULL * 4);
  bf16*  Wo    = (bf16*)alloc(1024ULL * 1024 * 2);
  bf16*  Wf1   = (bf16*)alloc(1536ULL * 1024 * 2);
  bf16*  Wf2   = (bf16*)alloc(1024ULL * 1536 * 2);
  bf16*  Wsgf  = (bf16*)alloc(8192ULL * 256 * 2);
  bf16*  Wswg  = (bf16*)alloc(4096ULL * 256 * 2);
  bf16*  Wsh1  = (bf16*)alloc(256ULL * 2048 * 2);
  bf16*  qkvb  = (bf16*)alloc(8192ULL * 3072 * 2);
  bf16*  cbuf  = (bf16*)alloc(8192ULL * 32 * 2);
  float* hpre  = (float*)alloc(128ULL * 256 * 4);
  bf16*  hbb   = (bf16*)alloc(128ULL * 256 * 2);
  float* gpre  = (float*)alloc(128ULL * 8192 * 4);
  bf16*  gbb   = (bf16*)alloc(128ULL * 8192 * 2);
  bf16*  swb   = (bf16*)alloc(4096ULL * 4096 * 2);
  bf16*  avb   = (bf16*)alloc(8192ULL * 1024 * 2);
  bf16*  out1b = (bf16*)alloc(8192ULL * 1024 * 2);
  bf16*  f1b   = (bf16*)alloc(8192ULL * 1536 * 2);
  if (off > ws_size) {
    sentinel_k<<<1, 1, 0, stream>>>((float*)d_out);
    return;
  }

  cvt_f32_bf16_k<<<8192, 256, 0, stream>>>(x_in, xb, 8192LL * 1024);

  for (int l = 0; l < 15; ++l) {
    const float* wq   = wq_w + (size_t)l * 1024 * 1024;
    const float* wk   = wk_w + (size_t)l * 1024 * 1024;
    const float* wv   = wv_w + (size_t)l * 1024 * 1024;
    const float* wo   = wo_w + (size_t)l * 1024 * 1024;
    const float* f1w  = ffn1_w + (size_t)l * 1024 * 1536;
    const float* f2w  = ffn2_w + (size_t)l * 1536 * 1024;
    const float* sgf  = sgf_w + (size_t)l * 256 * 8192;
    const float* swg  = swg_w + (size_t)l * 256 * 4096;
    const float* scw  = sc_w + (size_t)l * 1024 * 32;
    const float* sh1w = sh1_w + (size_t)l * 2048 * 256;

    transpose_layer<<<10752, 256, 0, stream>>>(wq, wk, wv, wo, f1w, f2w, sgf, swg, sh1w,
                                               Wqkv, Wo, Wf1, Wf2, Wsgf, Wswg, Wsh1);
    pack3_k<<<12, 256, 0, stream>>>(wq_b + l * 1024, wk_b + l * 1024, wv_b + l * 1024, bqkv);

    const float* xc = (l == 0) ? x_in : ((l & 1) ? P0 : P1);
    float* Pout = (l & 1) ? P1 : P0;

    // QKV projection
    gemm_tn<0, true, true><<<dim3(24, 64), 256, 0, stream>>>(xb, Wqkv, bqkv, nullptr, qkvb,
                                                             8192, 3072, 1024);
    // smolgen chain
    c_kernel<<<1024, 256, 0, stream>>>(xc, scw, cbuf);
    gemm_tn<1, false, true><<<dim3(2, 1), 256, 0, stream>>>(cbuf, Wsh1, sh1_b + l * 256,
                                                            hpre, nullptr, 128, 256, 2048);
    ln256_kernel<<<128, 256, 0, stream>>>(hpre, sln1_g + l * 256, sln1_b + l * 256, hbb);
    gemm_tn<1, false, true><<<dim3(64, 1), 256, 0, stream>>>(hbb, Wsgf, sgf_b + (size_t)l * 8192,
                                                             gpre, nullptr, 128, 8192, 256);
    ln8192_kernel<<<128, 1024, 0, stream>>>(gpre, sln2_g + (size_t)l * 8192,
                                            sln2_b + (size_t)l * 8192, gbb);
    gemm_tn<0, true, false><<<dim3(32, 32), 256, 0, stream>>>(gbb, Wswg, nullptr, nullptr, swb,
                                                              4096, 4096, 256);
    // attention (MFMA)
    attn_kernel<<<4096, 256, 0, stream>>>(qkvb, swb, avb);
    // output projection + LN1
    gemm_tn<0, false, true><<<dim3(8, 64), 256, 0, stream>>>(avb, Wo, wo_b + l * 1024, Tbuf,
                                                             nullptr, 8192, 1024, 1024);
    ln_residual_kernel<<<8192, 256, 0, stream>>>(xc, Tbuf, n1_g + l * 1024, n1_b + l * 1024,
                                                 Pout, out1b);
    // FFN + LN2
    gemm_tn<2, true, true><<<dim3(12, 64), 256, 0, stream>>>(out1b, Wf1, ffn1_b + l * 1536,
                                                             nullptr, f1b, 8192, 1536, 1024);
    gemm_tn<0, false, true><<<dim3(8, 64), 256, 0, stream>>>(f1b, Wf2, ffn2_b + l * 1024, Tbuf,
                                                             nullptr, 8192, 1024, 1536);
    float* xnext = (l == 14) ? (float*)d_out : Pout;
    ln_residual_kernel<<<8192, 256, 0, stream>>>(Pout, Tbuf, n2_g + l * 1024, n2_b + l * 1024,
                                                 xnext, xb);
  }
}

// Round 9
// 8957.487 us; speedup vs baseline: 1.8667x; 1.0416x over previous
//
#include <hip/hip_runtime.h>
#include <hip/hip_bf16.h>

typedef __attribute__((ext_vector_type(8))) short bf16x8;
typedef __attribute__((ext_vector_type(4))) float f32x4;
typedef __hip_bfloat16 bf16;

#define ALPHA_F 0.42728713f
#define LN_EPS 1e-3f

__device__ __forceinline__ float silu_f(float x) { return x / (1.0f + __expf(-x)); }
__device__ __forceinline__ float mish_f(float x) {
  float sp = (x > 20.0f) ? x : log1pf(__expf(x));
  return x * tanhf(sp);
}
__device__ __forceinline__ unsigned short f2bfu(float x) {
  bf16 h = __float2bfloat16(x);
  return *(unsigned short*)&h;
}
__device__ __forceinline__ float bfu2f(unsigned short u) {
  unsigned int v = (unsigned int)u << 16;
  return *(float*)&v;
}

// Builtin MFMA: LLVM sees real dataflow -> acc lives in AGPRs.
#define MFMA16(acc, a, b) \
  (acc) = __builtin_amdgcn_mfma_f32_16x16x32_bf16((a), (b), (acc), 0, 0, 0)

#define GLOAD_LDS16(gp, lp)                                                              \
  __builtin_amdgcn_global_load_lds((__attribute__((address_space(1))) void*)(void*)(gp), \
                                   (__attribute__((address_space(3))) void*)(void*)(lp), \
                                   16, 0, 0)

// ---------------- batched per-layer weight transpose: W[K,N] f32 -> Wt[N,K] bf16 -------
__global__ __launch_bounds__(256) void transpose_layer(
    const float* __restrict__ wq, const float* __restrict__ wk, const float* __restrict__ wv,
    const float* __restrict__ wo, const float* __restrict__ f1, const float* __restrict__ f2,
    const float* __restrict__ sgf, const float* __restrict__ swg, const float* __restrict__ sh1,
    bf16* __restrict__ Wqkv, bf16* __restrict__ Wo, bf16* __restrict__ Wf1,
    bf16* __restrict__ Wf2, bf16* __restrict__ Wsgf, bf16* __restrict__ Wswg,
    bf16* __restrict__ Wsh1) {
  __shared__ float tile[32][33];
  int b = blockIdx.x;
  const float* W;
  bf16* Wt;
  int K, N, tb;
  if (b < 3072) {
    int m = b >> 10;
    W = (m == 0) ? wq : ((m == 1) ? wk : wv);
    Wt = Wqkv + (size_t)m * 1024 * 1024;
    K = 1024; N = 1024; tb = b & 1023;
  } else if (b < 4096)  { W = wo;  Wt = Wo;   K = 1024; N = 1024; tb = b - 3072; }
  else if (b < 5632)    { W = f1;  Wt = Wf1;  K = 1024; N = 1536; tb = b - 4096; }
  else if (b < 7168)    { W = f2;  Wt = Wf2;  K = 1536; N = 1024; tb = b - 5632; }
  else if (b < 9216)    { W = sgf; Wt = Wsgf; K = 256;  N = 8192; tb = b - 7168; }
  else if (b < 10240)   { W = swg; Wt = Wswg; K = 256;  N = 4096; tb = b - 9216; }
  else                  { W = sh1; Wt = Wsh1; K = 2048; N = 256;  tb = b - 10240; }
  int ntx = N >> 5;
  int ty_ = tb / ntx, tx_ = tb - ty_ * ntx;
  int nb = tx_ * 32, kb = ty_ * 32;
  int tx = threadIdx.x & 31, ty = threadIdx.x >> 5;
#pragma unroll
  for (int i = 0; i < 4; ++i)
    tile[ty + i * 8][tx] = W[(size_t)(kb + ty + i * 8) * N + nb + tx];
  __syncthreads();
#pragma unroll
  for (int i = 0; i < 4; ++i)
    Wt[(size_t)(nb + ty + i * 8) * K + kb + tx] = __float2bfloat16(tile[tx][ty + i * 8]);
}

__global__ __launch_bounds__(256) void cvt_f32_bf16_k(const float* __restrict__ in,
                                                      bf16* __restrict__ out, long long n) {
  long long i = ((long long)blockIdx.x * 256 + threadIdx.x) * 4;
  if (i + 3 < n) {
    float4 v = *(const float4*)(in + i);
    out[i + 0] = __float2bfloat16(v.x);
    out[i + 1] = __float2bfloat16(v.y);
    out[i + 2] = __float2bfloat16(v.z);
    out[i + 3] = __float2bfloat16(v.w);
  }
}

__global__ __launch_bounds__(256) void pack3_k(const float* __restrict__ a,
                                               const float* __restrict__ b,
                                               const float* __restrict__ c,
                                               float* __restrict__ o) {
  int i = blockIdx.x * 256 + threadIdx.x;
  if (i < 1024) o[i] = a[i];
  else if (i < 2048) o[i] = b[i - 1024];
  else if (i < 3072) o[i] = c[i - 2048];
}

__global__ __launch_bounds__(1) void sentinel_k(float* __restrict__ o) { o[0] = 1.2345e7f; }

// ---------------- 128x128 bf16 MFMA GEMM (m97 structure + bijective XCD swizzle) -------
// R8: default round-robin block->XCD spread panel-sharing blocks across L2s (FFN1
// FETCH 69MB vs 19MB ideal, HBM-bound at 520GB/s). 1D grid + m204 bijective swizzle
// gives each XCD a contiguous x-fastest tile chunk -> A-panel L2-shared per XCD.
template <int ACT, bool OUTBF16, bool BIAS>
__global__ __launch_bounds__(256) void gemm_tn(const bf16* __restrict__ A,
                                               const bf16* __restrict__ Bt,
                                               const float* __restrict__ bias,
                                               float* __restrict__ Cf, bf16* __restrict__ Cb,
                                               int M, int N, int K) {
  __shared__ __align__(128) short As[128 * 32];
  __shared__ __align__(128) short Bs[128 * 32];
  int t = threadIdx.x;
  int lane = t & 63, wave = t >> 6;
  // bijective XCD swizzle (m204): hardware XCD = bid%8 gets contiguous logical chunk
  int nbx = N >> 7;
  int nwg = gridDim.x;
  int q = nwg >> 3, r = nwg & 7;
  int xcd = blockIdx.x & 7, lid = blockIdx.x >> 3;
  int swz = (xcd < r ? xcd * (q + 1) : r * (q + 1) + (xcd - r) * q) + lid;
  int by = swz / nbx, bx = swz - by * nbx;
  int m0 = by << 7, n0 = bx << 7;
  int wr = wave >> 1, wc = wave & 1;
  int fr = lane & 15;
  int fk = (lane >> 4) << 3;

  f32x4 acc[4][4] = {};

  int row0 = t >> 2, ko0 = (t & 3) << 3;
  int row1 = 64 + (t >> 2), ko1 = ko0;
  short* lpA0 = As + (size_t)(wave * 64) * 8;
  short* lpA1 = As + (size_t)(256 + wave * 64) * 8;
  short* lpB0 = Bs + (size_t)(wave * 64) * 8;
  short* lpB1 = Bs + (size_t)(256 + wave * 64) * 8;

  const short* ArdBase = As + ((wr * 64 + fr) * 32 + fk);
  const short* BrdBase = Bs + ((wc * 64 + fr) * 32 + fk);

  const bf16* Ag0 = A + (size_t)(m0 + row0) * K + ko0;
  const bf16* Ag1 = A + (size_t)(m0 + row1) * K + ko1;
  const bf16* Bg0 = Bt + (size_t)(n0 + row0) * K + ko0;
  const bf16* Bg1 = Bt + (size_t)(n0 + row1) * K + ko1;

  int nk = K >> 5;
  for (int kt = 0; kt < nk; ++kt) {
    int k0 = kt << 5;
    GLOAD_LDS16(Ag0 + k0, lpA0);
    GLOAD_LDS16(Ag1 + k0, lpA1);
    GLOAD_LDS16(Bg0 + k0, lpB0);
    GLOAD_LDS16(Bg1 + k0, lpB1);
    __syncthreads();
    bf16x8 af[4], bfv[4];
#pragma unroll
    for (int a = 0; a < 4; ++a) af[a] = *(const bf16x8*)(ArdBase + a * 512);
#pragma unroll
    for (int b = 0; b < 4; ++b) bfv[b] = *(const bf16x8*)(BrdBase + b * 512);
#pragma unroll
    for (int a = 0; a < 4; ++a)
#pragma unroll
      for (int b = 0; b < 4; ++b) MFMA16(acc[a][b], af[a], bfv[b]);
    __syncthreads();
  }
  int lr = (lane >> 4) << 2;
  int lc = lane & 15;
#pragma unroll
  for (int a = 0; a < 4; ++a) {
#pragma unroll
    for (int b = 0; b < 4; ++b) {
      int col = n0 + wc * 64 + b * 16 + lc;
      float bv = 0.0f;
      if constexpr (BIAS) bv = bias[col];
#pragma unroll
      for (int j = 0; j < 4; ++j) {
        int rowi = m0 + wr * 64 + a * 16 + lr + j;
        float v = acc[a][b][j] + bv;
        if constexpr (ACT == 1) v = silu_f(v);
        if constexpr (ACT == 2) v = mish_f(v);
        if constexpr (OUTBF16) Cb[(size_t)rowi * N + col] = __float2bfloat16(v);
        else Cf[(size_t)rowi * N + col] = v;
      }
    }
  }
}

// ---------------- c = xb @ sc_w : [8192,1024]bf16 @ [1024,32]f32 -> bf16 [8192,32] -----
__global__ __launch_bounds__(256) void c_kernel(const bf16* __restrict__ xb,
                                                const float* __restrict__ scw,
                                                bf16* __restrict__ cout) {
  __shared__ float Xs[8][1024];
  int t = threadIdx.x;
  int row0 = blockIdx.x * 8;
#pragma unroll
  for (int i = 0; i < 4; ++i) {
    int idx = (t + i * 256) * 8;  // 8 bf16 per thread-iter
    bf16x8 v = *(const bf16x8*)(xb + (size_t)row0 * 1024 + idx);
#pragma unroll
    for (int j = 0; j < 8; ++j)
      Xs[(idx + j) >> 10][(idx + j) & 1023] = bfu2f((unsigned short)v[j]);
  }
  __syncthreads();
  int r = t >> 5, n = t & 31;
  float acc = 0.0f;
#pragma unroll 4
  for (int k = 0; k < 1024; ++k) acc += Xs[r][k] * scw[k * 32 + n];
  cout[(size_t)(row0 + r) * 32 + n] = __float2bfloat16(acc);
}

// ---------------- LN over 256 cols: hb = LN(hpre) -> bf16 ------------------------------
__global__ __launch_bounds__(256) void ln256_kernel(const float* __restrict__ hpre,
                                                    const float* __restrict__ gam,
                                                    const float* __restrict__ bet,
                                                    bf16* __restrict__ hb) {
  __shared__ float rsm[4], rs2[4], st2[2];
  int t = threadIdx.x, row = blockIdx.x;
  float sv = hpre[(size_t)row * 256 + t];
  float s = sv, s2 = sv * sv;
#pragma unroll
  for (int o = 32; o > 0; o >>= 1) { s += __shfl_down(s, o); s2 += __shfl_down(s2, o); }
  if ((t & 63) == 0) { rsm[t >> 6] = s; rs2[t >> 6] = s2; }
  __syncthreads();
  if (t == 0) {
    float a = rsm[0] + rsm[1] + rsm[2] + rsm[3];
    float b2 = rs2[0] + rs2[1] + rs2[2] + rs2[3];
    float m = a * (1.0f / 256.0f);
    st2[0] = m;
    st2[1] = rsqrtf(b2 * (1.0f / 256.0f) - m * m + LN_EPS);
  }
  __syncthreads();
  float y = (sv - st2[0]) * st2[1] * gam[t] + bet[t];
  hb[(size_t)row * 256 + t] = __float2bfloat16(y);
}

// ---------------- LN over 8192 cols (smolgen g) -> bf16 --------------------------------
__global__ __launch_bounds__(1024) void ln8192_kernel(const float* __restrict__ gpre,
                                                      const float* __restrict__ gam,
                                                      const float* __restrict__ bet,
                                                      bf16* __restrict__ gb) {
  __shared__ float rsm[16], rs2[16], st2[2];
  int t = threadIdx.x, row = blockIdx.x;
  const float* p = gpre + (size_t)row * 8192;
  float v[8];
  float s = 0.0f, s2 = 0.0f;
#pragma unroll
  for (int i = 0; i < 8; ++i) {
    v[i] = p[t + i * 1024];
    s += v[i];
    s2 += v[i] * v[i];
  }
#pragma unroll
  for (int o = 32; o > 0; o >>= 1) { s += __shfl_down(s, o); s2 += __shfl_down(s2, o); }
  int lane = t & 63, w = t >> 6;
  if (lane == 0) { rsm[w] = s; rs2[w] = s2; }
  __syncthreads();
  if (t == 0) {
    float a = 0.0f, b2 = 0.0f;
#pragma unroll
    for (int i = 0; i < 16; ++i) { a += rsm[i]; b2 += rs2[i]; }
    float m = a * (1.0f / 8192.0f);
    st2[0] = m;
    st2[1] = rsqrtf(b2 * (1.0f / 8192.0f) - m * m + LN_EPS);
  }
  __syncthreads();
  float m = st2[0], r = st2[1];
#pragma unroll
  for (int i = 0; i < 8; ++i) {
    int n = t + i * 1024;
    gb[(size_t)row * 8192 + n] = __float2bfloat16((v[i] - m) * r * gam[n] + bet[n]);
  }
}

// ---------------- residual + LN over 1024 cols (f32 base, bf16 delta) ------------------
__global__ __launch_bounds__(256) void ln_residual_kernel(const float* __restrict__ base,
                                                          const bf16* __restrict__ delta,
                                                          const float* __restrict__ gam,
                                                          const float* __restrict__ bet,
                                                          float* __restrict__ outf,
                                                          bf16* __restrict__ outb) {
  __shared__ float rsm[4], rs2[4], st2[2];
  int t = threadIdx.x, row = blockIdx.x;
  float4 bv = ((const float4*)(base + (size_t)row * 1024))[t];
  ushort4 du = ((const ushort4*)(delta + (size_t)row * 1024))[t];
  float4 v;
  v.x = bv.x + bfu2f(du.x) * ALPHA_F;
  v.y = bv.y + bfu2f(du.y) * ALPHA_F;
  v.z = bv.z + bfu2f(du.z) * ALPHA_F;
  v.w = bv.w + bfu2f(du.w) * ALPHA_F;
  float s = v.x + v.y + v.z + v.w;
  float s2 = v.x * v.x + v.y * v.y + v.z * v.z + v.w * v.w;
#pragma unroll
  for (int o = 32; o > 0; o >>= 1) { s += __shfl_down(s, o); s2 += __shfl_down(s2, o); }
  if ((t & 63) == 0) { rsm[t >> 6] = s; rs2[t >> 6] = s2; }
  __syncthreads();
  if (t == 0) {
    float a = rsm[0] + rsm[1] + rsm[2] + rsm[3];
    float b2 = rs2[0] + rs2[1] + rs2[2] + rs2[3];
    float m = a * (1.0f / 1024.0f);
    st2[0] = m;
    st2[1] = rsqrtf(b2 * (1.0f / 1024.0f) - m * m + LN_EPS);
  }
  __syncthreads();
  float m = st2[0], r = st2[1];
  float4 g4 = ((const float4*)gam)[t];
  float4 b4 = ((const float4*)bet)[t];
  float4 y;
  y.x = (v.x - m) * r * g4.x + b4.x;
  y.y = (v.y - m) * r * g4.y + b4.y;
  y.z = (v.z - m) * r * g4.z + b4.z;
  y.w = (v.w - m) * r * g4.w + b4.w;
  ((float4*)(outf + (size_t)row * 1024))[t] = y;
  ushort4 o4;
  o4.x = f2bfu(y.x); o4.y = f2bfu(y.y); o4.z = f2bfu(y.z); o4.w = f2bfu(y.w);
  ((ushort4*)(outb + (size_t)row * 1024))[t] = o4;
}

// ---------------- MFMA fused attention per (b,h) ---------------------------------------
__global__ __launch_bounds__(256) void attn_kernel(const bf16* __restrict__ qkv,
                                                   const bf16* __restrict__ sw,
                                                   bf16* __restrict__ avb) {
  __shared__ __align__(16) short Vt[32 * 72];
  __shared__ __align__(16) short Sw[64 * 64];
  __shared__ __align__(16) short Pl[64 * 72];
  const int t = threadIdx.x, lane = t & 63, w = t >> 6;
  const int fr = lane & 15, s4 = lane >> 4;
  const int bh = blockIdx.x, b = bh >> 5, h = bh & 31;
  const size_t qb = (size_t)b * 64 * 3072 + h * 32;
  // stage V transposed: Vt[d][k]
  {
    int k = t >> 2, d0 = (t & 3) * 8;
    bf16x8 v = *(const bf16x8*)(qkv + qb + (size_t)k * 3072 + 2048 + d0);
#pragma unroll
    for (int i = 0; i < 8; ++i) Vt[(d0 + i) * 72 + k] = v[i];
  }
  // stage sw bias [64][64]
  {
    const bf16* swp = sw + (size_t)bh * 4096;
    *(bf16x8*)(Sw + t * 8) = *(const bf16x8*)(swp + t * 8);
    *(bf16x8*)(Sw + 2048 + t * 8) = *(const bf16x8*)(swp + 2048 + t * 8);
  }
  __syncthreads();
  // QK^T: S[16 rows][64 cols] per wave
  f32x4 acc[4] = {};
  {
    bf16x8 aq = *(const bf16x8*)(qkv + qb + (size_t)(16 * w + fr) * 3072 + s4 * 8);
#pragma unroll
    for (int n = 0; n < 4; ++n) {
      bf16x8 bk = *(const bf16x8*)(qkv + qb + (size_t)(n * 16 + fr) * 3072 + 1024 + s4 * 8);
      acc[n] = __builtin_amdgcn_mfma_f32_16x16x32_bf16(aq, bk, acc[n], 0, 0, 0);
    }
  }
  // softmax over k for rows q = 16w + s4*4 + j (cols n*16+fr per lane)
  float rinv[4];
#pragma unroll
  for (int j = 0; j < 4; ++j) {
    int q = 16 * w + s4 * 4 + j;
    float pv[4];
    float mx = -1e30f;
#pragma unroll
    for (int n = 0; n < 4; ++n) {
      float v = acc[n][j] * 0.17677669529663687f +
                __bfloat162float(((const bf16*)Sw)[q * 64 + n * 16 + fr]);
      pv[n] = v;
      mx = fmaxf(mx, v);
    }
    mx = fmaxf(mx, __shfl_xor(mx, 1));
    mx = fmaxf(mx, __shfl_xor(mx, 2));
    mx = fmaxf(mx, __shfl_xor(mx, 4));
    mx = fmaxf(mx, __shfl_xor(mx, 8));
    float sum = 0.0f;
#pragma unroll
    for (int n = 0; n < 4; ++n) {
      float e = __expf(pv[n] - mx);
      sum += e;
      ((bf16*)Pl)[q * 72 + n * 16 + fr] = __float2bfloat16(e);
    }
    sum += __shfl_xor(sum, 1);
    sum += __shfl_xor(sum, 2);
    sum += __shfl_xor(sum, 4);
    sum += __shfl_xor(sum, 8);
    rinv[j] = 1.0f / sum;
  }
  __syncthreads();
  // PV: out[16 rows][32 d] per wave
  f32x4 acc2[2] = {};
#pragma unroll
  for (int kt = 0; kt < 2; ++kt) {
    bf16x8 ap = *(const bf16x8*)(Pl + (16 * w + fr) * 72 + kt * 32 + s4 * 8);
#pragma unroll
    for (int n2 = 0; n2 < 2; ++n2) {
      bf16x8 bv = *(const bf16x8*)(Vt + (n2 * 16 + fr) * 72 + kt * 32 + s4 * 8);
      acc2[n2] = __builtin_amdgcn_mfma_f32_16x16x32_bf16(ap, bv, acc2[n2], 0, 0, 0);
    }
  }
#pragma unroll
  for (int n2 = 0; n2 < 2; ++n2) {
#pragma unroll
    for (int j = 0; j < 4; ++j) {
      int q = 16 * w + s4 * 4 + j;
      int d = n2 * 16 + fr;
      avb[(size_t)(b * 64 + q) * 1024 + h * 32 + d] =
          __float2bfloat16(acc2[n2][j] * rinv[j]);
    }
  }
}

extern "C" void kernel_launch(void* const* d_in, const int* in_sizes, int n_in,
                              void* d_out, int out_size, void* d_ws, size_t ws_size,
                              hipStream_t stream) {
  const float* x_in   = (const float*)d_in[0];
  const float* wq_w   = (const float*)d_in[1];
  const float* wq_b   = (const float*)d_in[2];
  const float* wk_w   = (const float*)d_in[3];
  const float* wk_b   = (const float*)d_in[4];
  const float* wv_w   = (const float*)d_in[5];
  const float* wv_b   = (const float*)d_in[6];
  const float* wo_w   = (const float*)d_in[7];
  const float* wo_b   = (const float*)d_in[8];
  const float* sc_w   = (const float*)d_in[9];
  const float* sh1_w  = (const float*)d_in[10];
  const float* sh1_b  = (const float*)d_in[11];
  const float* sln1_g = (const float*)d_in[12];
  const float* sln1_b = (const float*)d_in[13];
  const float* sgf_w  = (const float*)d_in[14];
  const float* sgf_b  = (const float*)d_in[15];
  const float* sln2_g = (const float*)d_in[16];
  const float* sln2_b = (const float*)d_in[17];
  const float* swg_w  = (const float*)d_in[18];
  const float* ffn1_w = (const float*)d_in[19];
  const float* ffn1_b = (const float*)d_in[20];
  const float* ffn2_w = (const float*)d_in[21];
  const float* ffn2_b = (const float*)d_in[22];
  const float* n1_g   = (const float*)d_in[23];
  const float* n1_b   = (const float*)d_in[24];
  const float* n2_g   = (const float*)d_in[25];
  const float* n2_b   = (const float*)d_in[26];

  char* ws = (char*)d_ws;
  size_t off = 0;
  auto alloc = [&](size_t bytes) -> void* {
    void* p = ws + off;
    off += (bytes + 255) & ~(size_t)255;
    return p;
  };
  bf16*  xb    = (bf16*)alloc(8192ULL * 1024 * 2);
  float* P0    = (float*)alloc(8192ULL * 1024 * 4);
  float* P1    = (float*)alloc(8192ULL * 1024 * 4);
  bf16*  dT    = (bf16*)alloc(8192ULL * 1024 * 2);
  bf16*  Wqkv  = (bf16*)alloc(3072ULL * 1024 * 2);
  float* bqkv  = (float*)alloc(3072ULL * 4);
  bf16*  Wo    = (bf16*)alloc(1024ULL * 1024 * 2);
  bf16*  Wf1   = (bf16*)alloc(1536ULL * 1024 * 2);
  bf16*  Wf2   = (bf16*)alloc(1024ULL * 1536 * 2);
  bf16*  Wsgf  = (bf16*)alloc(8192ULL * 256 * 2);
  bf16*  Wswg  = (bf16*)alloc(4096ULL * 256 * 2);
  bf16*  Wsh1  = (bf16*)alloc(256ULL * 2048 * 2);
  bf16*  qkvb  = (bf16*)alloc(8192ULL * 3072 * 2);
  bf16*  cbuf  = (bf16*)alloc(8192ULL * 32 * 2);
  float* hpre  = (float*)alloc(128ULL * 256 * 4);
  bf16*  hbb   = (bf16*)alloc(128ULL * 256 * 2);
  float* gpre  = (float*)alloc(128ULL * 8192 * 4);
  bf16*  gbb   = (bf16*)alloc(128ULL * 8192 * 2);
  bf16*  swb   = (bf16*)alloc(4096ULL * 4096 * 2);
  bf16*  avb   = (bf16*)alloc(8192ULL * 1024 * 2);
  bf16*  out1b = (bf16*)alloc(8192ULL * 1024 * 2);
  bf16*  f1b   = (bf16*)alloc(8192ULL * 1536 * 2);
  if (off > ws_size) {
    sentinel_k<<<1, 1, 0, stream>>>((float*)d_out);
    return;
  }

  cvt_f32_bf16_k<<<8192, 256, 0, stream>>>(x_in, xb, 8192LL * 1024);

  for (int l = 0; l < 15; ++l) {
    const float* wq   = wq_w + (size_t)l * 1024 * 1024;
    const float* wk   = wk_w + (size_t)l * 1024 * 1024;
    const float* wv   = wv_w + (size_t)l * 1024 * 1024;
    const float* wo   = wo_w + (size_t)l * 1024 * 1024;
    const float* f1w  = ffn1_w + (size_t)l * 1024 * 1536;
    const float* f2w  = ffn2_w + (size_t)l * 1536 * 1024;
    const float* sgf  = sgf_w + (size_t)l * 256 * 8192;
    const float* swg  = swg_w + (size_t)l * 256 * 4096;
    const float* scw  = sc_w + (size_t)l * 1024 * 32;
    const float* sh1w = sh1_w + (size_t)l * 2048 * 256;

    transpose_layer<<<10752, 256, 0, stream>>>(wq, wk, wv, wo, f1w, f2w, sgf, swg, sh1w,
                                               Wqkv, Wo, Wf1, Wf2, Wsgf, Wswg, Wsh1);
    pack3_k<<<12, 256, 0, stream>>>(wq_b + l * 1024, wk_b + l * 1024, wv_b + l * 1024, bqkv);

    const float* xc = (l == 0) ? x_in : ((l & 1) ? P0 : P1);
    float* Pout = (l & 1) ? P1 : P0;

    // QKV projection
    gemm_tn<0, true, true><<<1536, 256, 0, stream>>>(xb, Wqkv, bqkv, nullptr, qkvb,
                                                     8192, 3072, 1024);
    // smolgen chain
    c_kernel<<<1024, 256, 0, stream>>>(xb, scw, cbuf);
    gemm_tn<1, false, true><<<2, 256, 0, stream>>>(cbuf, Wsh1, sh1_b + l * 256,
                                                   hpre, nullptr, 128, 256, 2048);
    ln256_kernel<<<128, 256, 0, stream>>>(hpre, sln1_g + l * 256, sln1_b + l * 256, hbb);
    gemm_tn<1, false, true><<<64, 256, 0, stream>>>(hbb, Wsgf, sgf_b + (size_t)l * 8192,
                                                    gpre, nullptr, 128, 8192, 256);
    ln8192_kernel<<<128, 1024, 0, stream>>>(gpre, sln2_g + (size_t)l * 8192,
                                            sln2_b + (size_t)l * 8192, gbb);
    gemm_tn<0, true, false><<<1024, 256, 0, stream>>>(gbb, Wswg, nullptr, nullptr, swb,
                                                      4096, 4096, 256);
    // attention (MFMA)
    attn_kernel<<<4096, 256, 0, stream>>>(qkvb, swb, avb);
    // output projection + LN1 (bf16 delta)
    gemm_tn<0, true, true><<<512, 256, 0, stream>>>(avb, Wo, wo_b + l * 1024, nullptr, dT,
                                                    8192, 1024, 1024);
    ln_residual_kernel<<<8192, 256, 0, stream>>>(xc, dT, n1_g + l * 1024, n1_b + l * 1024,
                                                 Pout, out1b);
    // FFN + LN2 (bf16 delta)
    gemm_tn<2, true, true><<<768, 256, 0, stream>>>(out1b, Wf1, ffn1_b + l * 1536,
                                                    nullptr, f1b, 8192, 1536, 1024);
    gemm_tn<0, true, true><<<512, 256, 0, stream>>>(f1b, Wf2, ffn2_b + l * 1024, nullptr, dT,
                                                    8192, 1024, 1536);
    float* xnext = (l == 14) ? (float*)d_out : Pout;
    ln_residual_kernel<<<8192, 256, 0, stream>>>(Pout, dT, n2_g + l * 1024, n2_b + l * 1024,
                                                 xnext, xb);
  }
}

// Round 10
// 8766.946 us; speedup vs baseline: 1.9072x; 1.0217x over previous
//
#include <hip/hip_runtime.h>
#include <hip/hip_bf16.h>

typedef __attribute__((ext_vector_type(8))) short bf16x8;
typedef __attribute__((ext_vector_type(4))) float f32x4;
typedef __hip_bfloat16 bf16;

#define ALPHA_F 0.42728713f
#define LN_EPS 1e-3f

__device__ __forceinline__ float silu_f(float x) { return x / (1.0f + __expf(-x)); }
__device__ __forceinline__ float mish_f(float x) {
  float sp = (x > 20.0f) ? x : log1pf(__expf(x));
  return x * tanhf(sp);
}
__device__ __forceinline__ unsigned short f2bfu(float x) {
  bf16 h = __float2bfloat16(x);
  return *(unsigned short*)&h;
}
__device__ __forceinline__ float bfu2f(unsigned short u) {
  unsigned int v = (unsigned int)u << 16;
  return *(float*)&v;
}

// Builtin MFMA: LLVM sees real dataflow -> acc lives in AGPRs.
#define MFMA16(acc, a, b) \
  (acc) = __builtin_amdgcn_mfma_f32_16x16x32_bf16((a), (b), (acc), 0, 0, 0)

#define GLOAD_LDS16(gp, lp)                                                              \
  __builtin_amdgcn_global_load_lds((__attribute__((address_space(1))) void*)(void*)(gp), \
                                   (__attribute__((address_space(3))) void*)(void*)(lp), \
                                   16, 0, 0)

// ---------------- batched per-layer weight transpose: W[K,N] f32 -> Wt[N,K] bf16 -------
__global__ __launch_bounds__(256) void transpose_layer(
    const float* __restrict__ wq, const float* __restrict__ wk, const float* __restrict__ wv,
    const float* __restrict__ wo, const float* __restrict__ f1, const float* __restrict__ f2,
    const float* __restrict__ sgf, const float* __restrict__ swg, const float* __restrict__ sh1,
    bf16* __restrict__ Wqkv, bf16* __restrict__ Wo, bf16* __restrict__ Wf1,
    bf16* __restrict__ Wf2, bf16* __restrict__ Wsgf, bf16* __restrict__ Wswg,
    bf16* __restrict__ Wsh1) {
  __shared__ float tile[32][33];
  int b = blockIdx.x;
  const float* W;
  bf16* Wt;
  int K, N, tb;
  if (b < 3072) {
    int m = b >> 10;
    W = (m == 0) ? wq : ((m == 1) ? wk : wv);
    Wt = Wqkv + (size_t)m * 1024 * 1024;
    K = 1024; N = 1024; tb = b & 1023;
  } else if (b < 4096)  { W = wo;  Wt = Wo;   K = 1024; N = 1024; tb = b - 3072; }
  else if (b < 5632)    { W = f1;  Wt = Wf1;  K = 1024; N = 1536; tb = b - 4096; }
  else if (b < 7168)    { W = f2;  Wt = Wf2;  K = 1536; N = 1024; tb = b - 5632; }
  else if (b < 9216)    { W = sgf; Wt = Wsgf; K = 256;  N = 8192; tb = b - 7168; }
  else if (b < 10240)   { W = swg; Wt = Wswg; K = 256;  N = 4096; tb = b - 9216; }
  else                  { W = sh1; Wt = Wsh1; K = 2048; N = 256;  tb = b - 10240; }
  int ntx = N >> 5;
  int ty_ = tb / ntx, tx_ = tb - ty_ * ntx;
  int nb = tx_ * 32, kb = ty_ * 32;
  int tx = threadIdx.x & 31, ty = threadIdx.x >> 5;
#pragma unroll
  for (int i = 0; i < 4; ++i)
    tile[ty + i * 8][tx] = W[(size_t)(kb + ty + i * 8) * N + nb + tx];
  __syncthreads();
#pragma unroll
  for (int i = 0; i < 4; ++i)
    Wt[(size_t)(nb + ty + i * 8) * K + kb + tx] = __float2bfloat16(tile[tx][ty + i * 8]);
}

__global__ __launch_bounds__(256) void cvt_f32_bf16_k(const float* __restrict__ in,
                                                      bf16* __restrict__ out, long long n) {
  long long i = ((long long)blockIdx.x * 256 + threadIdx.x) * 4;
  if (i + 3 < n) {
    float4 v = *(const float4*)(in + i);
    out[i + 0] = __float2bfloat16(v.x);
    out[i + 1] = __float2bfloat16(v.y);
    out[i + 2] = __float2bfloat16(v.z);
    out[i + 3] = __float2bfloat16(v.w);
  }
}

__global__ __launch_bounds__(256) void pack3_k(const float* __restrict__ a,
                                               const float* __restrict__ b,
                                               const float* __restrict__ c,
                                               float* __restrict__ o) {
  int i = blockIdx.x * 256 + threadIdx.x;
  if (i < 1024) o[i] = a[i];
  else if (i < 2048) o[i] = b[i - 1024];
  else if (i < 3072) o[i] = c[i - 2048];
}

__global__ __launch_bounds__(1) void sentinel_k(float* __restrict__ o) { o[0] = 1.2345e7f; }

// ---------------- 128x128 bf16 MFMA GEMM, 2-phase double-buffered (T3 minimum) ---------
// R9: single-buffered 2-barrier loop exposed full load latency per K-tile (FFN1 142 TF,
// MfmaUtil 5.5%, on m102's documented small-shape curve). 2-phase: issue next tile's
// global_load_lds into the OTHER buffer BEFORE consuming current; one __syncthreads per
// tile (its vmcnt(0)+lgkm drain == the recipe's "vmcnt(0); barrier"). Measured 622 TF at
// 128^2 (m228d). XCD swizzle kept (R8: FETCH 69->21MB).
template <int ACT, bool OUTBF16, bool BIAS>
__global__ __launch_bounds__(256) void gemm_tn(const bf16* __restrict__ A,
                                               const bf16* __restrict__ Bt,
                                               const float* __restrict__ bias,
                                               float* __restrict__ Cf, bf16* __restrict__ Cb,
                                               int M, int N, int K) {
  __shared__ __align__(128) short As[2][128 * 32];
  __shared__ __align__(128) short Bs[2][128 * 32];
  int t = threadIdx.x;
  int lane = t & 63, wave = t >> 6;
  // bijective XCD swizzle (m204)
  int nbx = N >> 7;
  int nwg = gridDim.x;
  int q = nwg >> 3, r = nwg & 7;
  int xcd = blockIdx.x & 7, lid = blockIdx.x >> 3;
  int swz = (xcd < r ? xcd * (q + 1) : r * (q + 1) + (xcd - r) * q) + lid;
  int by = swz / nbx, bx = swz - by * nbx;
  int m0 = by << 7, n0 = bx << 7;
  int wr = wave >> 1, wc = wave & 1;
  int fr = lane & 15;
  int fk = (lane >> 4) << 3;

  f32x4 acc[4][4] = {};

  int row0 = t >> 2, ko0 = (t & 3) << 3;
  int row1 = 64 + (t >> 2);

  const bf16* Ag0 = A + (size_t)(m0 + row0) * K + ko0;
  const bf16* Ag1 = A + (size_t)(m0 + row1) * K + ko0;
  const bf16* Bg0 = Bt + (size_t)(n0 + row0) * K + ko0;
  const bf16* Bg1 = Bt + (size_t)(n0 + row1) * K + ko0;

  auto stageTo = [&](short* Ab, short* Bb, int k0) {
    GLOAD_LDS16(Ag0 + k0, Ab + wave * 512);
    GLOAD_LDS16(Ag1 + k0, Ab + 2048 + wave * 512);
    GLOAD_LDS16(Bg0 + k0, Bb + wave * 512);
    GLOAD_LDS16(Bg1 + k0, Bb + 2048 + wave * 512);
  };

  int nk = K >> 5;
  stageTo(As[0], Bs[0], 0);
  __syncthreads();  // vmcnt(0) drain: tile 0 resident

  const int rdA = (wr * 64 + fr) * 32 + fk;
  const int rdB = (wc * 64 + fr) * 32 + fk;

  for (int kt = 0; kt < nk; ++kt) {
    int cur = kt & 1;
    if (kt + 1 < nk) stageTo(As[cur ^ 1], Bs[cur ^ 1], (kt + 1) << 5);
    const short* Ard = As[cur] + rdA;
    const short* Brd = Bs[cur] + rdB;
    bf16x8 af[4], bfv[4];
#pragma unroll
    for (int a = 0; a < 4; ++a) af[a] = *(const bf16x8*)(Ard + a * 512);
#pragma unroll
    for (int b = 0; b < 4; ++b) bfv[b] = *(const bf16x8*)(Brd + b * 512);
#pragma unroll
    for (int a = 0; a < 4; ++a)
#pragma unroll
      for (int b = 0; b < 4; ++b) MFMA16(acc[a][b], af[a], bfv[b]);
    __syncthreads();  // drains prefetch (vmcnt 0) + all waves' lds reads of buf[cur]
  }
  int lr = (lane >> 4) << 2;
  int lc = lane & 15;
#pragma unroll
  for (int a = 0; a < 4; ++a) {
#pragma unroll
    for (int b = 0; b < 4; ++b) {
      int col = n0 + wc * 64 + b * 16 + lc;
      float bv = 0.0f;
      if constexpr (BIAS) bv = bias[col];
#pragma unroll
      for (int j = 0; j < 4; ++j) {
        int rowi = m0 + wr * 64 + a * 16 + lr + j;
        float v = acc[a][b][j] + bv;
        if constexpr (ACT == 1) v = silu_f(v);
        if constexpr (ACT == 2) v = mish_f(v);
        if constexpr (OUTBF16) Cb[(size_t)rowi * N + col] = __float2bfloat16(v);
        else Cf[(size_t)rowi * N + col] = v;
      }
    }
  }
}

// ---------------- c = xb @ sc_w : [8192,1024]bf16 @ [1024,32]f32 -> bf16 [8192,32] -----
__global__ __launch_bounds__(256) void c_kernel(const bf16* __restrict__ xb,
                                                const float* __restrict__ scw,
                                                bf16* __restrict__ cout) {
  __shared__ float Xs[8][1024];
  int t = threadIdx.x;
  int row0 = blockIdx.x * 8;
#pragma unroll
  for (int i = 0; i < 4; ++i) {
    int idx = (t + i * 256) * 8;  // 8 bf16 per thread-iter
    bf16x8 v = *(const bf16x8*)(xb + (size_t)row0 * 1024 + idx);
#pragma unroll
    for (int j = 0; j < 8; ++j)
      Xs[(idx + j) >> 10][(idx + j) & 1023] = bfu2f((unsigned short)v[j]);
  }
  __syncthreads();
  int r = t >> 5, n = t & 31;
  float acc = 0.0f;
#pragma unroll 4
  for (int k = 0; k < 1024; ++k) acc += Xs[r][k] * scw[k * 32 + n];
  cout[(size_t)(row0 + r) * 32 + n] = __float2bfloat16(acc);
}

// ---------------- LN over 256 cols: hb = LN(hpre) -> bf16 ------------------------------
__global__ __launch_bounds__(256) void ln256_kernel(const float* __restrict__ hpre,
                                                    const float* __restrict__ gam,
                                                    const float* __restrict__ bet,
                                                    bf16* __restrict__ hb) {
  __shared__ float rsm[4], rs2[4], st2[2];
  int t = threadIdx.x, row = blockIdx.x;
  float sv = hpre[(size_t)row * 256 + t];
  float s = sv, s2 = sv * sv;
#pragma unroll
  for (int o = 32; o > 0; o >>= 1) { s += __shfl_down(s, o); s2 += __shfl_down(s2, o); }
  if ((t & 63) == 0) { rsm[t >> 6] = s; rs2[t >> 6] = s2; }
  __syncthreads();
  if (t == 0) {
    float a = rsm[0] + rsm[1] + rsm[2] + rsm[3];
    float b2 = rs2[0] + rs2[1] + rs2[2] + rs2[3];
    float m = a * (1.0f / 256.0f);
    st2[0] = m;
    st2[1] = rsqrtf(b2 * (1.0f / 256.0f) - m * m + LN_EPS);
  }
  __syncthreads();
  float y = (sv - st2[0]) * st2[1] * gam[t] + bet[t];
  hb[(size_t)row * 256 + t] = __float2bfloat16(y);
}

// ---------------- LN over 8192 cols (smolgen g) -> bf16 --------------------------------
__global__ __launch_bounds__(1024) void ln8192_kernel(const float* __restrict__ gpre,
                                                      const float* __restrict__ gam,
                                                      const float* __restrict__ bet,
                                                      bf16* __restrict__ gb) {
  __shared__ float rsm[16], rs2[16], st2[2];
  int t = threadIdx.x, row = blockIdx.x;
  const float* p = gpre + (size_t)row * 8192;
  float v[8];
  float s = 0.0f, s2 = 0.0f;
#pragma unroll
  for (int i = 0; i < 8; ++i) {
    v[i] = p[t + i * 1024];
    s += v[i];
    s2 += v[i] * v[i];
  }
#pragma unroll
  for (int o = 32; o > 0; o >>= 1) { s += __shfl_down(s, o); s2 += __shfl_down(s2, o); }
  int lane = t & 63, w = t >> 6;
  if (lane == 0) { rsm[w] = s; rs2[w] = s2; }
  __syncthreads();
  if (t == 0) {
    float a = 0.0f, b2 = 0.0f;
#pragma unroll
    for (int i = 0; i < 16; ++i) { a += rsm[i]; b2 += rs2[i]; }
    float m = a * (1.0f / 8192.0f);
    st2[0] = m;
    st2[1] = rsqrtf(b2 * (1.0f / 8192.0f) - m * m + LN_EPS);
  }
  __syncthreads();
  float m = st2[0], r = st2[1];
#pragma unroll
  for (int i = 0; i < 8; ++i) {
    int n = t + i * 1024;
    gb[(size_t)row * 8192 + n] = __float2bfloat16((v[i] - m) * r * gam[n] + bet[n]);
  }
}

// ---------------- residual + LN over 1024 cols (f32 base, bf16 delta) ------------------
__global__ __launch_bounds__(256) void ln_residual_kernel(const float* __restrict__ base,
                                                          const bf16* __restrict__ delta,
                                                          const float* __restrict__ gam,
                                                          const float* __restrict__ bet,
                                                          float* __restrict__ outf,
                                                          bf16* __restrict__ outb) {
  __shared__ float rsm[4], rs2[4], st2[2];
  int t = threadIdx.x, row = blockIdx.x;
  float4 bv = ((const float4*)(base + (size_t)row * 1024))[t];
  ushort4 du = ((const ushort4*)(delta + (size_t)row * 1024))[t];
  float4 v;
  v.x = bv.x + bfu2f(du.x) * ALPHA_F;
  v.y = bv.y + bfu2f(du.y) * ALPHA_F;
  v.z = bv.z + bfu2f(du.z) * ALPHA_F;
  v.w = bv.w + bfu2f(du.w) * ALPHA_F;
  float s = v.x + v.y + v.z + v.w;
  float s2 = v.x * v.x + v.y * v.y + v.z * v.z + v.w * v.w;
#pragma unroll
  for (int o = 32; o > 0; o >>= 1) { s += __shfl_down(s, o); s2 += __shfl_down(s2, o); }
  if ((t & 63) == 0) { rsm[t >> 6] = s; rs2[t >> 6] = s2; }
  __syncthreads();
  if (t == 0) {
    float a = rsm[0] + rsm[1] + rsm[2] + rsm[3];
    float b2 = rs2[0] + rs2[1] + rs2[2] + rs2[3];
    float m = a * (1.0f / 1024.0f);
    st2[0] = m;
    st2[1] = rsqrtf(b2 * (1.0f / 1024.0f) - m * m + LN_EPS);
  }
  __syncthreads();
  float m = st2[0], r = st2[1];
  float4 g4 = ((const float4*)gam)[t];
  float4 b4 = ((const float4*)bet)[t];
  float4 y;
  y.x = (v.x - m) * r * g4.x + b4.x;
  y.y = (v.y - m) * r * g4.y + b4.y;
  y.z = (v.z - m) * r * g4.z + b4.z;
  y.w = (v.w - m) * r * g4.w + b4.w;
  ((float4*)(outf + (size_t)row * 1024))[t] = y;
  ushort4 o4;
  o4.x = f2bfu(y.x); o4.y = f2bfu(y.y); o4.z = f2bfu(y.z); o4.w = f2bfu(y.w);
  ((ushort4*)(outb + (size_t)row * 1024))[t] = o4;
}

// ---------------- MFMA fused attention per (b,h) ---------------------------------------
__global__ __launch_bounds__(256) void attn_kernel(const bf16* __restrict__ qkv,
                                                   const bf16* __restrict__ sw,
                                                   bf16* __restrict__ avb) {
  __shared__ __align__(16) short Vt[32 * 72];
  __shared__ __align__(16) short Sw[64 * 64];
  __shared__ __align__(16) short Pl[64 * 72];
  const int t = threadIdx.x, lane = t & 63, w = t >> 6;
  const int fr = lane & 15, s4 = lane >> 4;
  const int bh = blockIdx.x, b = bh >> 5, h = bh & 31;
  const size_t qb = (size_t)b * 64 * 3072 + h * 32;
  // stage V transposed: Vt[d][k]
  {
    int k = t >> 2, d0 = (t & 3) * 8;
    bf16x8 v = *(const bf16x8*)(qkv + qb + (size_t)k * 3072 + 2048 + d0);
#pragma unroll
    for (int i = 0; i < 8; ++i) Vt[(d0 + i) * 72 + k] = v[i];
  }
  // stage sw bias [64][64]
  {
    const bf16* swp = sw + (size_t)bh * 4096;
    *(bf16x8*)(Sw + t * 8) = *(const bf16x8*)(swp + t * 8);
    *(bf16x8*)(Sw + 2048 + t * 8) = *(const bf16x8*)(swp + 2048 + t * 8);
  }
  __syncthreads();
  // QK^T: S[16 rows][64 cols] per wave
  f32x4 acc[4] = {};
  {
    bf16x8 aq = *(const bf16x8*)(qkv + qb + (size_t)(16 * w + fr) * 3072 + s4 * 8);
#pragma unroll
    for (int n = 0; n < 4; ++n) {
      bf16x8 bk = *(const bf16x8*)(qkv + qb + (size_t)(n * 16 + fr) * 3072 + 1024 + s4 * 8);
      acc[n] = __builtin_amdgcn_mfma_f32_16x16x32_bf16(aq, bk, acc[n], 0, 0, 0);
    }
  }
  // softmax over k for rows q = 16w + s4*4 + j (cols n*16+fr per lane)
  float rinv[4];
#pragma unroll
  for (int j = 0; j < 4; ++j) {
    int q = 16 * w + s4 * 4 + j;
    float pv[4];
    float mx = -1e30f;
#pragma unroll
    for (int n = 0; n < 4; ++n) {
      float v = acc[n][j] * 0.17677669529663687f +
                __bfloat162float(((const bf16*)Sw)[q * 64 + n * 16 + fr]);
      pv[n] = v;
      mx = fmaxf(mx, v);
    }
    mx = fmaxf(mx, __shfl_xor(mx, 1));
    mx = fmaxf(mx, __shfl_xor(mx, 2));
    mx = fmaxf(mx, __shfl_xor(mx, 4));
    mx = fmaxf(mx, __shfl_xor(mx, 8));
    float sum = 0.0f;
#pragma unroll
    for (int n = 0; n < 4; ++n) {
      float e = __expf(pv[n] - mx);
      sum += e;
      ((bf16*)Pl)[q * 72 + n * 16 + fr] = __float2bfloat16(e);
    }
    sum += __shfl_xor(sum, 1);
    sum += __shfl_xor(sum, 2);
    sum += __shfl_xor(sum, 4);
    sum += __shfl_xor(sum, 8);
    rinv[j] = 1.0f / sum;
  }
  __syncthreads();
  // PV: out[16 rows][32 d] per wave
  f32x4 acc2[2] = {};
#pragma unroll
  for (int kt = 0; kt < 2; ++kt) {
    bf16x8 ap = *(const bf16x8*)(Pl + (16 * w + fr) * 72 + kt * 32 + s4 * 8);
#pragma unroll
    for (int n2 = 0; n2 < 2; ++n2) {
      bf16x8 bv = *(const bf16x8*)(Vt + (n2 * 16 + fr) * 72 + kt * 32 + s4 * 8);
      acc2[n2] = __builtin_amdgcn_mfma_f32_16x16x32_bf16(ap, bv, acc2[n2], 0, 0, 0);
    }
  }
#pragma unroll
  for (int n2 = 0; n2 < 2; ++n2) {
#pragma unroll
    for (int j = 0; j < 4; ++j) {
      int q = 16 * w + s4 * 4 + j;
      int d = n2 * 16 + fr;
      avb[(size_t)(b * 64 + q) * 1024 + h * 32 + d] =
          __float2bfloat16(acc2[n2][j] * rinv[j]);
    }
  }
}

extern "C" void kernel_launch(void* const* d_in, const int* in_sizes, int n_in,
                              void* d_out, int out_size, void* d_ws, size_t ws_size,
                              hipStream_t stream) {
  const float* x_in   = (const float*)d_in[0];
  const float* wq_w   = (const float*)d_in[1];
  const float* wq_b   = (const float*)d_in[2];
  const float* wk_w   = (const float*)d_in[3];
  const float* wk_b   = (const float*)d_in[4];
  const float* wv_w   = (const float*)d_in[5];
  const float* wv_b   = (const float*)d_in[6];
  const float* wo_w   = (const float*)d_in[7];
  const float* wo_b   = (const float*)d_in[8];
  const float* sc_w   = (const float*)d_in[9];
  const float* sh1_w  = (const float*)d_in[10];
  const float* sh1_b  = (const float*)d_in[11];
  const float* sln1_g = (const float*)d_in[12];
  const float* sln1_b = (const float*)d_in[13];
  const float* sgf_w  = (const float*)d_in[14];
  const float* sgf_b  = (const float*)d_in[15];
  const float* sln2_g = (const float*)d_in[16];
  const float* sln2_b = (const float*)d_in[17];
  const float* swg_w  = (const float*)d_in[18];
  const float* ffn1_w = (const float*)d_in[19];
  const float* ffn1_b = (const float*)d_in[20];
  const float* ffn2_w = (const float*)d_in[21];
  const float* ffn2_b = (const float*)d_in[22];
  const float* n1_g   = (const float*)d_in[23];
  const float* n1_b   = (const float*)d_in[24];
  const float* n2_g   = (const float*)d_in[25];
  const float* n2_b   = (const float*)d_in[26];

  char* ws = (char*)d_ws;
  size_t off = 0;
  auto alloc = [&](size_t bytes) -> void* {
    void* p = ws + off;
    off += (bytes + 255) & ~(size_t)255;
    return p;
  };
  bf16*  xb    = (bf16*)alloc(8192ULL * 1024 * 2);
  float* P0    = (float*)alloc(8192ULL * 1024 * 4);
  float* P1    = (float*)alloc(8192ULL * 1024 * 4);
  bf16*  dT    = (bf16*)alloc(8192ULL * 1024 * 2);
  bf16*  Wqkv  = (bf16*)alloc(3072ULL * 1024 * 2);
  float* bqkv  = (float*)alloc(3072ULL * 4);
  bf16*  Wo    = (bf16*)alloc(1024ULL * 1024 * 2);
  bf16*  Wf1   = (bf16*)alloc(1536ULL * 1024 * 2);
  bf16*  Wf2   = (bf16*)alloc(1024ULL * 1536 * 2);
  bf16*  Wsgf  = (bf16*)alloc(8192ULL * 256 * 2);
  bf16*  Wswg  = (bf16*)alloc(4096ULL * 256 * 2);
  bf16*  Wsh1  = (bf16*)alloc(256ULL * 2048 * 2);
  bf16*  qkvb  = (bf16*)alloc(8192ULL * 3072 * 2);
  bf16*  cbuf  = (bf16*)alloc(8192ULL * 32 * 2);
  float* hpre  = (float*)alloc(128ULL * 256 * 4);
  bf16*  hbb   = (bf16*)alloc(128ULL * 256 * 2);
  float* gpre  = (float*)alloc(128ULL * 8192 * 4);
  bf16*  gbb   = (bf16*)alloc(128ULL * 8192 * 2);
  bf16*  swb   = (bf16*)alloc(4096ULL * 4096 * 2);
  bf16*  avb   = (bf16*)alloc(8192ULL * 1024 * 2);
  bf16*  out1b = (bf16*)alloc(8192ULL * 1024 * 2);
  bf16*  f1b   = (bf16*)alloc(8192ULL * 1536 * 2);
  if (off > ws_size) {
    sentinel_k<<<1, 1, 0, stream>>>((float*)d_out);
    return;
  }

  cvt_f32_bf16_k<<<8192, 256, 0, stream>>>(x_in, xb, 8192LL * 1024);

  for (int l = 0; l < 15; ++l) {
    const float* wq   = wq_w + (size_t)l * 1024 * 1024;
    const float* wk   = wk_w + (size_t)l * 1024 * 1024;
    const float* wv   = wv_w + (size_t)l * 1024 * 1024;
    const float* wo   = wo_w + (size_t)l * 1024 * 1024;
    const float* f1w  = ffn1_w + (size_t)l * 1024 * 1536;
    const float* f2w  = ffn2_w + (size_t)l * 1536 * 1024;
    const float* sgf  = sgf_w + (size_t)l * 256 * 8192;
    const float* swg  = swg_w + (size_t)l * 256 * 4096;
    const float* scw  = sc_w + (size_t)l * 1024 * 32;
    const float* sh1w = sh1_w + (size_t)l * 2048 * 256;

    transpose_layer<<<10752, 256, 0, stream>>>(wq, wk, wv, wo, f1w, f2w, sgf, swg, sh1w,
                                               Wqkv, Wo, Wf1, Wf2, Wsgf, Wswg, Wsh1);
    pack3_k<<<12, 256, 0, stream>>>(wq_b + l * 1024, wk_b + l * 1024, wv_b + l * 1024, bqkv);

    const float* xc = (l == 0) ? x_in : ((l & 1) ? P0 : P1);
    float* Pout = (l & 1) ? P1 : P0;

    // QKV projection
    gemm_tn<0, true, true><<<1536, 256, 0, stream>>>(xb, Wqkv, bqkv, nullptr, qkvb,
                                                     8192, 3072, 1024);
    // smolgen chain
    c_kernel<<<1024, 256, 0, stream>>>(xb, scw, cbuf);
    gemm_tn<1, false, true><<<2, 256, 0, stream>>>(cbuf, Wsh1, sh1_b + l * 256,
                                                   hpre, nullptr, 128, 256, 2048);
    ln256_kernel<<<128, 256, 0, stream>>>(hpre, sln1_g + l * 256, sln1_b + l * 256, hbb);
    gemm_tn<1, false, true><<<64, 256, 0, stream>>>(hbb, Wsgf, sgf_b + (size_t)l * 8192,
                                                    gpre, nullptr, 128, 8192, 256);
    ln8192_kernel<<<128, 1024, 0, stream>>>(gpre, sln2_g + (size_t)l * 8192,
                                            sln2_b + (size_t)l * 8192, gbb);
    gemm_tn<0, true, false><<<1024, 256, 0, stream>>>(gbb, Wswg, nullptr, nullptr, swb,
                                                      4096, 4096, 256);
    // attention (MFMA)
    attn_kernel<<<4096, 256, 0, stream>>>(qkvb, swb, avb);
    // output projection + LN1 (bf16 delta)
    gemm_tn<0, true, true><<<512, 256, 0, stream>>>(avb, Wo, wo_b + l * 1024, nullptr, dT,
                                                    8192, 1024, 1024);
    ln_residual_kernel<<<8192, 256, 0, stream>>>(xc, dT, n1_g + l * 1024, n1_b + l * 1024,
                                                 Pout, out1b);
    // FFN + LN2 (bf16 delta)
    gemm_tn<2, true, true><<<768, 256, 0, stream>>>(out1b, Wf1, ffn1_b + l * 1536,
                                                    nullptr, f1b, 8192, 1536, 1024);
    gemm_tn<0, true, true><<<512, 256, 0, stream>>>(f1b, Wf2, ffn2_b + l * 1024, nullptr, dT,
                                                    8192, 1024, 1536);
    float* xnext = (l == 14) ? (float*)d_out : Pout;
    ln_residual_kernel<<<8192, 256, 0, stream>>>(Pout, dT, n2_g + l * 1024, n2_b + l * 1024,
                                                 xnext, xb);
  }
}

// Round 11
// 6674.554 us; speedup vs baseline: 2.5051x; 1.3135x over previous
//
#include <hip/hip_runtime.h>
#include <hip/hip_bf16.h>

typedef __attribute__((ext_vector_type(8))) short bf16x8;
typedef __attribute__((ext_vector_type(4))) float f32x4;
typedef __hip_bfloat16 bf16;

#define ALPHA_F 0.42728713f
#define LN_EPS 1e-3f

__device__ __forceinline__ float silu_f(float x) { return x / (1.0f + __expf(-x)); }
// mish(x) = x*tanh(ln(1+e^x)) = x*(t^2-1)/(t^2+1), t=1+e^x  (exact rewrite, no tanh/log1p)
__device__ __forceinline__ float mish_f(float x) {
  if (x > 20.0f) return x;
  float t = 1.0f + __expf(x);
  float t2 = t * t;
  return x * (t2 - 1.0f) / (t2 + 1.0f);
}
__device__ __forceinline__ unsigned short f2bfu(float x) {
  bf16 h = __float2bfloat16(x);
  return *(unsigned short*)&h;
}
__device__ __forceinline__ float bfu2f(unsigned short u) {
  unsigned int v = (unsigned int)u << 16;
  return *(float*)&v;
}

// Builtin MFMA: LLVM sees real dataflow -> acc lives in AGPRs.
#define MFMA16(acc, a, b) \
  (acc) = __builtin_amdgcn_mfma_f32_16x16x32_bf16((a), (b), (acc), 0, 0, 0)

#define GLOAD_LDS16(gp, lp)                                                              \
  __builtin_amdgcn_global_load_lds((__attribute__((address_space(1))) void*)(void*)(gp), \
                                   (__attribute__((address_space(3))) void*)(void*)(lp), \
                                   16, 0, 0)

// ---------------- batched per-layer weight transpose: W[K,N] f32 -> Wt[N,K] bf16 -------
__global__ __launch_bounds__(256) void transpose_layer(
    const float* __restrict__ wq, const float* __restrict__ wk, const float* __restrict__ wv,
    const float* __restrict__ wo, const float* __restrict__ f1, const float* __restrict__ f2,
    const float* __restrict__ sgf, const float* __restrict__ swg, const float* __restrict__ sh1,
    bf16* __restrict__ Wqkv, bf16* __restrict__ Wo, bf16* __restrict__ Wf1,
    bf16* __restrict__ Wf2, bf16* __restrict__ Wsgf, bf16* __restrict__ Wswg,
    bf16* __restrict__ Wsh1) {
  __shared__ float tile[32][33];
  int b = blockIdx.x;
  const float* W;
  bf16* Wt;
  int K, N, tb;
  if (b < 3072) {
    int m = b >> 10;
    W = (m == 0) ? wq : ((m == 1) ? wk : wv);
    Wt = Wqkv + (size_t)m * 1024 * 1024;
    K = 1024; N = 1024; tb = b & 1023;
  } else if (b < 4096)  { W = wo;  Wt = Wo;   K = 1024; N = 1024; tb = b - 3072; }
  else if (b < 5632)    { W = f1;  Wt = Wf1;  K = 1024; N = 1536; tb = b - 4096; }
  else if (b < 7168)    { W = f2;  Wt = Wf2;  K = 1536; N = 1024; tb = b - 5632; }
  else if (b < 9216)    { W = sgf; Wt = Wsgf; K = 256;  N = 8192; tb = b - 7168; }
  else if (b < 10240)   { W = swg; Wt = Wswg; K = 256;  N = 4096; tb = b - 9216; }
  else                  { W = sh1; Wt = Wsh1; K = 2048; N = 256;  tb = b - 10240; }
  int ntx = N >> 5;
  int ty_ = tb / ntx, tx_ = tb - ty_ * ntx;
  int nb = tx_ * 32, kb = ty_ * 32;
  int tx = threadIdx.x & 31, ty = threadIdx.x >> 5;
#pragma unroll
  for (int i = 0; i < 4; ++i)
    tile[ty + i * 8][tx] = W[(size_t)(kb + ty + i * 8) * N + nb + tx];
  __syncthreads();
#pragma unroll
  for (int i = 0; i < 4; ++i)
    Wt[(size_t)(nb + ty + i * 8) * K + kb + tx] = __float2bfloat16(tile[tx][ty + i * 8]);
}

__global__ __launch_bounds__(256) void cvt_f32_bf16_k(const float* __restrict__ in,
                                                      bf16* __restrict__ out, long long n) {
  long long i = ((long long)blockIdx.x * 256 + threadIdx.x) * 4;
  if (i + 3 < n) {
    float4 v = *(const float4*)(in + i);
    out[i + 0] = __float2bfloat16(v.x);
    out[i + 1] = __float2bfloat16(v.y);
    out[i + 2] = __float2bfloat16(v.z);
    out[i + 3] = __float2bfloat16(v.w);
  }
}

__global__ __launch_bounds__(256) void pack3_k(const float* __restrict__ a,
                                               const float* __restrict__ b,
                                               const float* __restrict__ c,
                                               float* __restrict__ o) {
  int i = blockIdx.x * 256 + threadIdx.x;
  if (i < 1024) o[i] = a[i];
  else if (i < 2048) o[i] = b[i - 1024];
  else if (i < 3072) o[i] = c[i - 2048];
}

__global__ __launch_bounds__(1) void sentinel_k(float* __restrict__ o) { o[0] = 1.2345e7f; }

// ---------------- BMxBN bf16 MFMA GEMM, 2-phase double-buffered, XCD-swizzled ----------
// R10: GEMMs are latency-bound with throughput proportional to resident blocks/CU
// (QKV 6/CU runs 2x FFN1 3/CU per-FLOP; BW/conflicts/MFMA all minor). 64x64 tiles
// (16KB LDS, tiny VGPR) lift the small-N GEMMs to ~8 blocks/CU. <128,128> reduces
// exactly to the R9 kernel (used for QKV).
template <int BM, int BN, int ACT, bool OUTBF16, bool BIAS>
__global__ __launch_bounds__(256) void gemm_tn(const bf16* __restrict__ A,
                                               const bf16* __restrict__ Bt,
                                               const float* __restrict__ bias,
                                               float* __restrict__ Cf, bf16* __restrict__ Cb,
                                               int M, int N, int K) {
  constexpr int NWC = (BN == 128) ? 2 : 1;  // waves along N
  constexpr int NWR = 4 / NWC;              // waves along M
  constexpr int AR = BM / (16 * NWR);       // row frags per wave
  constexpr int AC = BN / (16 * NWC);       // col frags per wave
  __shared__ __align__(128) short As[2][BM * 32];
  __shared__ __align__(128) short Bs[2][BN * 32];
  int t = threadIdx.x;
  int lane = t & 63, wave = t >> 6;
  // bijective XCD swizzle (m204)
  int nbx = N / BN;
  int nwg = gridDim.x;
  int q = nwg >> 3, r = nwg & 7;
  int xcd = blockIdx.x & 7, lid = blockIdx.x >> 3;
  int swz = (xcd < r ? xcd * (q + 1) : r * (q + 1) + (xcd - r) * q) + lid;
  int by = swz / nbx, bx = swz - by * nbx;
  int m0 = by * BM, n0 = bx * BN;
  int wr = wave / NWC, wc = wave % NWC;
  int fr = lane & 15;
  int fk = (lane >> 4) << 3;

  f32x4 acc[AR][AC] = {};

  int row0 = t >> 2, ko0 = (t & 3) << 3;

  const bf16* Ag0 = A + (size_t)(m0 + row0) * K + ko0;
  const bf16* Ag1 = A + (size_t)(m0 + 64 + row0) * K + ko0;   // used only if BM==128
  const bf16* Bg0 = Bt + (size_t)(n0 + row0) * K + ko0;
  const bf16* Bg1 = Bt + (size_t)(n0 + 64 + row0) * K + ko0;  // used only if BN==128

  auto stageTo = [&](int buf, int k0) {
    GLOAD_LDS16(Ag0 + k0, &As[buf][wave * 512]);
    if constexpr (BM == 128) GLOAD_LDS16(Ag1 + k0, &As[buf][2048 + wave * 512]);
    GLOAD_LDS16(Bg0 + k0, &Bs[buf][wave * 512]);
    if constexpr (BN == 128) GLOAD_LDS16(Bg1 + k0, &Bs[buf][2048 + wave * 512]);
  };

  int nk = K >> 5;
  stageTo(0, 0);
  __syncthreads();  // vmcnt(0) drain: tile 0 resident

  const int rdA = (wr * (BM / NWR) + fr) * 32 + fk;
  const int rdB = (wc * (BN / NWC) + fr) * 32 + fk;

  for (int kt = 0; kt < nk; ++kt) {
    int cur = kt & 1;
    if (kt + 1 < nk) stageTo(cur ^ 1, (kt + 1) << 5);
    bf16x8 af[AR], bfv[AC];
#pragma unroll
    for (int a = 0; a < AR; ++a) af[a] = *(const bf16x8*)(&As[cur][rdA + a * 512]);
#pragma unroll
    for (int b = 0; b < AC; ++b) bfv[b] = *(const bf16x8*)(&Bs[cur][rdB + b * 512]);
#pragma unroll
    for (int a = 0; a < AR; ++a)
#pragma unroll
      for (int b = 0; b < AC; ++b) MFMA16(acc[a][b], af[a], bfv[b]);
    __syncthreads();  // drains prefetch + all waves' reads of buf[cur]
  }
  int lr = (lane >> 4) << 2;
  int lc = lane & 15;
#pragma unroll
  for (int a = 0; a < AR; ++a) {
#pragma unroll
    for (int b = 0; b < AC; ++b) {
      int col = n0 + wc * (BN / NWC) + b * 16 + lc;
      float bv = 0.0f;
      if constexpr (BIAS) bv = bias[col];
#pragma unroll
      for (int j = 0; j < 4; ++j) {
        int rowi = m0 + wr * (BM / NWR) + a * 16 + lr + j;
        float v = acc[a][b][j] + bv;
        if constexpr (ACT == 1) v = silu_f(v);
        if constexpr (ACT == 2) v = mish_f(v);
        if constexpr (OUTBF16) Cb[(size_t)rowi * N + col] = __float2bfloat16(v);
        else Cf[(size_t)rowi * N + col] = v;
      }
    }
  }
}

// ---------------- c = xb @ sc_w : [8192,1024]bf16 @ [1024,32]f32 -> bf16 [8192,32] -----
__global__ __launch_bounds__(256) void c_kernel(const bf16* __restrict__ xb,
                                                const float* __restrict__ scw,
                                                bf16* __restrict__ cout) {
  __shared__ float Xs[8][1024];
  int t = threadIdx.x;
  int row0 = blockIdx.x * 8;
#pragma unroll
  for (int i = 0; i < 4; ++i) {
    int idx = (t + i * 256) * 8;  // 8 bf16 per thread-iter
    bf16x8 v = *(const bf16x8*)(xb + (size_t)row0 * 1024 + idx);
#pragma unroll
    for (int j = 0; j < 8; ++j)
      Xs[(idx + j) >> 10][(idx + j) & 1023] = bfu2f((unsigned short)v[j]);
  }
  __syncthreads();
  int r = t >> 5, n = t & 31;
  float acc = 0.0f;
#pragma unroll 4
  for (int k = 0; k < 1024; ++k) acc += Xs[r][k] * scw[k * 32 + n];
  cout[(size_t)(row0 + r) * 32 + n] = __float2bfloat16(acc);
}

// ---------------- LN over 256 cols: hb = LN(hpre) -> bf16 ------------------------------
__global__ __launch_bounds__(256) void ln256_kernel(const float* __restrict__ hpre,
                                                    const float* __restrict__ gam,
                                                    const float* __restrict__ bet,
                                                    bf16* __restrict__ hb) {
  __shared__ float rsm[4], rs2[4], st2[2];
  int t = threadIdx.x, row = blockIdx.x;
  float sv = hpre[(size_t)row * 256 + t];
  float s = sv, s2 = sv * sv;
#pragma unroll
  for (int o = 32; o > 0; o >>= 1) { s += __shfl_down(s, o); s2 += __shfl_down(s2, o); }
  if ((t & 63) == 0) { rsm[t >> 6] = s; rs2[t >> 6] = s2; }
  __syncthreads();
  if (t == 0) {
    float a = rsm[0] + rsm[1] + rsm[2] + rsm[3];
    float b2 = rs2[0] + rs2[1] + rs2[2] + rs2[3];
    float m = a * (1.0f / 256.0f);
    st2[0] = m;
    st2[1] = rsqrtf(b2 * (1.0f / 256.0f) - m * m + LN_EPS);
  }
  __syncthreads();
  float y = (sv - st2[0]) * st2[1] * gam[t] + bet[t];
  hb[(size_t)row * 256 + t] = __float2bfloat16(y);
}

// ---------------- LN over 8192 cols (smolgen g) -> bf16 --------------------------------
__global__ __launch_bounds__(1024) void ln8192_kernel(const float* __restrict__ gpre,
                                                      const float* __restrict__ gam,
                                                      const float* __restrict__ bet,
                                                      bf16* __restrict__ gb) {
  __shared__ float rsm[16], rs2[16], st2[2];
  int t = threadIdx.x, row = blockIdx.x;
  const float* p = gpre + (size_t)row * 8192;
  float v[8];
  float s = 0.0f, s2 = 0.0f;
#pragma unroll
  for (int i = 0; i < 8; ++i) {
    v[i] = p[t + i * 1024];
    s += v[i];
    s2 += v[i] * v[i];
  }
#pragma unroll
  for (int o = 32; o > 0; o >>= 1) { s += __shfl_down(s, o); s2 += __shfl_down(s2, o); }
  int lane = t & 63, w = t >> 6;
  if (lane == 0) { rsm[w] = s; rs2[w] = s2; }
  __syncthreads();
  if (t == 0) {
    float a = 0.0f, b2 = 0.0f;
#pragma unroll
    for (int i = 0; i < 16; ++i) { a += rsm[i]; b2 += rs2[i]; }
    float m = a * (1.0f / 8192.0f);
    st2[0] = m;
    st2[1] = rsqrtf(b2 * (1.0f / 8192.0f) - m * m + LN_EPS);
  }
  __syncthreads();
  float m = st2[0], r = st2[1];
#pragma unroll
  for (int i = 0; i < 8; ++i) {
    int n = t + i * 1024;
    gb[(size_t)row * 8192 + n] = __float2bfloat16((v[i] - m) * r * gam[n] + bet[n]);
  }
}

// ---------------- residual + LN over 1024 cols (f32 base, bf16 delta) ------------------
__global__ __launch_bounds__(256) void ln_residual_kernel(const float* __restrict__ base,
                                                          const bf16* __restrict__ delta,
                                                          const float* __restrict__ gam,
                                                          const float* __restrict__ bet,
                                                          float* __restrict__ outf,
                                                          bf16* __restrict__ outb) {
  __shared__ float rsm[4], rs2[4], st2[2];
  int t = threadIdx.x, row = blockIdx.x;
  float4 bv = ((const float4*)(base + (size_t)row * 1024))[t];
  ushort4 du = ((const ushort4*)(delta + (size_t)row * 1024))[t];
  float4 v;
  v.x = bv.x + bfu2f(du.x) * ALPHA_F;
  v.y = bv.y + bfu2f(du.y) * ALPHA_F;
  v.z = bv.z + bfu2f(du.z) * ALPHA_F;
  v.w = bv.w + bfu2f(du.w) * ALPHA_F;
  float s = v.x + v.y + v.z + v.w;
  float s2 = v.x * v.x + v.y * v.y + v.z * v.z + v.w * v.w;
#pragma unroll
  for (int o = 32; o > 0; o >>= 1) { s += __shfl_down(s, o); s2 += __shfl_down(s2, o); }
  if ((t & 63) == 0) { rsm[t >> 6] = s; rs2[t >> 6] = s2; }
  __syncthreads();
  if (t == 0) {
    float a = rsm[0] + rsm[1] + rsm[2] + rsm[3];
    float b2 = rs2[0] + rs2[1] + rs2[2] + rs2[3];
    float m = a * (1.0f / 1024.0f);
    st2[0] = m;
    st2[1] = rsqrtf(b2 * (1.0f / 1024.0f) - m * m + LN_EPS);
  }
  __syncthreads();
  float m = st2[0], r = st2[1];
  float4 g4 = ((const float4*)gam)[t];
  float4 b4 = ((const float4*)bet)[t];
  float4 y;
  y.x = (v.x - m) * r * g4.x + b4.x;
  y.y = (v.y - m) * r * g4.y + b4.y;
  y.z = (v.z - m) * r * g4.z + b4.z;
  y.w = (v.w - m) * r * g4.w + b4.w;
  ((float4*)(outf + (size_t)row * 1024))[t] = y;
  ushort4 o4;
  o4.x = f2bfu(y.x); o4.y = f2bfu(y.y); o4.z = f2bfu(y.z); o4.w = f2bfu(y.w);
  ((ushort4*)(outb + (size_t)row * 1024))[t] = o4;
}

// ---------------- MFMA fused attention per (b,h) ---------------------------------------
__global__ __launch_bounds__(256) void attn_kernel(const bf16* __restrict__ qkv,
                                                   const bf16* __restrict__ sw,
                                                   bf16* __restrict__ avb) {
  __shared__ __align__(16) short Vt[32 * 72];
  __shared__ __align__(16) short Sw[64 * 64];
  __shared__ __align__(16) short Pl[64 * 72];
  const int t = threadIdx.x, lane = t & 63, w = t >> 6;
  const int fr = lane & 15, s4 = lane >> 4;
  const int bh = blockIdx.x, b = bh >> 5, h = bh & 31;
  const size_t qb = (size_t)b * 64 * 3072 + h * 32;
  // stage V transposed: Vt[d][k]
  {
    int k = t >> 2, d0 = (t & 3) * 8;
    bf16x8 v = *(const bf16x8*)(qkv + qb + (size_t)k * 3072 + 2048 + d0);
#pragma unroll
    for (int i = 0; i < 8; ++i) Vt[(d0 + i) * 72 + k] = v[i];
  }
  // stage sw bias [64][64]
  {
    const bf16* swp = sw + (size_t)bh * 4096;
    *(bf16x8*)(Sw + t * 8) = *(const bf16x8*)(swp + t * 8);
    *(bf16x8*)(Sw + 2048 + t * 8) = *(const bf16x8*)(swp + 2048 + t * 8);
  }
  __syncthreads();
  // QK^T: S[16 rows][64 cols] per wave
  f32x4 acc[4] = {};
  {
    bf16x8 aq = *(const bf16x8*)(qkv + qb + (size_t)(16 * w + fr) * 3072 + s4 * 8);
#pragma unroll
    for (int n = 0; n < 4; ++n) {
      bf16x8 bk = *(const bf16x8*)(qkv + qb + (size_t)(n * 16 + fr) * 3072 + 1024 + s4 * 8);
      acc[n] = __builtin_amdgcn_mfma_f32_16x16x32_bf16(aq, bk, acc[n], 0, 0, 0);
    }
  }
  // softmax over k for rows q = 16w + s4*4 + j (cols n*16+fr per lane)
  float rinv[4];
#pragma unroll
  for (int j = 0; j < 4; ++j) {
    int q = 16 * w + s4 * 4 + j;
    float pv[4];
    float mx = -1e30f;
#pragma unroll
    for (int n = 0; n < 4; ++n) {
      float v = acc[n][j] * 0.17677669529663687f +
                __bfloat162float(((const bf16*)Sw)[q * 64 + n * 16 + fr]);
      pv[n] = v;
      mx = fmaxf(mx, v);
    }
    mx = fmaxf(mx, __shfl_xor(mx, 1));
    mx = fmaxf(mx, __shfl_xor(mx, 2));
    mx = fmaxf(mx, __shfl_xor(mx, 4));
    mx = fmaxf(mx, __shfl_xor(mx, 8));
    float sum = 0.0f;
#pragma unroll
    for (int n = 0; n < 4; ++n) {
      float e = __expf(pv[n] - mx);
      sum += e;
      ((bf16*)Pl)[q * 72 + n * 16 + fr] = __float2bfloat16(e);
    }
    sum += __shfl_xor(sum, 1);
    sum += __shfl_xor(sum, 2);
    sum += __shfl_xor(sum, 4);
    sum += __shfl_xor(sum, 8);
    rinv[j] = 1.0f / sum;
  }
  __syncthreads();
  // PV: out[16 rows][32 d] per wave
  f32x4 acc2[2] = {};
#pragma unroll
  for (int kt = 0; kt < 2; ++kt) {
    bf16x8 ap = *(const bf16x8*)(Pl + (16 * w + fr) * 72 + kt * 32 + s4 * 8);
#pragma unroll
    for (int n2 = 0; n2 < 2; ++n2) {
      bf16x8 bv = *(const bf16x8*)(Vt + (n2 * 16 + fr) * 72 + kt * 32 + s4 * 8);
      acc2[n2] = __builtin_amdgcn_mfma_f32_16x16x32_bf16(ap, bv, acc2[n2], 0, 0, 0);
    }
  }
#pragma unroll
  for (int n2 = 0; n2 < 2; ++n2) {
#pragma unroll
    for (int j = 0; j < 4; ++j) {
      int q = 16 * w + s4 * 4 + j;
      int d = n2 * 16 + fr;
      avb[(size_t)(b * 64 + q) * 1024 + h * 32 + d] =
          __float2bfloat16(acc2[n2][j] * rinv[j]);
    }
  }
}

extern "C" void kernel_launch(void* const* d_in, const int* in_sizes, int n_in,
                              void* d_out, int out_size, void* d_ws, size_t ws_size,
                              hipStream_t stream) {
  const float* x_in   = (const float*)d_in[0];
  const float* wq_w   = (const float*)d_in[1];
  const float* wq_b   = (const float*)d_in[2];
  const float* wk_w   = (const float*)d_in[3];
  const float* wk_b   = (const float*)d_in[4];
  const float* wv_w   = (const float*)d_in[5];
  const float* wv_b   = (const float*)d_in[6];
  const float* wo_w   = (const float*)d_in[7];
  const float* wo_b   = (const float*)d_in[8];
  const float* sc_w   = (const float*)d_in[9];
  const float* sh1_w  = (const float*)d_in[10];
  const float* sh1_b  = (const float*)d_in[11];
  const float* sln1_g = (const float*)d_in[12];
  const float* sln1_b = (const float*)d_in[13];
  const float* sgf_w  = (const float*)d_in[14];
  const float* sgf_b  = (const float*)d_in[15];
  const float* sln2_g = (const float*)d_in[16];
  const float* sln2_b = (const float*)d_in[17];
  const float* swg_w  = (const float*)d_in[18];
  const float* ffn1_w = (const float*)d_in[19];
  const float* ffn1_b = (const float*)d_in[20];
  const float* ffn2_w = (const float*)d_in[21];
  const float* ffn2_b = (const float*)d_in[22];
  const float* n1_g   = (const float*)d_in[23];
  const float* n1_b   = (const float*)d_in[24];
  const float* n2_g   = (const float*)d_in[25];
  const float* n2_b   = (const float*)d_in[26];

  char* ws = (char*)d_ws;
  size_t off = 0;
  auto alloc = [&](size_t bytes) -> void* {
    void* p = ws + off;
    off += (bytes + 255) & ~(size_t)255;
    return p;
  };
  bf16*  xb    = (bf16*)alloc(8192ULL * 1024 * 2);
  float* P0    = (float*)alloc(8192ULL * 1024 * 4);
  float* P1    = (float*)alloc(8192ULL * 1024 * 4);
  bf16*  dT    = (bf16*)alloc(8192ULL * 1024 * 2);
  bf16*  Wqkv  = (bf16*)alloc(3072ULL * 1024 * 2);
  float* bqkv  = (float*)alloc(3072ULL * 4);
  bf16*  Wo    = (bf16*)alloc(1024ULL * 1024 * 2);
  bf16*  Wf1   = (bf16*)alloc(1536ULL * 1024 * 2);
  bf16*  Wf2   = (bf16*)alloc(1024ULL * 1536 * 2);
  bf16*  Wsgf  = (bf16*)alloc(8192ULL * 256 * 2);
  bf16*  Wswg  = (bf16*)alloc(4096ULL * 256 * 2);
  bf16*  Wsh1  = (bf16*)alloc(256ULL * 2048 * 2);
  bf16*  qkvb  = (bf16*)alloc(8192ULL * 3072 * 2);
  bf16*  cbuf  = (bf16*)alloc(8192ULL * 32 * 2);
  float* hpre  = (float*)alloc(128ULL * 256 * 4);
  bf16*  hbb   = (bf16*)alloc(128ULL * 256 * 2);
  float* gpre  = (float*)alloc(128ULL * 8192 * 4);
  bf16*  gbb   = (bf16*)alloc(128ULL * 8192 * 2);
  bf16*  swb   = (bf16*)alloc(4096ULL * 4096 * 2);
  bf16*  avb   = (bf16*)alloc(8192ULL * 1024 * 2);
  bf16*  out1b = (bf16*)alloc(8192ULL * 1024 * 2);
  bf16*  f1b   = (bf16*)alloc(8192ULL * 1536 * 2);
  if (off > ws_size) {
    sentinel_k<<<1, 1, 0, stream>>>((float*)d_out);
    return;
  }

  cvt_f32_bf16_k<<<8192, 256, 0, stream>>>(x_in, xb, 8192LL * 1024);

  for (int l = 0; l < 15; ++l) {
    const float* wq   = wq_w + (size_t)l * 1024 * 1024;
    const float* wk   = wk_w + (size_t)l * 1024 * 1024;
    const float* wv   = wv_w + (size_t)l * 1024 * 1024;
    const float* wo   = wo_w + (size_t)l * 1024 * 1024;
    const float* f1w  = ffn1_w + (size_t)l * 1024 * 1536;
    const float* f2w  = ffn2_w + (size_t)l * 1536 * 1024;
    const float* sgf  = sgf_w + (size_t)l * 256 * 8192;
    const float* swg  = swg_w + (size_t)l * 256 * 4096;
    const float* scw  = sc_w + (size_t)l * 1024 * 32;
    const float* sh1w = sh1_w + (size_t)l * 2048 * 256;

    transpose_layer<<<10752, 256, 0, stream>>>(wq, wk, wv, wo, f1w, f2w, sgf, swg, sh1w,
                                               Wqkv, Wo, Wf1, Wf2, Wsgf, Wswg, Wsh1);
    pack3_k<<<12, 256, 0, stream>>>(wq_b + l * 1024, wk_b + l * 1024, wv_b + l * 1024, bqkv);

    const float* xc = (l == 0) ? x_in : ((l & 1) ? P0 : P1);
    float* Pout = (l & 1) ? P1 : P0;

    // QKV projection (128x128, 6 blocks/CU)
    gemm_tn<128, 128, 0, true, true><<<1536, 256, 0, stream>>>(xb, Wqkv, bqkv, nullptr, qkvb,
                                                               8192, 3072, 1024);
    // smolgen chain (64x64 tiles for concurrency)
    c_kernel<<<1024, 256, 0, stream>>>(xb, scw, cbuf);
    gemm_tn<64, 64, 1, false, true><<<8, 256, 0, stream>>>(cbuf, Wsh1, sh1_b + l * 256,
                                                           hpre, nullptr, 128, 256, 2048);
    ln256_kernel<<<128, 256, 0, stream>>>(hpre, sln1_g + l * 256, sln1_b + l * 256, hbb);
    gemm_tn<64, 64, 1, false, true><<<256, 256, 0, stream>>>(hbb, Wsgf,
                                                             sgf_b + (size_t)l * 8192,
                                                             gpre, nullptr, 128, 8192, 256);
    ln8192_kernel<<<128, 1024, 0, stream>>>(gpre, sln2_g + (size_t)l * 8192,
                                            sln2_b + (size_t)l * 8192, gbb);
    gemm_tn<64, 64, 0, true, false><<<4096, 256, 0, stream>>>(gbb, Wswg, nullptr, nullptr, swb,
                                                              4096, 4096, 256);
    // attention (MFMA)
    attn_kernel<<<4096, 256, 0, stream>>>(qkvb, swb, avb);
    // output projection + LN1 (bf16 delta)
    gemm_tn<64, 64, 0, true, true><<<2048, 256, 0, stream>>>(avb, Wo, wo_b + l * 1024,
                                                             nullptr, dT, 8192, 1024, 1024);
    ln_residual_kernel<<<8192, 256, 0, stream>>>(xc, dT, n1_g + l * 1024, n1_b + l * 1024,
                                                 Pout, out1b);
    // FFN + LN2 (bf16 delta)
    gemm_tn<64, 64, 2, true, true><<<3072, 256, 0, stream>>>(out1b, Wf1, ffn1_b + l * 1536,
                                                             nullptr, f1b, 8192, 1536, 1024);
    gemm_tn<64, 64, 0, true, true><<<2048, 256, 0, stream>>>(f1b, Wf2, ffn2_b + l * 1024,
                                                             nullptr, dT, 8192, 1024, 1536);
    float* xnext = (l == 14) ? (float*)d_out : Pout;
    ln_residual_kernel<<<8192, 256, 0, stream>>>(Pout, dT, n2_g + l * 1024, n2_b + l * 1024,
                                                 xnext, xb);
  }
}

// Round 12
// 5434.818 us; speedup vs baseline: 3.0766x; 1.2281x over previous
//
#include <hip/hip_runtime.h>
#include <hip/hip_bf16.h>

typedef __attribute__((ext_vector_type(8))) short bf16x8;
typedef __attribute__((ext_vector_type(4))) float f32x4;
typedef __hip_bfloat16 bf16;

#define ALPHA_F 0.42728713f
#define LN_EPS 1e-3f

__device__ __forceinline__ float silu_f(float x) { return x / (1.0f + __expf(-x)); }
// mish(x) = x*tanh(ln(1+e^x)) = x*(t^2-1)/(t^2+1), t=1+e^x  (exact rewrite, no tanh/log1p)
__device__ __forceinline__ float mish_f(float x) {
  if (x > 20.0f) return x;
  float t = 1.0f + __expf(x);
  float t2 = t * t;
  return x * (t2 - 1.0f) / (t2 + 1.0f);
}
__device__ __forceinline__ unsigned short f2bfu(float x) {
  bf16 h = __float2bfloat16(x);
  return *(unsigned short*)&h;
}
__device__ __forceinline__ float bfu2f(unsigned short u) {
  unsigned int v = (unsigned int)u << 16;
  return *(float*)&v;
}

// Builtin MFMA: LLVM sees real dataflow -> acc lives in AGPRs.
#define MFMA16(acc, a, b) \
  (acc) = __builtin_amdgcn_mfma_f32_16x16x32_bf16((a), (b), (acc), 0, 0, 0)

#define GLOAD_LDS16(gp, lp)                                                              \
  __builtin_amdgcn_global_load_lds((__attribute__((address_space(1))) void*)(void*)(gp), \
                                   (__attribute__((address_space(3))) void*)(void*)(lp), \
                                   16, 0, 0)

// ---------------- batched per-layer weight transpose: W[K,N] f32 -> Wt[N,K] bf16 -------
__global__ __launch_bounds__(256) void transpose_layer(
    const float* __restrict__ wq, const float* __restrict__ wk, const float* __restrict__ wv,
    const float* __restrict__ wo, const float* __restrict__ f1, const float* __restrict__ f2,
    const float* __restrict__ sgf, const float* __restrict__ swg, const float* __restrict__ sh1,
    const float* __restrict__ scw,
    bf16* __restrict__ Wqkv, bf16* __restrict__ Wo, bf16* __restrict__ Wf1,
    bf16* __restrict__ Wf2, bf16* __restrict__ Wsgf, bf16* __restrict__ Wswg,
    bf16* __restrict__ Wsh1, bf16* __restrict__ Wsc) {
  __shared__ float tile[32][33];
  int b = blockIdx.x;
  const float* W;
  bf16* Wt;
  int K, N, tb;
  if (b < 3072) {
    int m = b >> 10;
    W = (m == 0) ? wq : ((m == 1) ? wk : wv);
    Wt = Wqkv + (size_t)m * 1024 * 1024;
    K = 1024; N = 1024; tb = b & 1023;
  } else if (b < 4096)  { W = wo;  Wt = Wo;   K = 1024; N = 1024; tb = b - 3072; }
  else if (b < 5632)    { W = f1;  Wt = Wf1;  K = 1024; N = 1536; tb = b - 4096; }
  else if (b < 7168)    { W = f2;  Wt = Wf2;  K = 1536; N = 1024; tb = b - 5632; }
  else if (b < 9216)    { W = sgf; Wt = Wsgf; K = 256;  N = 8192; tb = b - 7168; }
  else if (b < 10240)   { W = swg; Wt = Wswg; K = 256;  N = 4096; tb = b - 9216; }
  else if (b < 10752)   { W = sh1; Wt = Wsh1; K = 2048; N = 256;  tb = b - 10240; }
  else                  { W = scw; Wt = Wsc;  K = 1024; N = 32;   tb = b - 10752; }
  int ntx = N >> 5;
  int ty_ = tb / ntx, tx_ = tb - ty_ * ntx;
  int nb = tx_ * 32, kb = ty_ * 32;
  int tx = threadIdx.x & 31, ty = threadIdx.x >> 5;
#pragma unroll
  for (int i = 0; i < 4; ++i)
    tile[ty + i * 8][tx] = W[(size_t)(kb + ty + i * 8) * N + nb + tx];
  __syncthreads();
#pragma unroll
  for (int i = 0; i < 4; ++i)
    Wt[(size_t)(nb + ty + i * 8) * K + kb + tx] = __float2bfloat16(tile[tx][ty + i * 8]);
}

__global__ __launch_bounds__(256) void cvt_f32_bf16_k(const float* __restrict__ in,
                                                      bf16* __restrict__ out, long long n) {
  long long i = ((long long)blockIdx.x * 256 + threadIdx.x) * 4;
  if (i + 3 < n) {
    float4 v = *(const float4*)(in + i);
    out[i + 0] = __float2bfloat16(v.x);
    out[i + 1] = __float2bfloat16(v.y);
    out[i + 2] = __float2bfloat16(v.z);
    out[i + 3] = __float2bfloat16(v.w);
  }
}

__global__ __launch_bounds__(256) void pack3_k(const float* __restrict__ a,
                                               const float* __restrict__ b,
                                               const float* __restrict__ c,
                                               float* __restrict__ o) {
  int i = blockIdx.x * 256 + threadIdx.x;
  if (i < 1024) o[i] = a[i];
  else if (i < 2048) o[i] = b[i - 1024];
  else if (i < 3072) o[i] = c[i - 2048];
}

__global__ __launch_bounds__(1) void sentinel_k(float* __restrict__ o) { o[0] = 1.2345e7f; }

// ---------------- BMxBN bf16 MFMA GEMM, 2-phase double-buffered, XCD-swizzled ----------
// R10/R11: GEMMs here are latency-bound; throughput ~ resident blocks/CU. 64x64 tiles
// (16KB LDS) -> ~8 blocks/CU for the small-N GEMMs; <128,128> (the R9 kernel) for QKV.
template <int BM, int BN, int ACT, bool OUTBF16, bool BIAS>
__global__ __launch_bounds__(256) void gemm_tn(const bf16* __restrict__ A,
                                               const bf16* __restrict__ Bt,
                                               const float* __restrict__ bias,
                                               float* __restrict__ Cf, bf16* __restrict__ Cb,
                                               int M, int N, int K) {
  constexpr int NWC = (BN == 128) ? 2 : 1;  // waves along N
  constexpr int NWR = 4 / NWC;              // waves along M
  constexpr int AR = BM / (16 * NWR);       // row frags per wave
  constexpr int AC = BN / (16 * NWC);       // col frags per wave
  __shared__ __align__(128) short As[2][BM * 32];
  __shared__ __align__(128) short Bs[2][BN * 32];
  int t = threadIdx.x;
  int lane = t & 63, wave = t >> 6;
  // bijective XCD swizzle (m204)
  int nbx = N / BN;
  int nwg = gridDim.x;
  int q = nwg >> 3, r = nwg & 7;
  int xcd = blockIdx.x & 7, lid = blockIdx.x >> 3;
  int swz = (xcd < r ? xcd * (q + 1) : r * (q + 1) + (xcd - r) * q) + lid;
  int by = swz / nbx, bx = swz - by * nbx;
  int m0 = by * BM, n0 = bx * BN;
  int wr = wave / NWC, wc = wave % NWC;
  int fr = lane & 15;
  int fk = (lane >> 4) << 3;

  f32x4 acc[AR][AC] = {};

  int row0 = t >> 2, ko0 = (t & 3) << 3;

  const bf16* Ag0 = A + (size_t)(m0 + row0) * K + ko0;
  const bf16* Ag1 = A + (size_t)(m0 + 64 + row0) * K + ko0;   // used only if BM==128
  const bf16* Bg0 = Bt + (size_t)(n0 + row0) * K + ko0;
  const bf16* Bg1 = Bt + (size_t)(n0 + 64 + row0) * K + ko0;  // used only if BN==128

  auto stageTo = [&](int buf, int k0) {
    GLOAD_LDS16(Ag0 + k0, &As[buf][wave * 512]);
    if constexpr (BM == 128) GLOAD_LDS16(Ag1 + k0, &As[buf][2048 + wave * 512]);
    GLOAD_LDS16(Bg0 + k0, &Bs[buf][wave * 512]);
    if constexpr (BN == 128) GLOAD_LDS16(Bg1 + k0, &Bs[buf][2048 + wave * 512]);
  };

  int nk = K >> 5;
  stageTo(0, 0);
  __syncthreads();  // vmcnt(0) drain: tile 0 resident

  const int rdA = (wr * (BM / NWR) + fr) * 32 + fk;
  const int rdB = (wc * (BN / NWC) + fr) * 32 + fk;

  for (int kt = 0; kt < nk; ++kt) {
    int cur = kt & 1;
    if (kt + 1 < nk) stageTo(cur ^ 1, (kt + 1) << 5);
    bf16x8 af[AR], bfv[AC];
#pragma unroll
    for (int a = 0; a < AR; ++a) af[a] = *(const bf16x8*)(&As[cur][rdA + a * 512]);
#pragma unroll
    for (int b = 0; b < AC; ++b) bfv[b] = *(const bf16x8*)(&Bs[cur][rdB + b * 512]);
#pragma unroll
    for (int a = 0; a < AR; ++a)
#pragma unroll
      for (int b = 0; b < AC; ++b) MFMA16(acc[a][b], af[a], bfv[b]);
    __syncthreads();  // drains prefetch + all waves' reads of buf[cur]
  }
  int lr = (lane >> 4) << 2;
  int lc = lane & 15;
#pragma unroll
  for (int a = 0; a < AR; ++a) {
#pragma unroll
    for (int b = 0; b < AC; ++b) {
      int col = n0 + wc * (BN / NWC) + b * 16 + lc;
      float bv = 0.0f;
      if constexpr (BIAS) bv = bias[col];
#pragma unroll
      for (int j = 0; j < 4; ++j) {
        int rowi = m0 + wr * (BM / NWR) + a * 16 + lr + j;
        float v = acc[a][b][j] + bv;
        if constexpr (ACT == 1) v = silu_f(v);
        if constexpr (ACT == 2) v = mish_f(v);
        if constexpr (OUTBF16) Cb[(size_t)rowi * N + col] = __float2bfloat16(v);
        else Cf[(size_t)rowi * N + col] = v;
      }
    }
  }
}

// ---------------- c = xb @ Wsc^T : [8192,1024]bf16 @ [32,1024]^T -> bf16 [8192,32] -----
// R11: old c_kernel was a serial K=1024 latency chain (98.7us, 0% MFMA, 5.4 TF).
// MFMA rewrite (attn-QK^T pattern): 1 wave per 16 rows, A/B frags direct from global
// (A row=row0+fr, k=s4*8), Wsc (64KB) L2-resident, acc the only dependent chain.
__global__ __launch_bounds__(64) void c_kernel(const bf16* __restrict__ xb,
                                               const bf16* __restrict__ Wsc,
                                               bf16* __restrict__ cout) {
  const int lane = threadIdx.x;
  const int fr = lane & 15, s4 = lane >> 4;
  const int row0 = blockIdx.x * 16;
  f32x4 acc[2] = {};
  const bf16* Arow = xb + (size_t)(row0 + fr) * 1024 + s4 * 8;
  const bf16* B0 = Wsc + (size_t)fr * 1024 + s4 * 8;
  const bf16* B1 = Wsc + (size_t)(16 + fr) * 1024 + s4 * 8;
#pragma unroll 8
  for (int kt = 0; kt < 32; ++kt) {
    bf16x8 a = *(const bf16x8*)(Arow + kt * 32);
    bf16x8 b0 = *(const bf16x8*)(B0 + kt * 32);
    bf16x8 b1 = *(const bf16x8*)(B1 + kt * 32);
    acc[0] = __builtin_amdgcn_mfma_f32_16x16x32_bf16(a, b0, acc[0], 0, 0, 0);
    acc[1] = __builtin_amdgcn_mfma_f32_16x16x32_bf16(a, b1, acc[1], 0, 0, 0);
  }
#pragma unroll
  for (int n2 = 0; n2 < 2; ++n2)
#pragma unroll
    for (int j = 0; j < 4; ++j)
      cout[(size_t)(row0 + s4 * 4 + j) * 32 + n2 * 16 + fr] =
          __float2bfloat16(acc[n2][j]);
}

// ---------------- LN over 256 cols: hb = LN(hpre) -> bf16 ------------------------------
__global__ __launch_bounds__(256) void ln256_kernel(const float* __restrict__ hpre,
                                                    const float* __restrict__ gam,
                                                    const float* __restrict__ bet,
                                                    bf16* __restrict__ hb) {
  __shared__ float rsm[4], rs2[4], st2[2];
  int t = threadIdx.x, row = blockIdx.x;
  float sv = hpre[(size_t)row * 256 + t];
  float s = sv, s2 = sv * sv;
#pragma unroll
  for (int o = 32; o > 0; o >>= 1) { s += __shfl_down(s, o); s2 += __shfl_down(s2, o); }
  if ((t & 63) == 0) { rsm[t >> 6] = s; rs2[t >> 6] = s2; }
  __syncthreads();
  if (t == 0) {
    float a = rsm[0] + rsm[1] + rsm[2] + rsm[3];
    float b2 = rs2[0] + rs2[1] + rs2[2] + rs2[3];
    float m = a * (1.0f / 256.0f);
    st2[0] = m;
    st2[1] = rsqrtf(b2 * (1.0f / 256.0f) - m * m + LN_EPS);
  }
  __syncthreads();
  float y = (sv - st2[0]) * st2[1] * gam[t] + bet[t];
  hb[(size_t)row * 256 + t] = __float2bfloat16(y);
}

// ---------------- LN over 8192 cols (smolgen g) -> bf16 --------------------------------
__global__ __launch_bounds__(1024) void ln8192_kernel(const float* __restrict__ gpre,
                                                      const float* __restrict__ gam,
                                                      const float* __restrict__ bet,
                                                      bf16* __restrict__ gb) {
  __shared__ float rsm[16], rs2[16], st2[2];
  int t = threadIdx.x, row = blockIdx.x;
  const float* p = gpre + (size_t)row * 8192;
  float v[8];
  float s = 0.0f, s2 = 0.0f;
#pragma unroll
  for (int i = 0; i < 8; ++i) {
    v[i] = p[t + i * 1024];
    s += v[i];
    s2 += v[i] * v[i];
  }
#pragma unroll
  for (int o = 32; o > 0; o >>= 1) { s += __shfl_down(s, o); s2 += __shfl_down(s2, o); }
  int lane = t & 63, w = t >> 6;
  if (lane == 0) { rsm[w] = s; rs2[w] = s2; }
  __syncthreads();
  if (t == 0) {
    float a = 0.0f, b2 = 0.0f;
#pragma unroll
    for (int i = 0; i < 16; ++i) { a += rsm[i]; b2 += rs2[i]; }
    float m = a * (1.0f / 8192.0f);
    st2[0] = m;
    st2[1] = rsqrtf(b2 * (1.0f / 8192.0f) - m * m + LN_EPS);
  }
  __syncthreads();
  float m = st2[0], r = st2[1];
#pragma unroll
  for (int i = 0; i < 8; ++i) {
    int n = t + i * 1024;
    gb[(size_t)row * 8192 + n] = __float2bfloat16((v[i] - m) * r * gam[n] + bet[n]);
  }
}

// ---------------- residual + LN over 1024 cols (f32 base, bf16 delta) ------------------
__global__ __launch_bounds__(256) void ln_residual_kernel(const float* __restrict__ base,
                                                          const bf16* __restrict__ delta,
                                                          const float* __restrict__ gam,
                                                          const float* __restrict__ bet,
                                                          float* __restrict__ outf,
                                                          bf16* __restrict__ outb) {
  __shared__ float rsm[4], rs2[4], st2[2];
  int t = threadIdx.x, row = blockIdx.x;
  float4 bv = ((const float4*)(base + (size_t)row * 1024))[t];
  ushort4 du = ((const ushort4*)(delta + (size_t)row * 1024))[t];
  float4 v;
  v.x = bv.x + bfu2f(du.x) * ALPHA_F;
  v.y = bv.y + bfu2f(du.y) * ALPHA_F;
  v.z = bv.z + bfu2f(du.z) * ALPHA_F;
  v.w = bv.w + bfu2f(du.w) * ALPHA_F;
  float s = v.x + v.y + v.z + v.w;
  float s2 = v.x * v.x + v.y * v.y + v.z * v.z + v.w * v.w;
#pragma unroll
  for (int o = 32; o > 0; o >>= 1) { s += __shfl_down(s, o); s2 += __shfl_down(s2, o); }
  if ((t & 63) == 0) { rsm[t >> 6] = s; rs2[t >> 6] = s2; }
  __syncthreads();
  if (t == 0) {
    float a = rsm[0] + rsm[1] + rsm[2] + rsm[3];
    float b2 = rs2[0] + rs2[1] + rs2[2] + rs2[3];
    float m = a * (1.0f / 1024.0f);
    st2[0] = m;
    st2[1] = rsqrtf(b2 * (1.0f / 1024.0f) - m * m + LN_EPS);
  }
  __syncthreads();
  float m = st2[0], r = st2[1];
  float4 g4 = ((const float4*)gam)[t];
  float4 b4 = ((const float4*)bet)[t];
  float4 y;
  y.x = (v.x - m) * r * g4.x + b4.x;
  y.y = (v.y - m) * r * g4.y + b4.y;
  y.z = (v.z - m) * r * g4.z + b4.z;
  y.w = (v.w - m) * r * g4.w + b4.w;
  ((float4*)(outf + (size_t)row * 1024))[t] = y;
  ushort4 o4;
  o4.x = f2bfu(y.x); o4.y = f2bfu(y.y); o4.z = f2bfu(y.z); o4.w = f2bfu(y.w);
  ((ushort4*)(outb + (size_t)row * 1024))[t] = o4;
}

// ---------------- MFMA fused attention per (b,h) ---------------------------------------
__global__ __launch_bounds__(256) void attn_kernel(const bf16* __restrict__ qkv,
                                                   const bf16* __restrict__ sw,
                                                   bf16* __restrict__ avb) {
  __shared__ __align__(16) short Vt[32 * 72];
  __shared__ __align__(16) short Sw[64 * 64];
  __shared__ __align__(16) short Pl[64 * 72];
  const int t = threadIdx.x, lane = t & 63, w = t >> 6;
  const int fr = lane & 15, s4 = lane >> 4;
  const int bh = blockIdx.x, b = bh >> 5, h = bh & 31;
  const size_t qb = (size_t)b * 64 * 3072 + h * 32;
  // stage V transposed: Vt[d][k]
  {
    int k = t >> 2, d0 = (t & 3) * 8;
    bf16x8 v = *(const bf16x8*)(qkv + qb + (size_t)k * 3072 + 2048 + d0);
#pragma unroll
    for (int i = 0; i < 8; ++i) Vt[(d0 + i) * 72 + k] = v[i];
  }
  // stage sw bias [64][64]
  {
    const bf16* swp = sw + (size_t)bh * 4096;
    *(bf16x8*)(Sw + t * 8) = *(const bf16x8*)(swp + t * 8);
    *(bf16x8*)(Sw + 2048 + t * 8) = *(const bf16x8*)(swp + 2048 + t * 8);
  }
  __syncthreads();
  // QK^T: S[16 rows][64 cols] per wave
  f32x4 acc[4] = {};
  {
    bf16x8 aq = *(const bf16x8*)(qkv + qb + (size_t)(16 * w + fr) * 3072 + s4 * 8);
#pragma unroll
    for (int n = 0; n < 4; ++n) {
      bf16x8 bk = *(const bf16x8*)(qkv + qb + (size_t)(n * 16 + fr) * 3072 + 1024 + s4 * 8);
      acc[n] = __builtin_amdgcn_mfma_f32_16x16x32_bf16(aq, bk, acc[n], 0, 0, 0);
    }
  }
  // softmax over k for rows q = 16w + s4*4 + j (cols n*16+fr per lane)
  float rinv[4];
#pragma unroll
  for (int j = 0; j < 4; ++j) {
    int q = 16 * w + s4 * 4 + j;
    float pv[4];
    float mx = -1e30f;
#pragma unroll
    for (int n = 0; n < 4; ++n) {
      float v = acc[n][j] * 0.17677669529663687f +
                __bfloat162float(((const bf16*)Sw)[q * 64 + n * 16 + fr]);
      pv[n] = v;
      mx = fmaxf(mx, v);
    }
    mx = fmaxf(mx, __shfl_xor(mx, 1));
    mx = fmaxf(mx, __shfl_xor(mx, 2));
    mx = fmaxf(mx, __shfl_xor(mx, 4));
    mx = fmaxf(mx, __shfl_xor(mx, 8));
    float sum = 0.0f;
#pragma unroll
    for (int n = 0; n < 4; ++n) {
      float e = __expf(pv[n] - mx);
      sum += e;
      ((bf16*)Pl)[q * 72 + n * 16 + fr] = __float2bfloat16(e);
    }
    sum += __shfl_xor(sum, 1);
    sum += __shfl_xor(sum, 2);
    sum += __shfl_xor(sum, 4);
    sum += __shfl_xor(sum, 8);
    rinv[j] = 1.0f / sum;
  }
  __syncthreads();
  // PV: out[16 rows][32 d] per wave
  f32x4 acc2[2] = {};
#pragma unroll
  for (int kt = 0; kt < 2; ++kt) {
    bf16x8 ap = *(const bf16x8*)(Pl + (16 * w + fr) * 72 + kt * 32 + s4 * 8);
#pragma unroll
    for (int n2 = 0; n2 < 2; ++n2) {
      bf16x8 bv = *(const bf16x8*)(Vt + (n2 * 16 + fr) * 72 + kt * 32 + s4 * 8);
      acc2[n2] = __builtin_amdgcn_mfma_f32_16x16x32_bf16(ap, bv, acc2[n2], 0, 0, 0);
    }
  }
#pragma unroll
  for (int n2 = 0; n2 < 2; ++n2) {
#pragma unroll
    for (int j = 0; j < 4; ++j) {
      int q = 16 * w + s4 * 4 + j;
      int d = n2 * 16 + fr;
      avb[(size_t)(b * 64 + q) * 1024 + h * 32 + d] =
          __float2bfloat16(acc2[n2][j] * rinv[j]);
    }
  }
}

extern "C" void kernel_launch(void* const* d_in, const int* in_sizes, int n_in,
                              void* d_out, int out_size, void* d_ws, size_t ws_size,
                              hipStream_t stream) {
  const float* x_in   = (const float*)d_in[0];
  const float* wq_w   = (const float*)d_in[1];
  const float* wq_b   = (const float*)d_in[2];
  const float* wk_w   = (const float*)d_in[3];
  const float* wk_b   = (const float*)d_in[4];
  const float* wv_w   = (const float*)d_in[5];
  const float* wv_b   = (const float*)d_in[6];
  const float* wo_w   = (const float*)d_in[7];
  const float* wo_b   = (const float*)d_in[8];
  const float* sc_w   = (const float*)d_in[9];
  const float* sh1_w  = (const float*)d_in[10];
  const float* sh1_b  = (const float*)d_in[11];
  const float* sln1_g = (const float*)d_in[12];
  const float* sln1_b = (const float*)d_in[13];
  const float* sgf_w  = (const float*)d_in[14];
  const float* sgf_b  = (const float*)d_in[15];
  const float* sln2_g = (const float*)d_in[16];
  const float* sln2_b = (const float*)d_in[17];
  const float* swg_w  = (const float*)d_in[18];
  const float* ffn1_w = (const float*)d_in[19];
  const float* ffn1_b = (const float*)d_in[20];
  const float* ffn2_w = (const float*)d_in[21];
  const float* ffn2_b = (const float*)d_in[22];
  const float* n1_g   = (const float*)d_in[23];
  const float* n1_b   = (const float*)d_in[24];
  const float* n2_g   = (const float*)d_in[25];
  const float* n2_b   = (const float*)d_in[26];

  char* ws = (char*)d_ws;
  size_t off = 0;
  auto alloc = [&](size_t bytes) -> void* {
    void* p = ws + off;
    off += (bytes + 255) & ~(size_t)255;
    return p;
  };
  bf16*  xb    = (bf16*)alloc(8192ULL * 1024 * 2);
  float* P0    = (float*)alloc(8192ULL * 1024 * 4);
  float* P1    = (float*)alloc(8192ULL * 1024 * 4);
  bf16*  dT    = (bf16*)alloc(8192ULL * 1024 * 2);
  bf16*  Wqkv  = (bf16*)alloc(3072ULL * 1024 * 2);
  float* bqkv  = (float*)alloc(3072ULL * 4);
  bf16*  Wo    = (bf16*)alloc(1024ULL * 1024 * 2);
  bf16*  Wf1   = (bf16*)alloc(1536ULL * 1024 * 2);
  bf16*  Wf2   = (bf16*)alloc(1024ULL * 1536 * 2);
  bf16*  Wsgf  = (bf16*)alloc(8192ULL * 256 * 2);
  bf16*  Wswg  = (bf16*)alloc(4096ULL * 256 * 2);
  bf16*  Wsh1  = (bf16*)alloc(256ULL * 2048 * 2);
  bf16*  Wsc   = (bf16*)alloc(32ULL * 1024 * 2);
  bf16*  qkvb  = (bf16*)alloc(8192ULL * 3072 * 2);
  bf16*  cbuf  = (bf16*)alloc(8192ULL * 32 * 2);
  float* hpre  = (float*)alloc(128ULL * 256 * 4);
  bf16*  hbb   = (bf16*)alloc(128ULL * 256 * 2);
  float* gpre  = (float*)alloc(128ULL * 8192 * 4);
  bf16*  gbb   = (bf16*)alloc(128ULL * 8192 * 2);
  bf16*  swb   = (bf16*)alloc(4096ULL * 4096 * 2);
  bf16*  avb   = (bf16*)alloc(8192ULL * 1024 * 2);
  bf16*  out1b = (bf16*)alloc(8192ULL * 1024 * 2);
  bf16*  f1b   = (bf16*)alloc(8192ULL * 1536 * 2);
  if (off > ws_size) {
    sentinel_k<<<1, 1, 0, stream>>>((float*)d_out);
    return;
  }

  cvt_f32_bf16_k<<<8192, 256, 0, stream>>>(x_in, xb, 8192LL * 1024);

  for (int l = 0; l < 15; ++l) {
    const float* wq   = wq_w + (size_t)l * 1024 * 1024;
    const float* wk   = wk_w + (size_t)l * 1024 * 1024;
    const float* wv   = wv_w + (size_t)l * 1024 * 1024;
    const float* wo   = wo_w + (size_t)l * 1024 * 1024;
    const float* f1w  = ffn1_w + (size_t)l * 1024 * 1536;
    const float* f2w  = ffn2_w + (size_t)l * 1536 * 1024;
    const float* sgf  = sgf_w + (size_t)l * 256 * 8192;
    const float* swg  = swg_w + (size_t)l * 256 * 4096;
    const float* scw  = sc_w + (size_t)l * 1024 * 32;
    const float* sh1w = sh1_w + (size_t)l * 2048 * 256;

    transpose_layer<<<10784, 256, 0, stream>>>(wq, wk, wv, wo, f1w, f2w, sgf, swg, sh1w, scw,
                                               Wqkv, Wo, Wf1, Wf2, Wsgf, Wswg, Wsh1, Wsc);
    pack3_k<<<12, 256, 0, stream>>>(wq_b + l * 1024, wk_b + l * 1024, wv_b + l * 1024, bqkv);

    const float* xc = (l == 0) ? x_in : ((l & 1) ? P0 : P1);
    float* Pout = (l & 1) ? P1 : P0;

    // QKV projection (128x128, 6 blocks/CU)
    gemm_tn<128, 128, 0, true, true><<<1536, 256, 0, stream>>>(xb, Wqkv, bqkv, nullptr, qkvb,
                                                               8192, 3072, 1024);
    // smolgen chain
    c_kernel<<<512, 64, 0, stream>>>(xb, Wsc, cbuf);
    gemm_tn<64, 64, 1, false, true><<<8, 256, 0, stream>>>(cbuf, Wsh1, sh1_b + l * 256,
                                                           hpre, nullptr, 128, 256, 2048);
    ln256_kernel<<<128, 256, 0, stream>>>(hpre, sln1_g + l * 256, sln1_b + l * 256, hbb);
    gemm_tn<64, 64, 1, false, true><<<256, 256, 0, stream>>>(hbb, Wsgf,
                                                             sgf_b + (size_t)l * 8192,
                                                             gpre, nullptr, 128, 8192, 256);
    ln8192_kernel<<<128, 1024, 0, stream>>>(gpre, sln2_g + (size_t)l * 8192,
                                            sln2_b + (size_t)l * 8192, gbb);
    gemm_tn<64, 64, 0, true, false><<<4096, 256, 0, stream>>>(gbb, Wswg, nullptr, nullptr, swb,
                                                              4096, 4096, 256);
    // attention (MFMA)
    attn_kernel<<<4096, 256, 0, stream>>>(qkvb, swb, avb);
    // output projection + LN1 (bf16 delta)
    gemm_tn<64, 64, 0, true, true><<<2048, 256, 0, stream>>>(avb, Wo, wo_b + l * 1024,
                                                             nullptr, dT, 8192, 1024, 1024);
    ln_residual_kernel<<<8192, 256, 0, stream>>>(xc, dT, n1_g + l * 1024, n1_b + l * 1024,
                                                 Pout, out1b);
    // FFN + LN2 (bf16 delta)
    gemm_tn<64, 64, 2, true, true><<<3072, 256, 0, stream>>>(out1b, Wf1, ffn1_b + l * 1536,
                                                             nullptr, f1b, 8192, 1536, 1024);
    gemm_tn<64, 64, 0, true, true><<<2048, 256, 0, stream>>>(f1b, Wf2, ffn2_b + l * 1024,
                                                             nullptr, dT, 8192, 1024, 1536);
    float* xnext = (l == 14) ? (float*)d_out : Pout;
    ln_residual_kernel<<<8192, 256, 0, stream>>>(Pout, dT, n2_g + l * 1024, n2_b + l * 1024,
                                                 xnext, xb);
  }
}